// Round 1
// baseline (732.400 us; speedup 1.0000x reference)
//
#include <hip/hip_runtime.h>
#include <math.h>

#define NN 50000
#define NE 400000

// ---------------- device helpers ----------------
__device__ __forceinline__ float lrelu(float v){ return v > 0.f ? v : 0.2f*v; }
__device__ __forceinline__ float elu1(float v){ return v > 0.f ? v : expm1f(v); }

// ---------------- CSR build ----------------
__global__ void k_count(const int* __restrict__ col, int* __restrict__ cnt, int E){
  int e = blockIdx.x*blockDim.x + threadIdx.x;
  if(e < E) atomicAdd(&cnt[col[e]], 1);
}

// single-block exclusive scan over cnt -> offs; also dis = (cnt+1)^-1/2, invc = 1/max(cnt,1)
__global__ void k_scan(const int* __restrict__ cnt, int* __restrict__ offs,
                       float* __restrict__ dis, float* __restrict__ invc, int N, int E){
  __shared__ int wsum[16];
  int tid = threadIdx.x, lane = tid & 63, w = tid >> 6;
  int carry = 0;
  for(int base = 0; base < N; base += 1024){
    int i = base + tid;
    int v = (i < N) ? cnt[i] : 0;
    int x = v;
    #pragma unroll
    for(int d = 1; d < 64; d <<= 1){ int t = __shfl_up(x, d, 64); if(lane >= d) x += t; }
    if(lane == 63) wsum[w] = x;
    __syncthreads();
    if(tid < 16){
      int s = wsum[tid];
      #pragma unroll
      for(int d = 1; d < 16; d <<= 1){ int t = __shfl_up(s, d, 16); if(tid >= d) s += t; }
      wsum[tid] = s;
    }
    __syncthreads();
    int pre = (w > 0) ? wsum[w-1] : 0;
    int tot = wsum[15];
    if(i < N){
      offs[i] = carry + pre + x - v;           // exclusive prefix
      dis[i]  = 1.0f / sqrtf((float)(v + 1));  // GCN: deg includes self loop
      invc[i] = 1.0f / fmaxf((float)v, 1.0f);  // SAGE mean denominator
    }
    carry += tot;
    __syncthreads();
  }
  if(tid == 0) offs[N] = E;
}

__global__ void k_fill(const int* __restrict__ row, const int* __restrict__ col,
                       const int* __restrict__ offs, int* __restrict__ cursor,
                       int* __restrict__ csr, int E){
  int e = blockIdx.x*blockDim.x + threadIdx.x;
  if(e < E){
    int c = col[e];
    int pos = offs[c] + atomicAdd(&cursor[c], 1);
    csr[pos] = row[e];
  }
}

// ---------------- gate ----------------
__global__ void k_colsum(const float* __restrict__ x, float* __restrict__ gsum, int N){
  __shared__ float part[4][64];
  int lane = threadIdx.x & 63, w = threadIdx.x >> 6;
  float s = 0.f;
  for(int r = blockIdx.x*4 + w; r < N; r += gridDim.x*4) s += x[(size_t)r*64 + lane];
  part[w][lane] = s;
  __syncthreads();
  if(w == 0) atomicAdd(&gsum[lane], part[0][lane]+part[1][lane]+part[2][lane]+part[3][lane]);
}

__global__ void k_gate(const float* __restrict__ gsum,
                       const float* __restrict__ w1, const float* __restrict__ b1,
                       const float* __restrict__ w2, const float* __restrict__ b2,
                       float* __restrict__ gatew){
  __shared__ float g[64]; __shared__ float hid[64]; __shared__ float lg[3];
  int t = threadIdx.x;
  g[t] = gsum[t] * (1.0f/(float)NN);
  __syncthreads();
  float acc = b1[t];
  for(int i = 0; i < 64; i++) acc += g[i]*w1[i*64 + t];
  hid[t] = fmaxf(acc, 0.f);
  __syncthreads();
  if(t < 3){
    float a = b2[t];
    for(int j = 0; j < 64; j++) a += hid[j]*w2[j*3 + t];
    lg[t] = a;
  }
  __syncthreads();
  if(t == 0){
    float m = fmaxf(lg[0], fmaxf(lg[1], lg[2]));
    float e0 = expf(lg[0]-m), e1 = expf(lg[1]-m), e2 = expf(lg[2]-m);
    float s = e0 + e1 + e2;
    gatew[0] = e0/s; gatew[1] = e1/s; gatew[2] = e2/s;
  }
}

// ---------------- dense matmul: C[N,Kout] = A[N,Kin] @ W[Kin,Kout] ----------------
// 64x64 output tile per block, 4x4 register tile per thread, K chunked by 64.
__global__ __launch_bounds__(256) void k_mm(const float* __restrict__ A, const float* __restrict__ W,
                                            float* __restrict__ C, int N, int Kin, int Kout){
  __shared__ float As[64][68];   // transposed: As[k][row], pad to 68 for 16B alignment
  __shared__ float Ws[64][64];   // Ws[k][col]
  int tid = threadIdx.x;
  int tx = tid & 15, ty = tid >> 4;
  int row0 = blockIdx.x*64;
  int col0 = blockIdx.y*64;
  float acc[4][4];
  #pragma unroll
  for(int i = 0; i < 4; i++)
    #pragma unroll
    for(int j = 0; j < 4; j++) acc[i][j] = 0.f;

  for(int kc = 0; kc < Kin; kc += 64){
    #pragma unroll
    for(int p = 0; p < 4; p++){
      int slot = p*256 + tid;
      int r = slot >> 4, k4 = (slot & 15) << 2;
      int rr = row0 + r; if(rr >= N) rr = N - 1;
      const float4 av = *(const float4*)&A[(size_t)rr*Kin + kc + k4];
      As[k4+0][r] = av.x; As[k4+1][r] = av.y; As[k4+2][r] = av.z; As[k4+3][r] = av.w;
      *(float4*)&Ws[r][k4] = *(const float4*)&W[(size_t)(kc + r)*Kout + col0 + k4];
    }
    __syncthreads();
    #pragma unroll 8
    for(int kk = 0; kk < 64; kk++){
      float4 av = *(const float4*)&As[kk][ty << 2];
      float4 bv = *(const float4*)&Ws[kk][tx << 2];
      float a_[4] = {av.x, av.y, av.z, av.w};
      float b_[4] = {bv.x, bv.y, bv.z, bv.w};
      #pragma unroll
      for(int i = 0; i < 4; i++)
        #pragma unroll
        for(int j = 0; j < 4; j++) acc[i][j] += a_[i]*b_[j];
    }
    __syncthreads();
  }
  #pragma unroll
  for(int i = 0; i < 4; i++){
    int r = row0 + (ty << 2) + i;
    if(r < N){
      float4 o; o.x = acc[i][0]; o.y = acc[i][1]; o.z = acc[i][2]; o.w = acc[i][3];
      *(float4*)&C[(size_t)r*Kout + col0 + (tx << 2)] = o;
    }
  }
}

// ---------------- attention per-node dots: asrc[n,h] = <h[n,h,:], att_src[h,:]> ----------------
__global__ void k_attdot(const float* __restrict__ h, const float* __restrict__ att_src,
                         const float* __restrict__ att_dst, float* __restrict__ asrc,
                         float* __restrict__ adst, int N, int H){
  int node = blockIdx.x*4 + (threadIdx.x >> 6);
  int lane = threadIdx.x & 63;
  if(node >= N) return;
  int C = H*64;
  for(int hh = 0; hh < H; hh++){
    float v = h[(size_t)node*C + hh*64 + lane];
    float vs = v*att_src[hh*64 + lane];
    float vd = v*att_dst[hh*64 + lane];
    #pragma unroll
    for(int d = 32; d >= 1; d >>= 1){ vs += __shfl_xor(vs, d, 64); vd += __shfl_xor(vd, d, 64); }
    if(lane == 0){ asrc[node*H + hh] = vs; adst[node*H + hh] = vd; }
  }
}

// ---------------- GCN aggregation (CSR, self-loop analytic) ----------------
// mode 0: out = relu(BN(agg + b));  mode 1: out = gatew[0]*(agg + b)   (fresh write to d_out)
__global__ void k_agg_gcn(const float* __restrict__ h, const float* __restrict__ dis,
                          const int* __restrict__ offs, const int* __restrict__ csr,
                          const float* __restrict__ bias, const float* __restrict__ gamma,
                          const float* __restrict__ beta, const float* __restrict__ gatew,
                          float* __restrict__ out, int N, int mode){
  int node = blockIdx.x*4 + (threadIdx.x >> 6);
  int lane = threadIdx.x & 63;
  if(node >= N) return;
  float dc = dis[node];
  float acc = dc * h[(size_t)node*64 + lane];   // self loop: dis[c]^2 * h[c] (dc applied below)
  int e0 = offs[node], e1 = offs[node+1];
  for(int e = e0; e < e1; e++){
    int s = csr[e];
    acc += dis[s]*h[(size_t)s*64 + lane];
  }
  float val = dc*acc + bias[lane];
  if(mode == 0){
    val = val * (gamma[lane]*rsqrtf(1.0f + 1e-5f)) + beta[lane];
    out[(size_t)node*64 + lane] = fmaxf(val, 0.f);
  } else {
    out[(size_t)node*64 + lane] = gatew[0]*val;
  }
}

// ---------------- GAT layer-1 aggregation: fused softmax (shift-invariant, no max pass) ----------------
__global__ void k_agg_gat1(const float* __restrict__ h1, const float* __restrict__ asrc,
                           const float* __restrict__ adst, const int* __restrict__ offs,
                           const int* __restrict__ csr, const float* __restrict__ bias,
                           float* __restrict__ out, int N){
  int node = blockIdx.x*4 + (threadIdx.x >> 6);
  int lane = threadIdx.x & 63;
  if(node >= N) return;
  float ad[4];
  #pragma unroll
  for(int h = 0; h < 4; h++) ad[h] = adst[node*4 + h];
  float num[4] = {0,0,0,0}, den[4] = {0,0,0,0};
  int e0 = offs[node], e1 = offs[node+1];
  for(int e = e0 - 1; e < e1; e++){           // e==e0-1 is the self loop
    int s = (e < e0) ? node : csr[e];
    const float* hp = &h1[(size_t)s*256];
    #pragma unroll
    for(int h = 0; h < 4; h++){
      float wv = expf(lrelu(asrc[s*4 + h] + ad[h]));
      num[h] += wv*hp[h*64 + lane];
      den[h] += wv;
    }
  }
  #pragma unroll
  for(int h = 0; h < 4; h++)
    out[(size_t)node*256 + h*64 + lane] = elu1(num[h]/den[h] + bias[h*64 + lane]);
}

// ---------------- GAT layer-2 aggregation (1 head), accumulate gatew[1]* into d_out ----------------
__global__ void k_agg_gat2(const float* __restrict__ h2, const float* __restrict__ asrc,
                           const float* __restrict__ adst, const int* __restrict__ offs,
                           const int* __restrict__ csr, const float* __restrict__ bias,
                           const float* __restrict__ gatew, float* __restrict__ out, int N){
  int node = blockIdx.x*4 + (threadIdx.x >> 6);
  int lane = threadIdx.x & 63;
  if(node >= N) return;
  float adc = adst[node];
  float num = 0.f, den = 0.f;
  int e0 = offs[node], e1 = offs[node+1];
  for(int e = e0 - 1; e < e1; e++){
    int s = (e < e0) ? node : csr[e];
    float wv = expf(lrelu(asrc[s] + adc));
    num += wv*h2[(size_t)s*64 + lane];
    den += wv;
  }
  float val = num/den + bias[lane];
  out[(size_t)node*64 + lane] += gatew[1]*val;
}

// ---------------- SAGE aggregation: mean(p over in-edges)/cnt + b + q, L2-normalize ----------------
// mode 0: relu -> out;  mode 1: out += gatew[2]*val
__global__ void k_agg_sage(const float* __restrict__ p, const float* __restrict__ q,
                           const float* __restrict__ invc, const int* __restrict__ offs,
                           const int* __restrict__ csr, const float* __restrict__ bias,
                           const float* __restrict__ gatew, float* __restrict__ out,
                           int N, int mode){
  int node = blockIdx.x*4 + (threadIdx.x >> 6);
  int lane = threadIdx.x & 63;
  if(node >= N) return;
  float m = 0.f;
  int e0 = offs[node], e1 = offs[node+1];
  for(int e = e0; e < e1; e++) m += p[(size_t)csr[e]*64 + lane];
  float val = m*invc[node] + bias[lane] + q[(size_t)node*64 + lane];
  float n2 = val*val;
  #pragma unroll
  for(int d = 32; d >= 1; d >>= 1) n2 += __shfl_xor(n2, d, 64);
  float nrm = sqrtf(n2);
  val = val / fmaxf(nrm, 1e-12f);
  if(mode == 0) out[(size_t)node*64 + lane] = fmaxf(val, 0.f);
  else          out[(size_t)node*64 + lane] += gatew[2]*val;
}

// ---------------- host ----------------
extern "C" void kernel_launch(void* const* d_in, const int* in_sizes, int n_in,
                              void* d_out, int out_size, void* d_ws, size_t ws_size,
                              hipStream_t stream){
  const float* x        = (const float*)d_in[0];
  const int*   ei       = (const int*)d_in[1];
  const int*   row      = ei;
  const int*   col      = ei + NE;
  const float* gate_w1  = (const float*)d_in[2];
  const float* gate_b1  = (const float*)d_in[3];
  const float* gate_w2  = (const float*)d_in[4];
  const float* gate_b2  = (const float*)d_in[5];
  const float* gcn_w1   = (const float*)d_in[6];
  const float* gcn_b1   = (const float*)d_in[7];
  const float* bn_gamma = (const float*)d_in[8];
  const float* bn_beta  = (const float*)d_in[9];
  const float* gcn_w2   = (const float*)d_in[10];
  const float* gcn_b2   = (const float*)d_in[11];
  const float* gat_w1   = (const float*)d_in[12];
  const float* gat_as1  = (const float*)d_in[13];
  const float* gat_ad1  = (const float*)d_in[14];
  const float* gat_b1   = (const float*)d_in[15];
  const float* gat_w2   = (const float*)d_in[16];
  const float* gat_as2  = (const float*)d_in[17];
  const float* gat_ad2  = (const float*)d_in[18];
  const float* gat_b2   = (const float*)d_in[19];
  const float* sage_wl1 = (const float*)d_in[20];
  const float* sage_bl1 = (const float*)d_in[21];
  const float* sage_wr1 = (const float*)d_in[22];
  const float* sage_wl2 = (const float*)d_in[23];
  const float* sage_bl2 = (const float*)d_in[24];
  const float* sage_wr2 = (const float*)d_in[25];
  float* out = (float*)d_out;

  // workspace layout (256B aligned chunks)
  char* wp = (char*)d_ws;
  auto alloc = [&](size_t bytes)->char*{ char* p = wp; wp += (bytes + 255) & ~(size_t)255; return p; };
  int*   cnt    = (int*)  alloc((size_t)NN*4);
  int*   offs   = (int*)  alloc((size_t)(NN+1)*4);
  int*   cursor = (int*)  alloc((size_t)NN*4);
  int*   csr    = (int*)  alloc((size_t)NE*4);
  float* dis    = (float*)alloc((size_t)NN*4);
  float* invc   = (float*)alloc((size_t)NN*4);
  float* gsum   = (float*)alloc(64*4);
  float* gatew  = (float*)alloc(16);
  float* pool   = (float*)alloc((size_t)520*NN*4);   // 104 MB shared pool

  hipMemsetAsync(cnt,    0, (size_t)NN*4, stream);
  hipMemsetAsync(cursor, 0, (size_t)NN*4, stream);
  hipMemsetAsync(gsum,   0, 64*4, stream);

  // CSR + gate
  k_count<<<(NE+255)/256, 256, 0, stream>>>(col, cnt, NE);
  k_scan <<<1, 1024, 0, stream>>>(cnt, offs, dis, invc, NN, NE);
  k_fill <<<(NE+255)/256, 256, 0, stream>>>(row, col, offs, cursor, csr, NE);
  k_colsum<<<256, 256, 0, stream>>>(x, gsum, NN);
  k_gate  <<<1, 64, 0, stream>>>(gsum, gate_w1, gate_b1, gate_w2, gate_b2, gatew);

  const int gN = (NN + 63) / 64;        // 782 row tiles
  const int gAgg = NN / 4;              // 12500 blocks, 4 nodes (waves) each
  const size_t NB = (size_t)64*NN;      // floats per [N,64] buffer

  // ---- GCN branch ----
  float* a0 = pool; float* a1 = pool + NB; float* a2 = pool + 2*NB;
  k_mm<<<dim3(gN,1), 256, 0, stream>>>(x, gcn_w1, a0, NN, 64, 64);
  k_agg_gcn<<<gAgg, 256, 0, stream>>>(a0, dis, offs, csr, gcn_b1, bn_gamma, bn_beta, gatew, a1, NN, 0);
  k_mm<<<dim3(gN,1), 256, 0, stream>>>(a1, gcn_w2, a2, NN, 64, 64);
  k_agg_gcn<<<gAgg, 256, 0, stream>>>(a2, dis, offs, csr, gcn_b2, bn_gamma, bn_beta, gatew, out, NN, 1);

  // ---- GAT branch ----
  float* hgat1 = pool;                    // [N,256]
  float* gath  = pool + 4*NB;             // [N,256]
  float* asrc1 = pool + 8*NB;             // [N,4]
  float* adst1 = asrc1 + (size_t)4*NN;    // [N,4]
  k_mm<<<dim3(gN,4), 256, 0, stream>>>(x, gat_w1, hgat1, NN, 64, 256);
  k_attdot<<<gAgg, 256, 0, stream>>>(hgat1, gat_as1, gat_ad1, asrc1, adst1, NN, 4);
  k_agg_gat1<<<gAgg, 256, 0, stream>>>(hgat1, asrc1, adst1, offs, csr, gat_b1, gath, NN);
  float* hgat2 = pool;                    // [N,64] (hgat1 dead)
  float* asrc2 = pool + NB;               // [N]
  float* adst2 = asrc2 + NN;              // [N]
  k_mm<<<dim3(gN,1), 256, 0, stream>>>(gath, gat_w2, hgat2, NN, 256, 64);
  k_attdot<<<gAgg, 256, 0, stream>>>(hgat2, gat_as2, gat_ad2, asrc2, adst2, NN, 1);
  k_agg_gat2<<<gAgg, 256, 0, stream>>>(hgat2, asrc2, adst2, offs, csr, gat_b2, gatew, out, NN);

  // ---- SAGE branch ----
  float* p1 = pool; float* q1 = pool + NB; float* s1 = pool + 2*NB;
  float* p2 = pool + 3*NB; float* q2 = pool + 4*NB;
  k_mm<<<dim3(gN,1), 256, 0, stream>>>(x, sage_wl1, p1, NN, 64, 64);
  k_mm<<<dim3(gN,1), 256, 0, stream>>>(x, sage_wr1, q1, NN, 64, 64);
  k_agg_sage<<<gAgg, 256, 0, stream>>>(p1, q1, invc, offs, csr, sage_bl1, gatew, s1, NN, 0);
  k_mm<<<dim3(gN,1), 256, 0, stream>>>(s1, sage_wl2, p2, NN, 64, 64);
  k_mm<<<dim3(gN,1), 256, 0, stream>>>(s1, sage_wr2, q2, NN, 64, 64);
  k_agg_sage<<<gAgg, 256, 0, stream>>>(p2, q2, invc, offs, csr, sage_bl2, gatew, out, NN, 1);
}

// Round 2
// 595.147 us; speedup vs baseline: 1.2306x; 1.2306x over previous
//
#include <hip/hip_runtime.h>
#include <hip/hip_bf16.h>
#include <math.h>

#define NN 50000
#define NE 400000

// ---------------- helpers ----------------
__device__ __forceinline__ float lrelu(float v){ return v > 0.f ? v : 0.2f*v; }
__device__ __forceinline__ float elu1(float v){ return v > 0.f ? v : expm1f(v); }
__device__ __forceinline__ float bf2f(unsigned short u){ return __uint_as_float(((unsigned int)u) << 16); }
__device__ __forceinline__ unsigned short f2bf(float f){
  __hip_bfloat16 h = __float2bfloat16(f);
  return *(unsigned short*)&h;
}

// ---------------- CSR build ----------------
__global__ void k_count(const int* __restrict__ col, int* __restrict__ cnt, int E){
  int e = blockIdx.x*blockDim.x + threadIdx.x;
  if(e < E) atomicAdd(&cnt[col[e]], 1);
}

__global__ void k_scan(const int* __restrict__ cnt, int* __restrict__ offs,
                       float* __restrict__ dis, float* __restrict__ invc, int N, int E){
  __shared__ int wsum[16];
  int tid = threadIdx.x, lane = tid & 63, w = tid >> 6;
  int carry = 0;
  for(int base = 0; base < N; base += 1024){
    int i = base + tid;
    int v = (i < N) ? cnt[i] : 0;
    int x = v;
    #pragma unroll
    for(int d = 1; d < 64; d <<= 1){ int t = __shfl_up(x, d, 64); if(lane >= d) x += t; }
    if(lane == 63) wsum[w] = x;
    __syncthreads();
    if(tid < 16){
      int s = wsum[tid];
      #pragma unroll
      for(int d = 1; d < 16; d <<= 1){ int t = __shfl_up(s, d, 16); if(tid >= d) s += t; }
      wsum[tid] = s;
    }
    __syncthreads();
    int pre = (w > 0) ? wsum[w-1] : 0;
    int tot = wsum[15];
    if(i < N){
      offs[i] = carry + pre + x - v;
      dis[i]  = 1.0f / sqrtf((float)(v + 1));
      invc[i] = 1.0f / fmaxf((float)v, 1.0f);
    }
    carry += tot;
    __syncthreads();
  }
  if(tid == 0) offs[N] = E;
}

__global__ void k_fill(const int* __restrict__ row, const int* __restrict__ col,
                       const int* __restrict__ offs, int* __restrict__ cursor,
                       int* __restrict__ csr, int E){
  int e = blockIdx.x*blockDim.x + threadIdx.x;
  if(e < E){
    int c = col[e];
    int pos = offs[c] + atomicAdd(&cursor[c], 1);
    csr[pos] = row[e];
  }
}

// ---------------- gate ----------------
__global__ void k_colsum(const float* __restrict__ x, float* __restrict__ gsum, int N){
  __shared__ float part[4][64];
  int lane = threadIdx.x & 63, w = threadIdx.x >> 6;
  float s = 0.f;
  for(int r = blockIdx.x*4 + w; r < N; r += gridDim.x*4) s += x[(size_t)r*64 + lane];
  part[w][lane] = s;
  __syncthreads();
  if(w == 0) atomicAdd(&gsum[lane], part[0][lane]+part[1][lane]+part[2][lane]+part[3][lane]);
}

__global__ void k_gate(const float* __restrict__ gsum,
                       const float* __restrict__ w1, const float* __restrict__ b1,
                       const float* __restrict__ w2, const float* __restrict__ b2,
                       float* __restrict__ gatew){
  __shared__ float g[64]; __shared__ float hid[64]; __shared__ float lg[3];
  int t = threadIdx.x;
  g[t] = gsum[t] * (1.0f/(float)NN);
  __syncthreads();
  float acc = b1[t];
  for(int i = 0; i < 64; i++) acc += g[i]*w1[i*64 + t];
  hid[t] = fmaxf(acc, 0.f);
  __syncthreads();
  if(t < 3){
    float a = b2[t];
    for(int j = 0; j < 64; j++) a += hid[j]*w2[j*3 + t];
    lg[t] = a;
  }
  __syncthreads();
  if(t == 0){
    float m = fmaxf(lg[0], fmaxf(lg[1], lg[2]));
    float e0 = expf(lg[0]-m), e1 = expf(lg[1]-m), e2 = expf(lg[2]-m);
    float s = e0 + e1 + e2;
    gatew[0] = e0/s; gatew[1] = e1/s; gatew[2] = e2/s;
  }
}

// ---------------- dense matmul tile (64x64 out per block, 4x4 per thread) ----------------
template<bool BF16OUT>
__device__ __forceinline__ void mm_tile(const float* __restrict__ A, const float* __restrict__ W,
                                        void* __restrict__ Cv, int N, int Kin, int Kout,
                                        int row0, int col0){
  __shared__ float As[64][68];
  __shared__ float Ws[64][64];
  int tid = threadIdx.x;
  int tx = tid & 15, ty = tid >> 4;
  float acc[4][4];
  #pragma unroll
  for(int i = 0; i < 4; i++)
    #pragma unroll
    for(int j = 0; j < 4; j++) acc[i][j] = 0.f;

  for(int kc = 0; kc < Kin; kc += 64){
    #pragma unroll
    for(int p = 0; p < 4; p++){
      int slot = p*256 + tid;
      int r = slot >> 4, k4 = (slot & 15) << 2;
      int rr = row0 + r; if(rr >= N) rr = N - 1;
      const float4 av = *(const float4*)&A[(size_t)rr*Kin + kc + k4];
      As[k4+0][r] = av.x; As[k4+1][r] = av.y; As[k4+2][r] = av.z; As[k4+3][r] = av.w;
      *(float4*)&Ws[r][k4] = *(const float4*)&W[(size_t)(kc + r)*Kout + col0 + k4];
    }
    __syncthreads();
    #pragma unroll 8
    for(int kk = 0; kk < 64; kk++){
      float4 av = *(const float4*)&As[kk][ty << 2];
      float4 bv = *(const float4*)&Ws[kk][tx << 2];
      float a_[4] = {av.x, av.y, av.z, av.w};
      float b_[4] = {bv.x, bv.y, bv.z, bv.w};
      #pragma unroll
      for(int i = 0; i < 4; i++)
        #pragma unroll
        for(int j = 0; j < 4; j++) acc[i][j] += a_[i]*b_[j];
    }
    __syncthreads();
  }
  #pragma unroll
  for(int i = 0; i < 4; i++){
    int r = row0 + (ty << 2) + i;
    if(r < N){
      if(BF16OUT){
        unsigned short* C = (unsigned short*)Cv;
        ushort4 u;
        u.x = f2bf(acc[i][0]); u.y = f2bf(acc[i][1]); u.z = f2bf(acc[i][2]); u.w = f2bf(acc[i][3]);
        *(ushort4*)&C[(size_t)r*Kout + col0 + (tx << 2)] = u;
      } else {
        float* C = (float*)Cv;
        float4 o; o.x = acc[i][0]; o.y = acc[i][1]; o.z = acc[i][2]; o.w = acc[i][3];
        *(float4*)&C[(size_t)r*Kout + col0 + (tx << 2)] = o;
      }
    }
  }
}

__global__ __launch_bounds__(256) void k_mm(const float* __restrict__ A, const float* __restrict__ W,
                                            float* __restrict__ C, int N, int Kin, int Kout){
  mm_tile<false>(A, W, C, N, Kin, Kout, blockIdx.x*64, blockIdx.y*64);
}

__global__ __launch_bounds__(256) void k_mm_bf16(const float* __restrict__ A, const float* __restrict__ W,
                                                 unsigned short* __restrict__ C, int N, int Kin, int Kout){
  mm_tile<true>(A, W, C, N, Kin, Kout, blockIdx.x*64, blockIdx.y*64);
}

// two independent 64-col matmuls sharing A (SAGE Wl/Wr)
__global__ __launch_bounds__(256) void k_mm2(const float* __restrict__ A,
                                             const float* __restrict__ W0, const float* __restrict__ W1,
                                             float* __restrict__ C0, float* __restrict__ C1,
                                             int N, int Kin){
  const float* W = blockIdx.y ? W1 : W0;
  float* C = blockIdx.y ? C1 : C0;
  mm_tile<false>(A, W, C, N, Kin, 64, blockIdx.x*64, 0);
}

// ---------------- attention per-node dots ----------------
__global__ void k_attdot4_bf16(const unsigned short* __restrict__ h,
                               const float* __restrict__ att_src, const float* __restrict__ att_dst,
                               float* __restrict__ asrc, float* __restrict__ adst, int N){
  int node = blockIdx.x*4 + (threadIdx.x >> 6);
  int lane = threadIdx.x & 63;
  if(node >= N) return;
  #pragma unroll
  for(int hh = 0; hh < 4; hh++){
    float v = bf2f(h[(size_t)node*256 + hh*64 + lane]);
    float vs = v*att_src[hh*64 + lane];
    float vd = v*att_dst[hh*64 + lane];
    #pragma unroll
    for(int d = 32; d >= 1; d >>= 1){ vs += __shfl_xor(vs, d, 64); vd += __shfl_xor(vd, d, 64); }
    if(lane == 0){ asrc[node*4 + hh] = vs; adst[node*4 + hh] = vd; }
  }
}

__global__ void k_attdot1_f32(const float* __restrict__ h,
                              const float* __restrict__ att_src, const float* __restrict__ att_dst,
                              float* __restrict__ asrc, float* __restrict__ adst, int N){
  int node = blockIdx.x*4 + (threadIdx.x >> 6);
  int lane = threadIdx.x & 63;
  if(node >= N) return;
  float v = h[(size_t)node*64 + lane];
  float vs = v*att_src[lane];
  float vd = v*att_dst[lane];
  #pragma unroll
  for(int d = 32; d >= 1; d >>= 1){ vs += __shfl_xor(vs, d, 64); vd += __shfl_xor(vd, d, 64); }
  if(lane == 0){ asrc[node] = vs; adst[node] = vd; }
}

// ---------------- GAT edge weights: wv[e] = exp(lrelu(asrc[s]+adst[c])), rden[c]=1/sum ----------------
__global__ void k_edgew1(const float* __restrict__ asrc, const float* __restrict__ adst,
                         const int* __restrict__ offs, const int* __restrict__ csr,
                         float* __restrict__ wvE, float* __restrict__ rdenN,
                         float* __restrict__ wvS, int N){
  int node = blockIdx.x*4 + (threadIdx.x >> 6);
  int lane = threadIdx.x & 63;
  if(node >= N) return;
  float4 ad = *(const float4*)&adst[node*4];
  float a0 = 0.f, a1 = 0.f, a2 = 0.f, a3 = 0.f;
  int e0 = offs[node], e1 = offs[node+1];
  for(int e = e0 + lane; e < e1; e += 64){
    int s = csr[e];
    float4 as = *(const float4*)&asrc[s*4];
    float4 w;
    w.x = expf(lrelu(as.x + ad.x));
    w.y = expf(lrelu(as.y + ad.y));
    w.z = expf(lrelu(as.z + ad.z));
    w.w = expf(lrelu(as.w + ad.w));
    a0 += w.x; a1 += w.y; a2 += w.z; a3 += w.w;
    *(float4*)&wvE[(size_t)e*4] = w;
  }
  #pragma unroll
  for(int d = 32; d >= 1; d >>= 1){
    a0 += __shfl_xor(a0, d, 64); a1 += __shfl_xor(a1, d, 64);
    a2 += __shfl_xor(a2, d, 64); a3 += __shfl_xor(a3, d, 64);
  }
  float4 asl = *(const float4*)&asrc[node*4];
  float4 ws;
  ws.x = expf(lrelu(asl.x + ad.x));
  ws.y = expf(lrelu(asl.y + ad.y));
  ws.z = expf(lrelu(asl.z + ad.z));
  ws.w = expf(lrelu(asl.w + ad.w));
  if(lane == 0){
    float4 rd;
    rd.x = 1.0f/(a0 + ws.x); rd.y = 1.0f/(a1 + ws.y);
    rd.z = 1.0f/(a2 + ws.z); rd.w = 1.0f/(a3 + ws.w);
    *(float4*)&rdenN[node*4] = rd;
    *(float4*)&wvS[node*4] = ws;
  }
}

__global__ void k_edgew2(const float* __restrict__ asrc, const float* __restrict__ adst,
                         const int* __restrict__ offs, const int* __restrict__ csr,
                         float* __restrict__ wvE, float* __restrict__ rdenN,
                         float* __restrict__ wvS, int N){
  int node = blockIdx.x*4 + (threadIdx.x >> 6);
  int lane = threadIdx.x & 63;
  if(node >= N) return;
  float ad = adst[node];
  float acc = 0.f;
  int e0 = offs[node], e1 = offs[node+1];
  for(int e = e0 + lane; e < e1; e += 64){
    float w = expf(lrelu(asrc[csr[e]] + ad));
    acc += w;
    wvE[e] = w;
  }
  #pragma unroll
  for(int d = 32; d >= 1; d >>= 1) acc += __shfl_xor(acc, d, 64);
  float ws = expf(lrelu(asrc[node] + ad));
  if(lane == 0){
    rdenN[node] = 1.0f/(acc + ws);
    wvS[node] = ws;
  }
}

// ---------------- GAT1 aggregation: wave per node, float4 over 256 bf16 channels ----------------
__global__ void k_agg_gat1v(const unsigned short* __restrict__ h1,
                            const float* __restrict__ wvE, const float* __restrict__ rdenN,
                            const float* __restrict__ wvS,
                            const int* __restrict__ offs, const int* __restrict__ csr,
                            const float* __restrict__ bias, float* __restrict__ out, int N){
  int node = blockIdx.x*4 + (threadIdx.x >> 6);
  int lane = threadIdx.x & 63;
  if(node >= N) return;
  int head = lane >> 4;
  float4 num; num.x = num.y = num.z = num.w = 0.f;
  // self loop
  {
    float a = wvS[node*4 + head];
    ushort4 u = *(const ushort4*)&h1[(size_t)node*256 + lane*4];
    num.x += a*bf2f(u.x); num.y += a*bf2f(u.y); num.z += a*bf2f(u.z); num.w += a*bf2f(u.w);
  }
  int e0 = offs[node], e1 = offs[node+1];
  for(int e = e0; e < e1; e++){
    int s = csr[e];
    float a = wvE[(size_t)e*4 + head];
    ushort4 u = *(const ushort4*)&h1[(size_t)s*256 + lane*4];
    num.x += a*bf2f(u.x); num.y += a*bf2f(u.y); num.z += a*bf2f(u.z); num.w += a*bf2f(u.w);
  }
  float rd = rdenN[node*4 + head];
  float4 b = *(const float4*)&bias[lane*4];
  float4 o;
  o.x = elu1(num.x*rd + b.x); o.y = elu1(num.y*rd + b.y);
  o.z = elu1(num.z*rd + b.z); o.w = elu1(num.w*rd + b.w);
  *(float4*)&out[(size_t)node*256 + lane*4] = o;
}

// ---------------- GAT2 aggregation: 16-lane group per node, float4 over 64 channels ----------------
__global__ void k_agg_gat2v(const float* __restrict__ h2,
                            const float* __restrict__ wvE, const float* __restrict__ rdenN,
                            const float* __restrict__ wvS,
                            const int* __restrict__ offs, const int* __restrict__ csr,
                            const float* __restrict__ bias, const float* __restrict__ gatew,
                            float* __restrict__ out, int N){
  int node = blockIdx.x*16 + (threadIdx.x >> 4);
  int l = threadIdx.x & 15;
  if(node >= N) return;
  float4 num; num.x = num.y = num.z = num.w = 0.f;
  {
    float a = wvS[node];
    float4 v = *(const float4*)&h2[(size_t)node*64 + l*4];
    num.x += a*v.x; num.y += a*v.y; num.z += a*v.z; num.w += a*v.w;
  }
  int e0 = offs[node], e1 = offs[node+1];
  for(int e = e0; e < e1; e++){
    int s = csr[e];
    float a = wvE[e];
    float4 v = *(const float4*)&h2[(size_t)s*64 + l*4];
    num.x += a*v.x; num.y += a*v.y; num.z += a*v.z; num.w += a*v.w;
  }
  float rd = rdenN[node];
  float4 b = *(const float4*)&bias[l*4];
  float g1 = gatew[1];
  float4 o = *(float4*)&out[(size_t)node*64 + l*4];
  o.x += g1*(num.x*rd + b.x); o.y += g1*(num.y*rd + b.y);
  o.z += g1*(num.z*rd + b.z); o.w += g1*(num.w*rd + b.w);
  *(float4*)&out[(size_t)node*64 + l*4] = o;
}

// ---------------- GCN aggregation: 16-lane group per node ----------------
__global__ void k_agg_gcnv(const float* __restrict__ h, const float* __restrict__ dis,
                           const int* __restrict__ offs, const int* __restrict__ csr,
                           const float* __restrict__ bias, const float* __restrict__ gamma,
                           const float* __restrict__ beta, const float* __restrict__ gatew,
                           float* __restrict__ out, int N, int mode){
  int node = blockIdx.x*16 + (threadIdx.x >> 4);
  int l = threadIdx.x & 15;
  if(node >= N) return;
  float dc = dis[node];
  float4 acc;
  {
    float4 v = *(const float4*)&h[(size_t)node*64 + l*4];
    acc.x = dc*v.x; acc.y = dc*v.y; acc.z = dc*v.z; acc.w = dc*v.w;
  }
  int e0 = offs[node], e1 = offs[node+1];
  for(int e = e0; e < e1; e++){
    int s = csr[e];
    float ds = dis[s];
    float4 v = *(const float4*)&h[(size_t)s*64 + l*4];
    acc.x += ds*v.x; acc.y += ds*v.y; acc.z += ds*v.z; acc.w += ds*v.w;
  }
  float4 b = *(const float4*)&bias[l*4];
  float4 val;
  val.x = dc*acc.x + b.x; val.y = dc*acc.y + b.y;
  val.z = dc*acc.z + b.z; val.w = dc*acc.w + b.w;
  if(mode == 0){
    const float s_ = rsqrtf(1.0f + 1e-5f);
    float4 g = *(const float4*)&gamma[l*4];
    float4 be = *(const float4*)&beta[l*4];
    val.x = val.x*(g.x*s_) + be.x; val.y = val.y*(g.y*s_) + be.y;
    val.z = val.z*(g.z*s_) + be.z; val.w = val.w*(g.w*s_) + be.w;
    float4 o;
    o.x = fmaxf(val.x, 0.f); o.y = fmaxf(val.y, 0.f);
    o.z = fmaxf(val.z, 0.f); o.w = fmaxf(val.w, 0.f);
    *(float4*)&out[(size_t)node*64 + l*4] = o;
  } else {
    float g0 = gatew[0];
    float4 o;
    o.x = g0*val.x; o.y = g0*val.y; o.z = g0*val.z; o.w = g0*val.w;
    *(float4*)&out[(size_t)node*64 + l*4] = o;
  }
}

// ---------------- SAGE aggregation: 16-lane group per node ----------------
__global__ void k_agg_sagev(const float* __restrict__ p, const float* __restrict__ q,
                            const float* __restrict__ invc, const int* __restrict__ offs,
                            const int* __restrict__ csr, const float* __restrict__ bias,
                            const float* __restrict__ gatew, float* __restrict__ out,
                            int N, int mode){
  int node = blockIdx.x*16 + (threadIdx.x >> 4);
  int l = threadIdx.x & 15;
  if(node >= N) return;
  float4 m; m.x = m.y = m.z = m.w = 0.f;
  int e0 = offs[node], e1 = offs[node+1];
  for(int e = e0; e < e1; e++){
    int s = csr[e];
    float4 v = *(const float4*)&p[(size_t)s*64 + l*4];
    m.x += v.x; m.y += v.y; m.z += v.z; m.w += v.w;
  }
  float ic = invc[node];
  float4 b = *(const float4*)&bias[l*4];
  float4 qv = *(const float4*)&q[(size_t)node*64 + l*4];
  float4 val;
  val.x = m.x*ic + b.x + qv.x; val.y = m.y*ic + b.y + qv.y;
  val.z = m.z*ic + b.z + qv.z; val.w = m.w*ic + b.w + qv.w;
  float n2 = val.x*val.x + val.y*val.y + val.z*val.z + val.w*val.w;
  #pragma unroll
  for(int d = 8; d >= 1; d >>= 1) n2 += __shfl_xor(n2, d, 64);
  float inv = 1.0f / fmaxf(sqrtf(n2), 1e-12f);
  val.x *= inv; val.y *= inv; val.z *= inv; val.w *= inv;
  if(mode == 0){
    float4 o;
    o.x = fmaxf(val.x, 0.f); o.y = fmaxf(val.y, 0.f);
    o.z = fmaxf(val.z, 0.f); o.w = fmaxf(val.w, 0.f);
    *(float4*)&out[(size_t)node*64 + l*4] = o;
  } else {
    float g2 = gatew[2];
    float4 o = *(float4*)&out[(size_t)node*64 + l*4];
    o.x += g2*val.x; o.y += g2*val.y; o.z += g2*val.z; o.w += g2*val.w;
    *(float4*)&out[(size_t)node*64 + l*4] = o;
  }
}

// ---------------- host ----------------
extern "C" void kernel_launch(void* const* d_in, const int* in_sizes, int n_in,
                              void* d_out, int out_size, void* d_ws, size_t ws_size,
                              hipStream_t stream){
  const float* x        = (const float*)d_in[0];
  const int*   ei       = (const int*)d_in[1];
  const int*   row      = ei;
  const int*   col      = ei + NE;
  const float* gate_w1  = (const float*)d_in[2];
  const float* gate_b1  = (const float*)d_in[3];
  const float* gate_w2  = (const float*)d_in[4];
  const float* gate_b2  = (const float*)d_in[5];
  const float* gcn_w1   = (const float*)d_in[6];
  const float* gcn_b1   = (const float*)d_in[7];
  const float* bn_gamma = (const float*)d_in[8];
  const float* bn_beta  = (const float*)d_in[9];
  const float* gcn_w2   = (const float*)d_in[10];
  const float* gcn_b2   = (const float*)d_in[11];
  const float* gat_w1   = (const float*)d_in[12];
  const float* gat_as1  = (const float*)d_in[13];
  const float* gat_ad1  = (const float*)d_in[14];
  const float* gat_b1   = (const float*)d_in[15];
  const float* gat_w2   = (const float*)d_in[16];
  const float* gat_as2  = (const float*)d_in[17];
  const float* gat_ad2  = (const float*)d_in[18];
  const float* gat_b2   = (const float*)d_in[19];
  const float* sage_wl1 = (const float*)d_in[20];
  const float* sage_bl1 = (const float*)d_in[21];
  const float* sage_wr1 = (const float*)d_in[22];
  const float* sage_wl2 = (const float*)d_in[23];
  const float* sage_bl2 = (const float*)d_in[24];
  const float* sage_wr2 = (const float*)d_in[25];
  float* out = (float*)d_out;

  char* wp = (char*)d_ws;
  auto alloc = [&](size_t bytes)->char*{ char* p = wp; wp += (bytes + 255) & ~(size_t)255; return p; };
  int*   cnt    = (int*)  alloc((size_t)NN*4);
  int*   offs   = (int*)  alloc((size_t)(NN+1)*4);
  int*   cursor = (int*)  alloc((size_t)NN*4);
  int*   csr    = (int*)  alloc((size_t)NE*4);
  float* dis    = (float*)alloc((size_t)NN*4);
  float* invc   = (float*)alloc((size_t)NN*4);
  float* gsum   = (float*)alloc(64*4);
  float* gatew  = (float*)alloc(16);
  float* asrc1  = (float*)alloc((size_t)NN*4*4);
  float* adst1  = (float*)alloc((size_t)NN*4*4);
  float* asrc2  = (float*)alloc((size_t)NN*4);
  float* adst2  = (float*)alloc((size_t)NN*4);
  float* wvE1   = (float*)alloc((size_t)NE*4*4);
  float* rden1  = (float*)alloc((size_t)NN*4*4);
  float* wvS1   = (float*)alloc((size_t)NN*4*4);
  float* wvE2   = (float*)alloc((size_t)NE*4);
  float* rden2  = (float*)alloc((size_t)NN*4);
  float* wvS2   = (float*)alloc((size_t)NN*4);
  const size_t NB = (size_t)64*NN;                  // floats per [N,64] fp32 buffer
  float* pool   = (float*)alloc(7*NB*4);            // 89.6 MB

  hipMemsetAsync(cnt,    0, (size_t)NN*4, stream);
  hipMemsetAsync(cursor, 0, (size_t)NN*4, stream);
  hipMemsetAsync(gsum,   0, 64*4, stream);

  k_count<<<(NE+255)/256, 256, 0, stream>>>(col, cnt, NE);
  k_scan <<<1, 1024, 0, stream>>>(cnt, offs, dis, invc, NN, NE);
  k_fill <<<(NE+255)/256, 256, 0, stream>>>(row, col, offs, cursor, csr, NE);
  k_colsum<<<256, 256, 0, stream>>>(x, gsum, NN);
  k_gate  <<<1, 64, 0, stream>>>(gsum, gate_w1, gate_b1, gate_w2, gate_b2, gatew);

  const int gN  = (NN + 63) / 64;   // 782
  const int g4  = NN / 4;           // 12500 (wave per node)
  const int g16 = NN / 16;          // 3125 (16-lane group per node)

  // ---- GCN branch ----
  float* a0 = pool; float* a1 = pool + NB; float* a2 = pool + 2*NB;
  k_mm<<<dim3(gN,1), 256, 0, stream>>>(x, gcn_w1, a0, NN, 64, 64);
  k_agg_gcnv<<<g16, 256, 0, stream>>>(a0, dis, offs, csr, gcn_b1, bn_gamma, bn_beta, gatew, a1, NN, 0);
  k_mm<<<dim3(gN,1), 256, 0, stream>>>(a1, gcn_w2, a2, NN, 64, 64);
  k_agg_gcnv<<<g16, 256, 0, stream>>>(a2, dis, offs, csr, gcn_b2, bn_gamma, bn_beta, gatew, out, NN, 1);

  // ---- GAT branch ----
  unsigned short* h1bf = (unsigned short*)pool;   // [N,256] bf16 = 25.6 MB (2 NB-slots)
  float* gath = pool + 2*NB;                      // [N,256] fp32 (4 NB-slots)
  float* h2   = pool + 6*NB;                      // [N,64] fp32
  k_mm_bf16<<<dim3(gN,4), 256, 0, stream>>>(x, gat_w1, h1bf, NN, 64, 256);
  k_attdot4_bf16<<<g4, 256, 0, stream>>>(h1bf, gat_as1, gat_ad1, asrc1, adst1, NN);
  k_edgew1<<<g4, 256, 0, stream>>>(asrc1, adst1, offs, csr, wvE1, rden1, wvS1, NN);
  k_agg_gat1v<<<g4, 256, 0, stream>>>(h1bf, wvE1, rden1, wvS1, offs, csr, gat_b1, gath, NN);
  k_mm<<<dim3(gN,1), 256, 0, stream>>>(gath, gat_w2, h2, NN, 256, 64);
  k_attdot1_f32<<<g4, 256, 0, stream>>>(h2, gat_as2, gat_ad2, asrc2, adst2, NN);
  k_edgew2<<<g4, 256, 0, stream>>>(asrc2, adst2, offs, csr, wvE2, rden2, wvS2, NN);
  k_agg_gat2v<<<g16, 256, 0, stream>>>(h2, wvE2, rden2, wvS2, offs, csr, gat_b2, gatew, out, NN);

  // ---- SAGE branch ----
  float* p1 = pool; float* q1 = pool + NB; float* s1 = pool + 2*NB;
  float* p2 = pool + 3*NB; float* q2 = pool + 4*NB;
  k_mm2<<<dim3(gN,2), 256, 0, stream>>>(x, sage_wl1, sage_wr1, p1, q1, NN, 64);
  k_agg_sagev<<<g16, 256, 0, stream>>>(p1, q1, invc, offs, csr, sage_bl1, gatew, s1, NN, 0);
  k_mm2<<<dim3(gN,2), 256, 0, stream>>>(s1, sage_wl2, sage_wr2, p2, q2, NN, 64);
  k_agg_sagev<<<g16, 256, 0, stream>>>(p2, q2, invc, offs, csr, sage_bl2, gatew, out, NN, 1);
}

// Round 3
// 458.132 us; speedup vs baseline: 1.5987x; 1.2991x over previous
//
#include <hip/hip_runtime.h>
#include <hip/hip_bf16.h>
#include <math.h>

#define NN 50000
#define NE 400000

typedef __attribute__((ext_vector_type(8))) short bf16x8;
typedef __attribute__((ext_vector_type(4))) float f32x4;

// ---------------- helpers ----------------
__device__ __forceinline__ float lrelu(float v){ return v > 0.f ? v : 0.2f*v; }
__device__ __forceinline__ float elu1(float v){ return v > 0.f ? v : expm1f(v); }
__device__ __forceinline__ float bf2f(unsigned short u){ return __uint_as_float(((unsigned int)u) << 16); }
__device__ __forceinline__ unsigned short f2bf(float f){
  __hip_bfloat16 h = __float2bfloat16(f);
  return *(unsigned short*)&h;
}
__device__ __forceinline__ float4 bfu4(ushort4 u){
  float4 r; r.x = bf2f(u.x); r.y = bf2f(u.y); r.z = bf2f(u.z); r.w = bf2f(u.w); return r;
}

// ---------------- CSR build ----------------
__global__ void k_count(const int* __restrict__ col, int* __restrict__ cnt, int E){
  int e = blockIdx.x*blockDim.x + threadIdx.x;
  if(e < E) atomicAdd(&cnt[col[e]], 1);
}

__global__ void k_scan(const int* __restrict__ cnt, int* __restrict__ offs,
                       float* __restrict__ dis, float* __restrict__ invc, int N, int E){
  __shared__ int wsum[16];
  int tid = threadIdx.x, lane = tid & 63, w = tid >> 6;
  int carry = 0;
  for(int base = 0; base < N; base += 1024){
    int i = base + tid;
    int v = (i < N) ? cnt[i] : 0;
    int x = v;
    #pragma unroll
    for(int d = 1; d < 64; d <<= 1){ int t = __shfl_up(x, d, 64); if(lane >= d) x += t; }
    if(lane == 63) wsum[w] = x;
    __syncthreads();
    if(tid < 16){
      int s = wsum[tid];
      #pragma unroll
      for(int d = 1; d < 16; d <<= 1){ int t = __shfl_up(s, d, 16); if(tid >= d) s += t; }
      wsum[tid] = s;
    }
    __syncthreads();
    int pre = (w > 0) ? wsum[w-1] : 0;
    int tot = wsum[15];
    if(i < N){
      offs[i] = carry + pre + x - v;
      dis[i]  = 1.0f / sqrtf((float)(v + 1));
      invc[i] = 1.0f / fmaxf((float)v, 1.0f);
    }
    carry += tot;
    __syncthreads();
  }
  if(tid == 0) offs[N] = E;
}

__global__ void k_fill(const int* __restrict__ row, const int* __restrict__ col,
                       const int* __restrict__ offs, int* __restrict__ cursor,
                       int* __restrict__ csr, int E){
  int e = blockIdx.x*blockDim.x + threadIdx.x;
  if(e < E){
    int c = col[e];
    int pos = offs[c] + atomicAdd(&cursor[c], 1);
    csr[pos] = row[e];
  }
}

// ---------------- cast x -> bf16 + column sums for gate ----------------
__global__ void k_castsum(const float* __restrict__ x, unsigned short* __restrict__ xb,
                          float* __restrict__ gsum, int N){
  __shared__ float part[4][64];
  int lane = threadIdx.x & 63, w = threadIdx.x >> 6;
  float s = 0.f;
  for(int r = blockIdx.x*4 + w; r < N; r += gridDim.x*4){
    float v = x[(size_t)r*64 + lane];
    xb[(size_t)r*64 + lane] = f2bf(v);
    s += v;
  }
  part[w][lane] = s;
  __syncthreads();
  if(w == 0) atomicAdd(&gsum[lane], part[0][lane]+part[1][lane]+part[2][lane]+part[3][lane]);
}

__global__ void k_gate(const float* __restrict__ gsum,
                       const float* __restrict__ w1, const float* __restrict__ b1,
                       const float* __restrict__ w2, const float* __restrict__ b2,
                       float* __restrict__ gatew){
  __shared__ float g[64]; __shared__ float hid[64]; __shared__ float lg[3];
  int t = threadIdx.x;
  g[t] = gsum[t] * (1.0f/(float)NN);
  __syncthreads();
  float acc = b1[t];
  for(int i = 0; i < 64; i++) acc += g[i]*w1[i*64 + t];
  hid[t] = fmaxf(acc, 0.f);
  __syncthreads();
  if(t < 3){
    float a = b2[t];
    for(int j = 0; j < 64; j++) a += hid[j]*w2[j*3 + t];
    lg[t] = a;
  }
  __syncthreads();
  if(t == 0){
    float m = fmaxf(lg[0], fmaxf(lg[1], lg[2]));
    float e0 = expf(lg[0]-m), e1 = expf(lg[1]-m), e2 = expf(lg[2]-m);
    float s = e0 + e1 + e2;
    gatew[0] = e0/s; gatew[1] = e1/s; gatew[2] = e2/s;
  }
}

// ---------------- MFMA bf16 matmul: C[N,?] = A[N,K] @ W[K, 64-col slab] ----------------
struct MMP {
  const unsigned short* A[4];
  const float* W[4];
  unsigned short* C[4];
  int K, ldw, ldc, slab, N;
};

__global__ __launch_bounds__(256) void k_mm_mfma(MMP p){
  __shared__ unsigned short Wt[64*264];   // transposed W slab, pitch K+8 (max K=256)
  int by = blockIdx.y;
  const unsigned short* A; const float* W; unsigned short* C; int col0;
  if(p.slab){ A = p.A[0]; W = p.W[0]; C = p.C[0]; col0 = by*64; }
  else      { A = p.A[by]; W = p.W[by]; C = p.C[by]; col0 = 0; }
  const int K = p.K, ldw = p.ldw, ldc = p.ldc, N = p.N;
  const int pitch = K + 8;
  int tid = threadIdx.x;
  {
    int n = tid & 63;
    for(int k = tid >> 6; k < K; k += 4)
      Wt[n*pitch + k] = f2bf(W[(size_t)k*ldw + col0 + n]);
  }
  __syncthreads();
  int w = tid >> 6, lane = tid & 63, quad = lane >> 4, m16 = lane & 15;
  int rowa = blockIdx.x*64 + w*16 + m16;
  int rowc = rowa < N ? rowa : N - 1;
  f32x4 acc[4];
  #pragma unroll
  for(int t = 0; t < 4; t++){ acc[t][0]=0.f; acc[t][1]=0.f; acc[t][2]=0.f; acc[t][3]=0.f; }
  for(int kc = 0; kc < K; kc += 64){
    bf16x8 a0 = *(const bf16x8*)&A[(size_t)rowc*K + kc + quad*8];
    bf16x8 a1 = *(const bf16x8*)&A[(size_t)rowc*K + kc + 32 + quad*8];
    #pragma unroll
    for(int t = 0; t < 4; t++){
      bf16x8 b0 = *(const bf16x8*)&Wt[(t*16 + m16)*pitch + kc + quad*8];
      bf16x8 b1 = *(const bf16x8*)&Wt[(t*16 + m16)*pitch + kc + 32 + quad*8];
      acc[t] = __builtin_amdgcn_mfma_f32_16x16x32_bf16(a0, b0, acc[t], 0, 0, 0);
      acc[t] = __builtin_amdgcn_mfma_f32_16x16x32_bf16(a1, b1, acc[t], 0, 0, 0);
    }
  }
  int robase = blockIdx.x*64 + w*16 + quad*4;
  #pragma unroll
  for(int t = 0; t < 4; t++){
    #pragma unroll
    for(int r = 0; r < 4; r++){
      int ro = robase + r;
      if(ro < N) C[(size_t)ro*ldc + col0 + t*16 + m16] = f2bf(acc[t][r]);
    }
  }
}

// ---------------- attention per-node dots (bf16 h) ----------------
__global__ void k_attdot4(const unsigned short* __restrict__ h,
                          const float* __restrict__ att_src, const float* __restrict__ att_dst,
                          float* __restrict__ asrc, float* __restrict__ adst, int N){
  int node = blockIdx.x*4 + (threadIdx.x >> 6);
  int lane = threadIdx.x & 63;
  if(node >= N) return;
  #pragma unroll
  for(int hh = 0; hh < 4; hh++){
    float v = bf2f(h[(size_t)node*256 + hh*64 + lane]);
    float vs = v*att_src[hh*64 + lane];
    float vd = v*att_dst[hh*64 + lane];
    #pragma unroll
    for(int d = 32; d >= 1; d >>= 1){ vs += __shfl_xor(vs, d, 64); vd += __shfl_xor(vd, d, 64); }
    if(lane == 0){ asrc[node*4 + hh] = vs; adst[node*4 + hh] = vd; }
  }
}

__global__ void k_attdot1(const unsigned short* __restrict__ h,
                          const float* __restrict__ att_src, const float* __restrict__ att_dst,
                          float* __restrict__ asrc, float* __restrict__ adst, int N){
  int node = blockIdx.x*4 + (threadIdx.x >> 6);
  int lane = threadIdx.x & 63;
  if(node >= N) return;
  float v = bf2f(h[(size_t)node*64 + lane]);
  float vs = v*att_src[lane];
  float vd = v*att_dst[lane];
  #pragma unroll
  for(int d = 32; d >= 1; d >>= 1){ vs += __shfl_xor(vs, d, 64); vd += __shfl_xor(vd, d, 64); }
  if(lane == 0){ asrc[node] = vs; adst[node] = vd; }
}

// ---------------- GAT edge weights ----------------
__global__ void k_edgew1(const float* __restrict__ asrc, const float* __restrict__ adst,
                         const int* __restrict__ offs, const int* __restrict__ csr,
                         float* __restrict__ wvE, float* __restrict__ rdenN,
                         float* __restrict__ wvS, int N){
  int node = blockIdx.x*4 + (threadIdx.x >> 6);
  int lane = threadIdx.x & 63;
  if(node >= N) return;
  float4 ad = *(const float4*)&adst[node*4];
  float a0 = 0.f, a1 = 0.f, a2 = 0.f, a3 = 0.f;
  int e0 = offs[node], e1 = offs[node+1];
  for(int e = e0 + lane; e < e1; e += 64){
    int s = csr[e];
    float4 as = *(const float4*)&asrc[s*4];
    float4 w;
    w.x = expf(lrelu(as.x + ad.x));
    w.y = expf(lrelu(as.y + ad.y));
    w.z = expf(lrelu(as.z + ad.z));
    w.w = expf(lrelu(as.w + ad.w));
    a0 += w.x; a1 += w.y; a2 += w.z; a3 += w.w;
    *(float4*)&wvE[(size_t)e*4] = w;
  }
  #pragma unroll
  for(int d = 32; d >= 1; d >>= 1){
    a0 += __shfl_xor(a0, d, 64); a1 += __shfl_xor(a1, d, 64);
    a2 += __shfl_xor(a2, d, 64); a3 += __shfl_xor(a3, d, 64);
  }
  float4 asl = *(const float4*)&asrc[node*4];
  float4 ws;
  ws.x = expf(lrelu(asl.x + ad.x));
  ws.y = expf(lrelu(asl.y + ad.y));
  ws.z = expf(lrelu(asl.z + ad.z));
  ws.w = expf(lrelu(asl.w + ad.w));
  if(lane == 0){
    float4 rd;
    rd.x = 1.0f/(a0 + ws.x); rd.y = 1.0f/(a1 + ws.y);
    rd.z = 1.0f/(a2 + ws.z); rd.w = 1.0f/(a3 + ws.w);
    *(float4*)&rdenN[node*4] = rd;
    *(float4*)&wvS[node*4] = ws;
  }
}

__global__ void k_edgew2(const float* __restrict__ asrc, const float* __restrict__ adst,
                         const int* __restrict__ offs, const int* __restrict__ csr,
                         float* __restrict__ wvE, float* __restrict__ rdenN,
                         float* __restrict__ wvS, int N){
  int node = blockIdx.x*4 + (threadIdx.x >> 6);
  int lane = threadIdx.x & 63;
  if(node >= N) return;
  float ad = adst[node];
  float acc = 0.f;
  int e0 = offs[node], e1 = offs[node+1];
  for(int e = e0 + lane; e < e1; e += 64){
    float w = expf(lrelu(asrc[csr[e]] + ad));
    acc += w;
    wvE[e] = w;
  }
  #pragma unroll
  for(int d = 32; d >= 1; d >>= 1) acc += __shfl_xor(acc, d, 64);
  float ws = expf(lrelu(asrc[node] + ad));
  if(lane == 0){
    rdenN[node] = 1.0f/(acc + ws);
    wvS[node] = ws;
  }
}

// ---------------- GAT1 aggregation: wave/node, 2 edges per iteration ----------------
__global__ void k_agg_gat1v(const unsigned short* __restrict__ h1,
                            const float* __restrict__ wvE, const float* __restrict__ rdenN,
                            const float* __restrict__ wvS,
                            const int* __restrict__ offs, const int* __restrict__ csr,
                            const float* __restrict__ bias, unsigned short* __restrict__ out, int N){
  int node = blockIdx.x*4 + (threadIdx.x >> 6);
  int lane = threadIdx.x & 63;
  if(node >= N) return;
  int half = lane >> 5, subl = lane & 31;
  int head = subl >> 3;                     // channels subl*8..subl*8+7 all in this head
  float num[8];
  #pragma unroll
  for(int j = 0; j < 8; j++) num[j] = 0.f;
  int e0 = offs[node], deg = offs[node+1] - e0;
  for(int i = half; i <= deg; i += 2){      // i==0 is the self loop
    int s; float a;
    if(i == 0){ s = node; a = wvS[node*4 + head]; }
    else { int e = e0 + i - 1; s = csr[e]; a = wvE[(size_t)e*4 + head]; }
    bf16x8 u = *(const bf16x8*)&h1[(size_t)s*256 + subl*8];
    #pragma unroll
    for(int j = 0; j < 8; j++) num[j] += a*bf2f((unsigned short)u[j]);
  }
  #pragma unroll
  for(int j = 0; j < 8; j++) num[j] += __shfl_xor(num[j], 32, 64);
  if(half == 0){
    float rd = rdenN[node*4 + head];
    float4 bA = *(const float4*)&bias[subl*8];
    float4 bB = *(const float4*)&bias[subl*8 + 4];
    float b[8] = {bA.x, bA.y, bA.z, bA.w, bB.x, bB.y, bB.z, bB.w};
    bf16x8 o;
    #pragma unroll
    for(int j = 0; j < 8; j++) o[j] = (short)f2bf(elu1(num[j]*rd + b[j]));
    *(bf16x8*)&out[(size_t)node*256 + subl*8] = o;
  }
}

// ---------------- fused layer-1 aggregation: GCN (BN+relu) + SAGE (relu+L2norm) ----------------
__global__ void k_agg_l1(const unsigned short* __restrict__ a0, const unsigned short* __restrict__ p1,
                         const unsigned short* __restrict__ q1,
                         const float* __restrict__ dis, const float* __restrict__ invc,
                         const int* __restrict__ offs, const int* __restrict__ csr,
                         const float* __restrict__ gcn_b1, const float* __restrict__ gamma,
                         const float* __restrict__ beta, const float* __restrict__ sage_bl1,
                         unsigned short* __restrict__ a1, unsigned short* __restrict__ s1, int N){
  int node = blockIdx.x*16 + (threadIdx.x >> 4);
  int l = threadIdx.x & 15;
  if(node >= N) return;
  float dc = dis[node];
  float4 g;
  {
    float4 v = bfu4(*(const ushort4*)&a0[(size_t)node*64 + l*4]);
    g.x = dc*v.x; g.y = dc*v.y; g.z = dc*v.z; g.w = dc*v.w;
  }
  float4 sg; sg.x = sg.y = sg.z = sg.w = 0.f;
  int e0 = offs[node], e1 = offs[node+1];
  for(int e = e0; e < e1; e++){
    int s = csr[e];
    float ds = dis[s];
    float4 va = bfu4(*(const ushort4*)&a0[(size_t)s*64 + l*4]);
    float4 vp = bfu4(*(const ushort4*)&p1[(size_t)s*64 + l*4]);
    g.x += ds*va.x; g.y += ds*va.y; g.z += ds*va.z; g.w += ds*va.w;
    sg.x += vp.x; sg.y += vp.y; sg.z += vp.z; sg.w += vp.w;
  }
  // GCN: val = dc*g + b, BN, relu -> bf16
  {
    const float sc = rsqrtf(1.0f + 1e-5f);
    float4 b = *(const float4*)&gcn_b1[l*4];
    float4 gm = *(const float4*)&gamma[l*4];
    float4 be = *(const float4*)&beta[l*4];
    ushort4 o;
    o.x = f2bf(fmaxf((dc*g.x + b.x)*(gm.x*sc) + be.x, 0.f));
    o.y = f2bf(fmaxf((dc*g.y + b.y)*(gm.y*sc) + be.y, 0.f));
    o.z = f2bf(fmaxf((dc*g.z + b.z)*(gm.z*sc) + be.z, 0.f));
    o.w = f2bf(fmaxf((dc*g.w + b.w)*(gm.w*sc) + be.w, 0.f));
    *(ushort4*)&a1[(size_t)node*64 + l*4] = o;
  }
  // SAGE: val = mean + b + q, L2-normalize, relu -> bf16
  {
    float ic = invc[node];
    float4 b = *(const float4*)&sage_bl1[l*4];
    float4 qv = bfu4(*(const ushort4*)&q1[(size_t)node*64 + l*4]);
    float4 val;
    val.x = sg.x*ic + b.x + qv.x; val.y = sg.y*ic + b.y + qv.y;
    val.z = sg.z*ic + b.z + qv.z; val.w = sg.w*ic + b.w + qv.w;
    float n2 = val.x*val.x + val.y*val.y + val.z*val.z + val.w*val.w;
    #pragma unroll
    for(int d = 8; d >= 1; d >>= 1) n2 += __shfl_xor(n2, d, 64);
    float inv = 1.0f / fmaxf(sqrtf(n2), 1e-12f);
    ushort4 o;
    o.x = f2bf(fmaxf(val.x*inv, 0.f)); o.y = f2bf(fmaxf(val.y*inv, 0.f));
    o.z = f2bf(fmaxf(val.z*inv, 0.f)); o.w = f2bf(fmaxf(val.w*inv, 0.f));
    *(ushort4*)&s1[(size_t)node*64 + l*4] = o;
  }
}

// ---------------- fused final aggregation: GCN2 + GAT2 + SAGE2 + gate combine ----------------
__global__ void k_agg_final(const unsigned short* __restrict__ a2, const unsigned short* __restrict__ h2,
                            const unsigned short* __restrict__ p2, const unsigned short* __restrict__ q2,
                            const float* __restrict__ dis, const float* __restrict__ invc,
                            const float* __restrict__ wvE, const float* __restrict__ rdenN,
                            const float* __restrict__ wvS,
                            const int* __restrict__ offs, const int* __restrict__ csr,
                            const float* __restrict__ gcn_b2, const float* __restrict__ gat_b2,
                            const float* __restrict__ sage_bl2, const float* __restrict__ gatew,
                            float* __restrict__ out, int N){
  int node = blockIdx.x*16 + (threadIdx.x >> 4);
  int l = threadIdx.x & 15;
  if(node >= N) return;
  float dc = dis[node];
  float4 g, t;
  {
    float4 v = bfu4(*(const ushort4*)&a2[(size_t)node*64 + l*4]);
    g.x = dc*v.x; g.y = dc*v.y; g.z = dc*v.z; g.w = dc*v.w;
    float a = wvS[node];
    float4 hv = bfu4(*(const ushort4*)&h2[(size_t)node*64 + l*4]);
    t.x = a*hv.x; t.y = a*hv.y; t.z = a*hv.z; t.w = a*hv.w;
  }
  float4 sgv; sgv.x = sgv.y = sgv.z = sgv.w = 0.f;
  int e0 = offs[node], e1 = offs[node+1];
  for(int e = e0; e < e1; e++){
    int s = csr[e];
    float ds = dis[s];
    float a = wvE[e];
    float4 va = bfu4(*(const ushort4*)&a2[(size_t)s*64 + l*4]);
    float4 vh = bfu4(*(const ushort4*)&h2[(size_t)s*64 + l*4]);
    float4 vp = bfu4(*(const ushort4*)&p2[(size_t)s*64 + l*4]);
    g.x += ds*va.x; g.y += ds*va.y; g.z += ds*va.z; g.w += ds*va.w;
    t.x += a*vh.x; t.y += a*vh.y; t.z += a*vh.z; t.w += a*vh.w;
    sgv.x += vp.x; sgv.y += vp.y; sgv.z += vp.z; sgv.w += vp.w;
  }
  float g0 = gatew[0], g1 = gatew[1], g2w = gatew[2];
  // GCN2
  float4 bg = *(const float4*)&gcn_b2[l*4];
  float4 ogcn;
  ogcn.x = dc*g.x + bg.x; ogcn.y = dc*g.y + bg.y; ogcn.z = dc*g.z + bg.z; ogcn.w = dc*g.w + bg.w;
  // GAT2
  float rd = rdenN[node];
  float4 bt = *(const float4*)&gat_b2[l*4];
  float4 ogat;
  ogat.x = t.x*rd + bt.x; ogat.y = t.y*rd + bt.y; ogat.z = t.z*rd + bt.z; ogat.w = t.w*rd + bt.w;
  // SAGE2
  float ic = invc[node];
  float4 bs = *(const float4*)&sage_bl2[l*4];
  float4 qv = bfu4(*(const ushort4*)&q2[(size_t)node*64 + l*4]);
  float4 val;
  val.x = sgv.x*ic + bs.x + qv.x; val.y = sgv.y*ic + bs.y + qv.y;
  val.z = sgv.z*ic + bs.z + qv.z; val.w = sgv.w*ic + bs.w + qv.w;
  float n2 = val.x*val.x + val.y*val.y + val.z*val.z + val.w*val.w;
  #pragma unroll
  for(int d = 8; d >= 1; d >>= 1) n2 += __shfl_xor(n2, d, 64);
  float inv = 1.0f / fmaxf(sqrtf(n2), 1e-12f);
  float4 o;
  o.x = g0*ogcn.x + g1*ogat.x + g2w*val.x*inv;
  o.y = g0*ogcn.y + g1*ogat.y + g2w*val.y*inv;
  o.z = g0*ogcn.z + g1*ogat.z + g2w*val.z*inv;
  o.w = g0*ogcn.w + g1*ogat.w + g2w*val.w*inv;
  *(float4*)&out[(size_t)node*64 + l*4] = o;
}

// ---------------- host ----------------
extern "C" void kernel_launch(void* const* d_in, const int* in_sizes, int n_in,
                              void* d_out, int out_size, void* d_ws, size_t ws_size,
                              hipStream_t stream){
  const float* x        = (const float*)d_in[0];
  const int*   ei       = (const int*)d_in[1];
  const int*   row      = ei;
  const int*   col      = ei + NE;
  const float* gate_w1  = (const float*)d_in[2];
  const float* gate_b1  = (const float*)d_in[3];
  const float* gate_w2  = (const float*)d_in[4];
  const float* gate_b2  = (const float*)d_in[5];
  const float* gcn_w1   = (const float*)d_in[6];
  const float* gcn_b1   = (const float*)d_in[7];
  const float* bn_gamma = (const float*)d_in[8];
  const float* bn_beta  = (const float*)d_in[9];
  const float* gcn_w2   = (const float*)d_in[10];
  const float* gcn_b2   = (const float*)d_in[11];
  const float* gat_w1   = (const float*)d_in[12];
  const float* gat_as1  = (const float*)d_in[13];
  const float* gat_ad1  = (const float*)d_in[14];
  const float* gat_b1   = (const float*)d_in[15];
  const float* gat_w2   = (const float*)d_in[16];
  const float* gat_as2  = (const float*)d_in[17];
  const float* gat_ad2  = (const float*)d_in[18];
  const float* gat_b2   = (const float*)d_in[19];
  const float* sage_wl1 = (const float*)d_in[20];
  const float* sage_bl1 = (const float*)d_in[21];
  const float* sage_wr1 = (const float*)d_in[22];
  const float* sage_wl2 = (const float*)d_in[23];
  const float* sage_bl2 = (const float*)d_in[24];
  const float* sage_wr2 = (const float*)d_in[25];
  float* out = (float*)d_out;

  char* wp = (char*)d_ws;
  auto alloc = [&](size_t bytes)->char*{ char* p = wp; wp += (bytes + 255) & ~(size_t)255; return p; };
  int*   cnt    = (int*)  alloc((size_t)NN*4);
  int*   offs   = (int*)  alloc((size_t)(NN+1)*4);
  int*   cursor = (int*)  alloc((size_t)NN*4);
  int*   csr    = (int*)  alloc((size_t)NE*4);
  float* dis    = (float*)alloc((size_t)NN*4);
  float* invc   = (float*)alloc((size_t)NN*4);
  float* gsum   = (float*)alloc(64*4);
  float* gatew  = (float*)alloc(16);
  float* asrc1  = (float*)alloc((size_t)NN*4*4);
  float* adst1  = (float*)alloc((size_t)NN*4*4);
  float* asrc2  = (float*)alloc((size_t)NN*4);
  float* adst2  = (float*)alloc((size_t)NN*4);
  float* wvE1   = (float*)alloc((size_t)NE*4*4);
  float* rden1  = (float*)alloc((size_t)NN*4*4);
  float* wvS1   = (float*)alloc((size_t)NN*4*4);
  float* wvE2   = (float*)alloc((size_t)NE*4);
  float* rden2  = (float*)alloc((size_t)NN*4);
  float* wvS2   = (float*)alloc((size_t)NN*4);
  // bf16 activation buffers
  unsigned short* xb  = (unsigned short*)alloc((size_t)NN*64*2);
  unsigned short* a0  = (unsigned short*)alloc((size_t)NN*64*2);  // also a2 later
  unsigned short* a1  = (unsigned short*)alloc((size_t)NN*64*2);
  unsigned short* p1  = (unsigned short*)alloc((size_t)NN*64*2);  // also p2
  unsigned short* q1  = (unsigned short*)alloc((size_t)NN*64*2);  // also q2
  unsigned short* s1  = (unsigned short*)alloc((size_t)NN*64*2);
  unsigned short* h1  = (unsigned short*)alloc((size_t)NN*256*2); // also h2
  unsigned short* gath= (unsigned short*)alloc((size_t)NN*256*2);
  unsigned short* a2 = a0;
  unsigned short* p2 = p1;
  unsigned short* q2 = q1;
  unsigned short* h2 = h1;

  hipMemsetAsync(cnt,    0, (size_t)NN*4, stream);
  hipMemsetAsync(cursor, 0, (size_t)NN*4, stream);
  hipMemsetAsync(gsum,   0, 64*4, stream);

  k_count<<<(NE+255)/256, 256, 0, stream>>>(col, cnt, NE);
  k_scan <<<1, 1024, 0, stream>>>(cnt, offs, dis, invc, NN, NE);
  k_fill <<<(NE+255)/256, 256, 0, stream>>>(row, col, offs, cursor, csr, NE);
  k_castsum<<<256, 256, 0, stream>>>(x, xb, gsum, NN);
  k_gate  <<<1, 64, 0, stream>>>(gsum, gate_w1, gate_b1, gate_w2, gate_b2, gatew);

  const int gN  = (NN + 63) / 64;   // 782
  const int g4  = NN / 4;           // 12500
  const int g16 = NN / 16;          // 3125

  // ---- layer-1 matmuls ----
  {
    MMP p = {};
    p.A[0]=xb; p.A[1]=xb; p.A[2]=xb;
    p.W[0]=gcn_w1; p.W[1]=sage_wl1; p.W[2]=sage_wr1;
    p.C[0]=a0; p.C[1]=p1; p.C[2]=q1;
    p.K=64; p.ldw=64; p.ldc=64; p.slab=0; p.N=NN;
    k_mm_mfma<<<dim3(gN,3), 256, 0, stream>>>(p);
  }
  {
    MMP p = {};
    p.A[0]=xb; p.W[0]=gat_w1; p.C[0]=h1;
    p.K=64; p.ldw=256; p.ldc=256; p.slab=1; p.N=NN;
    k_mm_mfma<<<dim3(gN,4), 256, 0, stream>>>(p);
  }

  // ---- GAT layer 1 ----
  k_attdot4<<<g4, 256, 0, stream>>>(h1, gat_as1, gat_ad1, asrc1, adst1, NN);
  k_edgew1<<<g4, 256, 0, stream>>>(asrc1, adst1, offs, csr, wvE1, rden1, wvS1, NN);
  k_agg_gat1v<<<g4, 256, 0, stream>>>(h1, wvE1, rden1, wvS1, offs, csr, gat_b1, gath, NN);

  // ---- layer-1 aggregations (GCN + SAGE fused) ----
  k_agg_l1<<<g16, 256, 0, stream>>>(a0, p1, q1, dis, invc, offs, csr,
                                    gcn_b1, bn_gamma, bn_beta, sage_bl1, a1, s1, NN);

  // ---- GAT layer 2 matmul (K=256) ----
  {
    MMP p = {};
    p.A[0]=gath; p.W[0]=gat_w2; p.C[0]=h2;
    p.K=256; p.ldw=64; p.ldc=64; p.slab=1; p.N=NN;
    k_mm_mfma<<<dim3(gN,1), 256, 0, stream>>>(p);
  }
  k_attdot1<<<g4, 256, 0, stream>>>(h2, gat_as2, gat_ad2, asrc2, adst2, NN);
  k_edgew2<<<g4, 256, 0, stream>>>(asrc2, adst2, offs, csr, wvE2, rden2, wvS2, NN);

  // ---- layer-2 matmuls (GCN + SAGE fused dispatch) ----
  {
    MMP p = {};
    p.A[0]=a1; p.A[1]=s1; p.A[2]=s1;
    p.W[0]=gcn_w2; p.W[1]=sage_wl2; p.W[2]=sage_wr2;
    p.C[0]=a2; p.C[1]=p2; p.C[2]=q2;
    p.K=64; p.ldw=64; p.ldc=64; p.slab=0; p.N=NN;
    k_mm_mfma<<<dim3(gN,3), 256, 0, stream>>>(p);
  }

  // ---- fused final aggregation ----
  k_agg_final<<<g16, 256, 0, stream>>>(a2, h2, p2, q2, dis, invc, wvE2, rden2, wvS2,
                                       offs, csr, gcn_b2, gat_b2, sage_bl2, gatew, out, NN);
}

// Round 4
// 421.664 us; speedup vs baseline: 1.7369x; 1.0865x over previous
//
#include <hip/hip_runtime.h>
#include <hip/hip_bf16.h>
#include <math.h>

#define NN 50000
#define NE 400000

typedef __attribute__((ext_vector_type(8))) short bf16x8;
typedef __attribute__((ext_vector_type(4))) float f32x4;

// ---------------- helpers ----------------
__device__ __forceinline__ float lrelu(float v){ return v > 0.f ? v : 0.2f*v; }
__device__ __forceinline__ float elu1(float v){ return v > 0.f ? v : expm1f(v); }
__device__ __forceinline__ float bf2f(unsigned short u){ return __uint_as_float(((unsigned int)u) << 16); }
__device__ __forceinline__ unsigned short f2bf(float f){
  __hip_bfloat16 h = __float2bfloat16(f);
  return *(unsigned short*)&h;
}
__device__ __forceinline__ float4 bfu4(ushort4 u){
  float4 r; r.x = bf2f(u.x); r.y = bf2f(u.y); r.z = bf2f(u.z); r.w = bf2f(u.w); return r;
}

// ---------------- CSR build ----------------
__global__ void k_count(const int* __restrict__ col, int* __restrict__ cnt, int E){
  int e = blockIdx.x*blockDim.x + threadIdx.x;
  if(e < E) atomicAdd(&cnt[col[e]], 1);
}

// parallel range allocation: wave-level scan + one atomicAdd per wave.
// CSR ranges land in arbitrary (atomic) order — contiguity per node is all we need.
__global__ void k_alloc(const int* __restrict__ cnt, int* __restrict__ offs,
                        float* __restrict__ dis, float* __restrict__ invc,
                        int* __restrict__ total, int N){
  int i = blockIdx.x*blockDim.x + threadIdx.x;
  int lane = threadIdx.x & 63;
  int v = (i < N) ? cnt[i] : 0;
  int x = v;
  #pragma unroll
  for(int d = 1; d < 64; d <<= 1){ int t = __shfl_up(x, d, 64); if(lane >= d) x += t; }
  int base = 0;
  if(lane == 63 && x > 0) base = atomicAdd(total, x);
  base = __shfl(base, 63, 64);
  if(i < N){
    offs[i] = base + x - v;
    dis[i]  = 1.0f / sqrtf((float)(v + 1));
    invc[i] = 1.0f / fmaxf((float)v, 1.0f);
  }
}

__global__ void k_fill(const int* __restrict__ row, const int* __restrict__ col,
                       const int* __restrict__ offs, int* __restrict__ cursor,
                       int* __restrict__ csr, int E){
  int e = blockIdx.x*blockDim.x + threadIdx.x;
  if(e < E){
    int c = col[e];
    int pos = offs[c] + atomicAdd(&cursor[c], 1);
    csr[pos] = row[e];
  }
}

// ---------------- cast x -> bf16 + column sums for gate ----------------
__global__ void k_castsum(const float* __restrict__ x, unsigned short* __restrict__ xb,
                          float* __restrict__ gsum, int N){
  __shared__ float part[4][64];
  int lane = threadIdx.x & 63, w = threadIdx.x >> 6;
  float s = 0.f;
  for(int r = blockIdx.x*4 + w; r < N; r += gridDim.x*4){
    float v = x[(size_t)r*64 + lane];
    xb[(size_t)r*64 + lane] = f2bf(v);
    s += v;
  }
  part[w][lane] = s;
  __syncthreads();
  if(w == 0) atomicAdd(&gsum[lane], part[0][lane]+part[1][lane]+part[2][lane]+part[3][lane]);
}

__global__ void k_gate(const float* __restrict__ gsum,
                       const float* __restrict__ w1, const float* __restrict__ b1,
                       const float* __restrict__ w2, const float* __restrict__ b2,
                       float* __restrict__ gatew){
  __shared__ float g[64]; __shared__ float hid[64]; __shared__ float lg[3];
  int t = threadIdx.x;
  g[t] = gsum[t] * (1.0f/(float)NN);
  __syncthreads();
  float acc = b1[t];
  for(int i = 0; i < 64; i++) acc += g[i]*w1[i*64 + t];
  hid[t] = fmaxf(acc, 0.f);
  __syncthreads();
  if(t < 3){
    float a = b2[t];
    for(int j = 0; j < 64; j++) a += hid[j]*w2[j*3 + t];
    lg[t] = a;
  }
  __syncthreads();
  if(t == 0){
    float m = fmaxf(lg[0], fmaxf(lg[1], lg[2]));
    float e0 = expf(lg[0]-m), e1 = expf(lg[1]-m), e2 = expf(lg[2]-m);
    float s = e0 + e1 + e2;
    gatew[0] = e0/s; gatew[1] = e1/s; gatew[2] = e2/s;
  }
}

// ---------------- MFMA bf16 matmul: C[N,?] = A[N,K] @ W[K, 64-col slab] ----------------
struct MMP {
  const unsigned short* A[4];
  const float* W[4];
  unsigned short* C[4];
  int K, ldw, ldc, slab, N;
};

__global__ __launch_bounds__(256) void k_mm_mfma(MMP p){
  __shared__ unsigned short Wt[64*264];   // transposed W slab, pitch K+8 (max K=256)
  int by = blockIdx.y;
  const unsigned short* A; const float* W; unsigned short* C; int col0;
  if(p.slab){ A = p.A[0]; W = p.W[0]; C = p.C[0]; col0 = by*64; }
  else      { A = p.A[by]; W = p.W[by]; C = p.C[by]; col0 = 0; }
  const int K = p.K, ldw = p.ldw, ldc = p.ldc, N = p.N;
  const int pitch = K + 8;
  int tid = threadIdx.x;
  {
    int n = tid & 63;
    for(int k = tid >> 6; k < K; k += 4)
      Wt[n*pitch + k] = f2bf(W[(size_t)k*ldw + col0 + n]);
  }
  __syncthreads();
  int w = tid >> 6, lane = tid & 63, quad = lane >> 4, m16 = lane & 15;
  int rowa = blockIdx.x*64 + w*16 + m16;
  int rowc = rowa < N ? rowa : N - 1;
  f32x4 acc[4];
  #pragma unroll
  for(int t = 0; t < 4; t++){ acc[t][0]=0.f; acc[t][1]=0.f; acc[t][2]=0.f; acc[t][3]=0.f; }
  for(int kc = 0; kc < K; kc += 64){
    bf16x8 a0 = *(const bf16x8*)&A[(size_t)rowc*K + kc + quad*8];
    bf16x8 a1 = *(const bf16x8*)&A[(size_t)rowc*K + kc + 32 + quad*8];
    #pragma unroll
    for(int t = 0; t < 4; t++){
      bf16x8 b0 = *(const bf16x8*)&Wt[(t*16 + m16)*pitch + kc + quad*8];
      bf16x8 b1 = *(const bf16x8*)&Wt[(t*16 + m16)*pitch + kc + 32 + quad*8];
      acc[t] = __builtin_amdgcn_mfma_f32_16x16x32_bf16(a0, b0, acc[t], 0, 0, 0);
      acc[t] = __builtin_amdgcn_mfma_f32_16x16x32_bf16(a1, b1, acc[t], 0, 0, 0);
    }
  }
  int robase = blockIdx.x*64 + w*16 + quad*4;
  #pragma unroll
  for(int t = 0; t < 4; t++){
    #pragma unroll
    for(int r = 0; r < 4; r++){
      int ro = robase + r;
      if(ro < N) C[(size_t)ro*ldc + col0 + t*16 + m16] = f2bf(acc[t][r]);
    }
  }
}

// ---------------- attention per-node dots (bf16 h) ----------------
__global__ void k_attdot4(const unsigned short* __restrict__ h,
                          const float* __restrict__ att_src, const float* __restrict__ att_dst,
                          float* __restrict__ asrc, float* __restrict__ adst, int N){
  int node = blockIdx.x*4 + (threadIdx.x >> 6);
  int lane = threadIdx.x & 63;
  if(node >= N) return;
  #pragma unroll
  for(int hh = 0; hh < 4; hh++){
    float v = bf2f(h[(size_t)node*256 + hh*64 + lane]);
    float vs = v*att_src[hh*64 + lane];
    float vd = v*att_dst[hh*64 + lane];
    #pragma unroll
    for(int d = 32; d >= 1; d >>= 1){ vs += __shfl_xor(vs, d, 64); vd += __shfl_xor(vd, d, 64); }
    if(lane == 0){ asrc[node*4 + hh] = vs; adst[node*4 + hh] = vd; }
  }
}

__global__ void k_attdot1(const unsigned short* __restrict__ h,
                          const float* __restrict__ att_src, const float* __restrict__ att_dst,
                          float* __restrict__ asrc, float* __restrict__ adst, int N){
  int node = blockIdx.x*4 + (threadIdx.x >> 6);
  int lane = threadIdx.x & 63;
  if(node >= N) return;
  float v = bf2f(h[(size_t)node*64 + lane]);
  float vs = v*att_src[lane];
  float vd = v*att_dst[lane];
  #pragma unroll
  for(int d = 32; d >= 1; d >>= 1){ vs += __shfl_xor(vs, d, 64); vd += __shfl_xor(vd, d, 64); }
  if(lane == 0){ asrc[node] = vs; adst[node] = vd; }
}

// ---------------- GAT edge weights ----------------
__global__ void k_edgew1(const float* __restrict__ asrc, const float* __restrict__ adst,
                         const int* __restrict__ offs, const int* __restrict__ cnt,
                         const int* __restrict__ csr,
                         float* __restrict__ wvE, float* __restrict__ rdenN,
                         float* __restrict__ wvS, int N){
  int node = blockIdx.x*4 + (threadIdx.x >> 6);
  int lane = threadIdx.x & 63;
  if(node >= N) return;
  float4 ad = *(const float4*)&adst[node*4];
  float a0 = 0.f, a1 = 0.f, a2 = 0.f, a3 = 0.f;
  int e0 = offs[node], e1 = e0 + cnt[node];
  for(int e = e0 + lane; e < e1; e += 64){
    int s = csr[e];
    float4 as = *(const float4*)&asrc[s*4];
    float4 w;
    w.x = expf(lrelu(as.x + ad.x));
    w.y = expf(lrelu(as.y + ad.y));
    w.z = expf(lrelu(as.z + ad.z));
    w.w = expf(lrelu(as.w + ad.w));
    a0 += w.x; a1 += w.y; a2 += w.z; a3 += w.w;
    *(float4*)&wvE[(size_t)e*4] = w;
  }
  #pragma unroll
  for(int d = 32; d >= 1; d >>= 1){
    a0 += __shfl_xor(a0, d, 64); a1 += __shfl_xor(a1, d, 64);
    a2 += __shfl_xor(a2, d, 64); a3 += __shfl_xor(a3, d, 64);
  }
  float4 asl = *(const float4*)&asrc[node*4];
  float4 ws;
  ws.x = expf(lrelu(asl.x + ad.x));
  ws.y = expf(lrelu(asl.y + ad.y));
  ws.z = expf(lrelu(asl.z + ad.z));
  ws.w = expf(lrelu(asl.w + ad.w));
  if(lane == 0){
    float4 rd;
    rd.x = 1.0f/(a0 + ws.x); rd.y = 1.0f/(a1 + ws.y);
    rd.z = 1.0f/(a2 + ws.z); rd.w = 1.0f/(a3 + ws.w);
    *(float4*)&rdenN[node*4] = rd;
    *(float4*)&wvS[node*4] = ws;
  }
}

__global__ void k_edgew2(const float* __restrict__ asrc, const float* __restrict__ adst,
                         const int* __restrict__ offs, const int* __restrict__ cnt,
                         const int* __restrict__ csr,
                         float* __restrict__ wvE, float* __restrict__ rdenN,
                         float* __restrict__ wvS, int N){
  int node = blockIdx.x*4 + (threadIdx.x >> 6);
  int lane = threadIdx.x & 63;
  if(node >= N) return;
  float ad = adst[node];
  float acc = 0.f;
  int e0 = offs[node], e1 = e0 + cnt[node];
  for(int e = e0 + lane; e < e1; e += 64){
    float w = expf(lrelu(asrc[csr[e]] + ad));
    acc += w;
    wvE[e] = w;
  }
  #pragma unroll
  for(int d = 32; d >= 1; d >>= 1) acc += __shfl_xor(acc, d, 64);
  float ws = expf(lrelu(asrc[node] + ad));
  if(lane == 0){
    rdenN[node] = 1.0f/(acc + ws);
    wvS[node] = ws;
  }
}

// ---------------- GAT1 aggregation: wave/node, 2 edges per iteration ----------------
__global__ void k_agg_gat1v(const unsigned short* __restrict__ h1,
                            const float* __restrict__ wvE, const float* __restrict__ rdenN,
                            const float* __restrict__ wvS,
                            const int* __restrict__ offs, const int* __restrict__ cnt,
                            const int* __restrict__ csr,
                            const float* __restrict__ bias, unsigned short* __restrict__ out, int N){
  int node = blockIdx.x*4 + (threadIdx.x >> 6);
  int lane = threadIdx.x & 63;
  if(node >= N) return;
  int half = lane >> 5, subl = lane & 31;
  int head = subl >> 3;                     // channels subl*8..subl*8+7 all in this head
  float num[8];
  #pragma unroll
  for(int j = 0; j < 8; j++) num[j] = 0.f;
  int e0 = offs[node], deg = cnt[node];
  for(int i = half; i <= deg; i += 2){      // i==0 is the self loop
    int s; float a;
    if(i == 0){ s = node; a = wvS[node*4 + head]; }
    else { int e = e0 + i - 1; s = csr[e]; a = wvE[(size_t)e*4 + head]; }
    bf16x8 u = *(const bf16x8*)&h1[(size_t)s*256 + subl*8];
    #pragma unroll
    for(int j = 0; j < 8; j++) num[j] += a*bf2f((unsigned short)u[j]);
  }
  #pragma unroll
  for(int j = 0; j < 8; j++) num[j] += __shfl_xor(num[j], 32, 64);
  if(half == 0){
    float rd = rdenN[node*4 + head];
    float4 bA = *(const float4*)&bias[subl*8];
    float4 bB = *(const float4*)&bias[subl*8 + 4];
    float b[8] = {bA.x, bA.y, bA.z, bA.w, bB.x, bB.y, bB.z, bB.w};
    bf16x8 o;
    #pragma unroll
    for(int j = 0; j < 8; j++) o[j] = (short)f2bf(elu1(num[j]*rd + b[j]));
    *(bf16x8*)&out[(size_t)node*256 + subl*8] = o;
  }
}

// ---------------- fused layer-1 aggregation: GCN (BN+relu) + SAGE (relu+L2norm) ----------------
__global__ void k_agg_l1(const unsigned short* __restrict__ a0, const unsigned short* __restrict__ p1,
                         const unsigned short* __restrict__ q1,
                         const float* __restrict__ dis, const float* __restrict__ invc,
                         const int* __restrict__ offs, const int* __restrict__ cnt,
                         const int* __restrict__ csr,
                         const float* __restrict__ gcn_b1, const float* __restrict__ gamma,
                         const float* __restrict__ beta, const float* __restrict__ sage_bl1,
                         unsigned short* __restrict__ a1, unsigned short* __restrict__ s1, int N){
  int node = blockIdx.x*16 + (threadIdx.x >> 4);
  int l = threadIdx.x & 15;
  if(node >= N) return;
  float dc = dis[node];
  float4 g;
  {
    float4 v = bfu4(*(const ushort4*)&a0[(size_t)node*64 + l*4]);
    g.x = dc*v.x; g.y = dc*v.y; g.z = dc*v.z; g.w = dc*v.w;
  }
  float4 sg; sg.x = sg.y = sg.z = sg.w = 0.f;
  int e0 = offs[node], e1 = e0 + cnt[node];
  for(int e = e0; e < e1; e++){
    int s = csr[e];
    float ds = dis[s];
    float4 va = bfu4(*(const ushort4*)&a0[(size_t)s*64 + l*4]);
    float4 vp = bfu4(*(const ushort4*)&p1[(size_t)s*64 + l*4]);
    g.x += ds*va.x; g.y += ds*va.y; g.z += ds*va.z; g.w += ds*va.w;
    sg.x += vp.x; sg.y += vp.y; sg.z += vp.z; sg.w += vp.w;
  }
  // GCN: val = dc*g + b, BN, relu -> bf16
  {
    const float sc = rsqrtf(1.0f + 1e-5f);
    float4 b = *(const float4*)&gcn_b1[l*4];
    float4 gm = *(const float4*)&gamma[l*4];
    float4 be = *(const float4*)&beta[l*4];
    ushort4 o;
    o.x = f2bf(fmaxf((dc*g.x + b.x)*(gm.x*sc) + be.x, 0.f));
    o.y = f2bf(fmaxf((dc*g.y + b.y)*(gm.y*sc) + be.y, 0.f));
    o.z = f2bf(fmaxf((dc*g.z + b.z)*(gm.z*sc) + be.z, 0.f));
    o.w = f2bf(fmaxf((dc*g.w + b.w)*(gm.w*sc) + be.w, 0.f));
    *(ushort4*)&a1[(size_t)node*64 + l*4] = o;
  }
  // SAGE: val = mean + b + q, L2-normalize, relu -> bf16
  {
    float ic = invc[node];
    float4 b = *(const float4*)&sage_bl1[l*4];
    float4 qv = bfu4(*(const ushort4*)&q1[(size_t)node*64 + l*4]);
    float4 val;
    val.x = sg.x*ic + b.x + qv.x; val.y = sg.y*ic + b.y + qv.y;
    val.z = sg.z*ic + b.z + qv.z; val.w = sg.w*ic + b.w + qv.w;
    float n2 = val.x*val.x + val.y*val.y + val.z*val.z + val.w*val.w;
    #pragma unroll
    for(int d = 8; d >= 1; d >>= 1) n2 += __shfl_xor(n2, d, 64);
    float inv = 1.0f / fmaxf(sqrtf(n2), 1e-12f);
    ushort4 o;
    o.x = f2bf(fmaxf(val.x*inv, 0.f)); o.y = f2bf(fmaxf(val.y*inv, 0.f));
    o.z = f2bf(fmaxf(val.z*inv, 0.f)); o.w = f2bf(fmaxf(val.w*inv, 0.f));
    *(ushort4*)&s1[(size_t)node*64 + l*4] = o;
  }
}

// ---------------- fused final aggregation: GCN2 + GAT2 + SAGE2 + gate combine ----------------
__global__ void k_agg_final(const unsigned short* __restrict__ a2, const unsigned short* __restrict__ h2,
                            const unsigned short* __restrict__ p2, const unsigned short* __restrict__ q2,
                            const float* __restrict__ dis, const float* __restrict__ invc,
                            const float* __restrict__ wvE, const float* __restrict__ rdenN,
                            const float* __restrict__ wvS,
                            const int* __restrict__ offs, const int* __restrict__ cnt,
                            const int* __restrict__ csr,
                            const float* __restrict__ gcn_b2, const float* __restrict__ gat_b2,
                            const float* __restrict__ sage_bl2, const float* __restrict__ gatew,
                            float* __restrict__ out, int N){
  int node = blockIdx.x*16 + (threadIdx.x >> 4);
  int l = threadIdx.x & 15;
  if(node >= N) return;
  float dc = dis[node];
  float4 g, t;
  {
    float4 v = bfu4(*(const ushort4*)&a2[(size_t)node*64 + l*4]);
    g.x = dc*v.x; g.y = dc*v.y; g.z = dc*v.z; g.w = dc*v.w;
    float a = wvS[node];
    float4 hv = bfu4(*(const ushort4*)&h2[(size_t)node*64 + l*4]);
    t.x = a*hv.x; t.y = a*hv.y; t.z = a*hv.z; t.w = a*hv.w;
  }
  float4 sgv; sgv.x = sgv.y = sgv.z = sgv.w = 0.f;
  int e0 = offs[node], e1 = e0 + cnt[node];
  for(int e = e0; e < e1; e++){
    int s = csr[e];
    float ds = dis[s];
    float a = wvE[e];
    float4 va = bfu4(*(const ushort4*)&a2[(size_t)s*64 + l*4]);
    float4 vh = bfu4(*(const ushort4*)&h2[(size_t)s*64 + l*4]);
    float4 vp = bfu4(*(const ushort4*)&p2[(size_t)s*64 + l*4]);
    g.x += ds*va.x; g.y += ds*va.y; g.z += ds*va.z; g.w += ds*va.w;
    t.x += a*vh.x; t.y += a*vh.y; t.z += a*vh.z; t.w += a*vh.w;
    sgv.x += vp.x; sgv.y += vp.y; sgv.z += vp.z; sgv.w += vp.w;
  }
  float g0 = gatew[0], g1 = gatew[1], g2w = gatew[2];
  float4 bg = *(const float4*)&gcn_b2[l*4];
  float4 ogcn;
  ogcn.x = dc*g.x + bg.x; ogcn.y = dc*g.y + bg.y; ogcn.z = dc*g.z + bg.z; ogcn.w = dc*g.w + bg.w;
  float rd = rdenN[node];
  float4 bt = *(const float4*)&gat_b2[l*4];
  float4 ogat;
  ogat.x = t.x*rd + bt.x; ogat.y = t.y*rd + bt.y; ogat.z = t.z*rd + bt.z; ogat.w = t.w*rd + bt.w;
  float ic = invc[node];
  float4 bs = *(const float4*)&sage_bl2[l*4];
  float4 qv = bfu4(*(const ushort4*)&q2[(size_t)node*64 + l*4]);
  float4 val;
  val.x = sgv.x*ic + bs.x + qv.x; val.y = sgv.y*ic + bs.y + qv.y;
  val.z = sgv.z*ic + bs.z + qv.z; val.w = sgv.w*ic + bs.w + qv.w;
  float n2 = val.x*val.x + val.y*val.y + val.z*val.z + val.w*val.w;
  #pragma unroll
  for(int d = 8; d >= 1; d >>= 1) n2 += __shfl_xor(n2, d, 64);
  float inv = 1.0f / fmaxf(sqrtf(n2), 1e-12f);
  float4 o;
  o.x = g0*ogcn.x + g1*ogat.x + g2w*val.x*inv;
  o.y = g0*ogcn.y + g1*ogat.y + g2w*val.y*inv;
  o.z = g0*ogcn.z + g1*ogat.z + g2w*val.z*inv;
  o.w = g0*ogcn.w + g1*ogat.w + g2w*val.w*inv;
  *(float4*)&out[(size_t)node*64 + l*4] = o;
}

// ---------------- host ----------------
extern "C" void kernel_launch(void* const* d_in, const int* in_sizes, int n_in,
                              void* d_out, int out_size, void* d_ws, size_t ws_size,
                              hipStream_t stream){
  const float* x        = (const float*)d_in[0];
  const int*   ei       = (const int*)d_in[1];
  const int*   row      = ei;
  const int*   col      = ei + NE;
  const float* gate_w1  = (const float*)d_in[2];
  const float* gate_b1  = (const float*)d_in[3];
  const float* gate_w2  = (const float*)d_in[4];
  const float* gate_b2  = (const float*)d_in[5];
  const float* gcn_w1   = (const float*)d_in[6];
  const float* gcn_b1   = (const float*)d_in[7];
  const float* bn_gamma = (const float*)d_in[8];
  const float* bn_beta  = (const float*)d_in[9];
  const float* gcn_w2   = (const float*)d_in[10];
  const float* gcn_b2   = (const float*)d_in[11];
  const float* gat_w1   = (const float*)d_in[12];
  const float* gat_as1  = (const float*)d_in[13];
  const float* gat_ad1  = (const float*)d_in[14];
  const float* gat_b1   = (const float*)d_in[15];
  const float* gat_w2   = (const float*)d_in[16];
  const float* gat_as2  = (const float*)d_in[17];
  const float* gat_ad2  = (const float*)d_in[18];
  const float* gat_b2   = (const float*)d_in[19];
  const float* sage_wl1 = (const float*)d_in[20];
  const float* sage_bl1 = (const float*)d_in[21];
  const float* sage_wr1 = (const float*)d_in[22];
  const float* sage_wl2 = (const float*)d_in[23];
  const float* sage_bl2 = (const float*)d_in[24];
  const float* sage_wr2 = (const float*)d_in[25];
  float* out = (float*)d_out;

  char* wp = (char*)d_ws;
  auto alloc = [&](size_t bytes)->char*{ char* p = wp; wp += (bytes + 255) & ~(size_t)255; return p; };
  // zero-init region: cnt, cursor, gsum, total (contiguous)
  int*   cnt    = (int*)  alloc((size_t)NN*4);
  int*   cursor = (int*)  alloc((size_t)NN*4);
  float* gsum   = (float*)alloc(64*4);
  int*   total  = (int*)  alloc(256);
  size_t zbytes = (size_t)(wp - (char*)cnt);
  int*   offs   = (int*)  alloc((size_t)NN*4);
  int*   csr    = (int*)  alloc((size_t)NE*4);
  float* dis    = (float*)alloc((size_t)NN*4);
  float* invc   = (float*)alloc((size_t)NN*4);
  float* gatew  = (float*)alloc(16);
  float* asrc1  = (float*)alloc((size_t)NN*4*4);
  float* adst1  = (float*)alloc((size_t)NN*4*4);
  float* asrc2  = (float*)alloc((size_t)NN*4);
  float* adst2  = (float*)alloc((size_t)NN*4);
  float* wvE1   = (float*)alloc((size_t)NE*4*4);
  float* rden1  = (float*)alloc((size_t)NN*4*4);
  float* wvS1   = (float*)alloc((size_t)NN*4*4);
  float* wvE2   = (float*)alloc((size_t)NE*4);
  float* rden2  = (float*)alloc((size_t)NN*4);
  float* wvS2   = (float*)alloc((size_t)NN*4);
  unsigned short* xb  = (unsigned short*)alloc((size_t)NN*64*2);
  unsigned short* a0  = (unsigned short*)alloc((size_t)NN*64*2);  // also a2
  unsigned short* a1  = (unsigned short*)alloc((size_t)NN*64*2);
  unsigned short* p1  = (unsigned short*)alloc((size_t)NN*64*2);  // also p2
  unsigned short* q1  = (unsigned short*)alloc((size_t)NN*64*2);  // also q2
  unsigned short* s1  = (unsigned short*)alloc((size_t)NN*64*2);
  unsigned short* h1  = (unsigned short*)alloc((size_t)NN*256*2); // also h2
  unsigned short* gath= (unsigned short*)alloc((size_t)NN*256*2);
  unsigned short* a2 = a0;
  unsigned short* p2 = p1;
  unsigned short* q2 = q1;
  unsigned short* h2 = h1;

  hipMemsetAsync(cnt, 0, zbytes, stream);

  const int gN  = (NN + 63) / 64;   // 782
  const int g4  = NN / 4;           // 12500
  const int g16 = NN / 16;          // 3125
  const int gA  = (NN + 255) / 256; // 196

  k_count<<<(NE+255)/256, 256, 0, stream>>>(col, cnt, NE);
  k_alloc<<<gA, 256, 0, stream>>>(cnt, offs, dis, invc, total, NN);
  k_fill <<<(NE+255)/256, 256, 0, stream>>>(row, col, offs, cursor, csr, NE);
  k_castsum<<<256, 256, 0, stream>>>(x, xb, gsum, NN);
  k_gate  <<<1, 64, 0, stream>>>(gsum, gate_w1, gate_b1, gate_w2, gate_b2, gatew);

  // ---- layer-1 matmuls ----
  {
    MMP p = {};
    p.A[0]=xb; p.A[1]=xb; p.A[2]=xb;
    p.W[0]=gcn_w1; p.W[1]=sage_wl1; p.W[2]=sage_wr1;
    p.C[0]=a0; p.C[1]=p1; p.C[2]=q1;
    p.K=64; p.ldw=64; p.ldc=64; p.slab=0; p.N=NN;
    k_mm_mfma<<<dim3(gN,3), 256, 0, stream>>>(p);
  }
  {
    MMP p = {};
    p.A[0]=xb; p.W[0]=gat_w1; p.C[0]=h1;
    p.K=64; p.ldw=256; p.ldc=256; p.slab=1; p.N=NN;
    k_mm_mfma<<<dim3(gN,4), 256, 0, stream>>>(p);
  }

  // ---- GAT layer 1 ----
  k_attdot4<<<g4, 256, 0, stream>>>(h1, gat_as1, gat_ad1, asrc1, adst1, NN);
  k_edgew1<<<g4, 256, 0, stream>>>(asrc1, adst1, offs, cnt, csr, wvE1, rden1, wvS1, NN);
  k_agg_gat1v<<<g4, 256, 0, stream>>>(h1, wvE1, rden1, wvS1, offs, cnt, csr, gat_b1, gath, NN);

  // ---- layer-1 aggregations (GCN + SAGE fused) ----
  k_agg_l1<<<g16, 256, 0, stream>>>(a0, p1, q1, dis, invc, offs, cnt, csr,
                                    gcn_b1, bn_gamma, bn_beta, sage_bl1, a1, s1, NN);

  // ---- GAT layer 2 matmul (K=256) ----
  {
    MMP p = {};
    p.A[0]=gath; p.W[0]=gat_w2; p.C[0]=h2;
    p.K=256; p.ldw=64; p.ldc=64; p.slab=1; p.N=NN;
    k_mm_mfma<<<dim3(gN,1), 256, 0, stream>>>(p);
  }
  k_attdot1<<<g4, 256, 0, stream>>>(h2, gat_as2, gat_ad2, asrc2, adst2, NN);
  k_edgew2<<<g4, 256, 0, stream>>>(asrc2, adst2, offs, cnt, csr, wvE2, rden2, wvS2, NN);

  // ---- layer-2 matmuls (GCN + SAGE fused dispatch) ----
  {
    MMP p = {};
    p.A[0]=a1; p.A[1]=s1; p.A[2]=s1;
    p.W[0]=gcn_w2; p.W[1]=sage_wl2; p.W[2]=sage_wr2;
    p.C[0]=a2; p.C[1]=p2; p.C[2]=q2;
    p.K=64; p.ldw=64; p.ldc=64; p.slab=0; p.N=NN;
    k_mm_mfma<<<dim3(gN,3), 256, 0, stream>>>(p);
  }

  // ---- fused final aggregation ----
  k_agg_final<<<g16, 256, 0, stream>>>(a2, h2, p2, q2, dis, invc, wvE2, rden2, wvS2,
                                       offs, cnt, csr, gcn_b2, gat_b2, sage_bl2, gatew, out, NN);
}

// Round 5
// 391.944 us; speedup vs baseline: 1.8686x; 1.0758x over previous
//
#include <hip/hip_runtime.h>
#include <hip/hip_bf16.h>
#include <math.h>

#define NN 50000
#define NE 400000

typedef __attribute__((ext_vector_type(8))) short bf16x8;
typedef __attribute__((ext_vector_type(4))) float f32x4;

// ---------------- helpers ----------------
__device__ __forceinline__ float lrelu(float v){ return v > 0.f ? v : 0.2f*v; }
__device__ __forceinline__ float elu1(float v){ return v > 0.f ? v : expm1f(v); }
__device__ __forceinline__ float bflo(unsigned int u){ return __uint_as_float(u << 16); }
__device__ __forceinline__ float bfhi(unsigned int u){ return __uint_as_float(u & 0xffff0000u); }
__device__ __forceinline__ unsigned short f2bf(float f){
  __hip_bfloat16 h = __float2bfloat16(f);
  return *(unsigned short*)&h;
}

// ---------------- CSR build ----------------
__global__ void k_count(const int* __restrict__ col, int* __restrict__ cnt, int E){
  int e = blockIdx.x*blockDim.x + threadIdx.x;
  if(e < E) atomicAdd(&cnt[col[e]], 1);
}

__global__ void k_alloc(const int* __restrict__ cnt, int* __restrict__ offs,
                        float* __restrict__ dis, float* __restrict__ invc,
                        int* __restrict__ total, int N){
  int i = blockIdx.x*blockDim.x + threadIdx.x;
  int lane = threadIdx.x & 63;
  int v = (i < N) ? cnt[i] : 0;
  int x = v;
  #pragma unroll
  for(int d = 1; d < 64; d <<= 1){ int t = __shfl_up(x, d, 64); if(lane >= d) x += t; }
  int base = 0;
  if(lane == 63 && x > 0) base = atomicAdd(total, x);
  base = __shfl(base, 63, 64);
  if(i < N){
    offs[i] = base + x - v;
    dis[i]  = 1.0f / sqrtf((float)(v + 1));
    invc[i] = 1.0f / fmaxf((float)v, 1.0f);
  }
}

__global__ void k_fill(const int* __restrict__ row, const int* __restrict__ col,
                       const int* __restrict__ offs, int* __restrict__ cursor,
                       int* __restrict__ csr, int E){
  int e = blockIdx.x*blockDim.x + threadIdx.x;
  if(e < E){
    int c = col[e];
    int pos = offs[c] + atomicAdd(&cursor[c], 1);
    csr[pos] = row[e];
  }
}

// ---------------- cast x -> bf16 + column sums for gate ----------------
__global__ void k_castsum(const float* __restrict__ x, unsigned short* __restrict__ xb,
                          float* __restrict__ gsum, int N){
  __shared__ float part[4][64];
  int lane = threadIdx.x & 63, w = threadIdx.x >> 6;
  float s = 0.f;
  for(int r = blockIdx.x*4 + w; r < N; r += gridDim.x*4){
    float v = x[(size_t)r*64 + lane];
    xb[(size_t)r*64 + lane] = f2bf(v);
    s += v;
  }
  part[w][lane] = s;
  __syncthreads();
  if(w == 0) atomicAdd(&gsum[lane], part[0][lane]+part[1][lane]+part[2][lane]+part[3][lane]);
}

__global__ void k_gate(const float* __restrict__ gsum,
                       const float* __restrict__ w1, const float* __restrict__ b1,
                       const float* __restrict__ w2, const float* __restrict__ b2,
                       float* __restrict__ gatew){
  __shared__ float g[64]; __shared__ float hid[64]; __shared__ float lg[3];
  int t = threadIdx.x;
  g[t] = gsum[t] * (1.0f/(float)NN);
  __syncthreads();
  float acc = b1[t];
  for(int i = 0; i < 64; i++) acc += g[i]*w1[i*64 + t];
  hid[t] = fmaxf(acc, 0.f);
  __syncthreads();
  if(t < 3){
    float a = b2[t];
    for(int j = 0; j < 64; j++) a += hid[j]*w2[j*3 + t];
    lg[t] = a;
  }
  __syncthreads();
  if(t == 0){
    float m = fmaxf(lg[0], fmaxf(lg[1], lg[2]));
    float e0 = expf(lg[0]-m), e1 = expf(lg[1]-m), e2 = expf(lg[2]-m);
    float s = e0 + e1 + e2;
    gatew[0] = e0/s; gatew[1] = e1/s; gatew[2] = e2/s;
  }
}

// ---------------- fold GAT1 attention vectors through W: Wsd[k][0..3]=src, [4..7]=dst ----------------
__global__ void k_fold1(const float* __restrict__ w1, const float* __restrict__ as,
                        const float* __restrict__ ad, float* __restrict__ wsd){
  int t = threadIdx.x;            // 256
  int k = t & 63, h = t >> 6;     // head 0..3
  float ssrc = 0.f, sdst = 0.f;
  for(int c = 0; c < 64; c++){
    float w = w1[k*256 + h*64 + c];
    ssrc += w * as[h*64 + c];
    sdst += w * ad[h*64 + c];
  }
  wsd[k*8 + h] = ssrc;
  wsd[k*8 + 4 + h] = sdst;
}

// ---------------- asrc1/adst1 = xb @ Wsd  (16 lanes per node) ----------------
__global__ void k_attdotx(const unsigned short* __restrict__ xb, const float* __restrict__ wsd,
                          float* __restrict__ asrc, float* __restrict__ adst, int N){
  __shared__ float ws[64*8];
  int tid = threadIdx.x;
  ws[tid] = wsd[tid];
  ws[tid + 256] = wsd[tid + 256];
  __syncthreads();
  int node = blockIdx.x*16 + (tid >> 4);
  int l = tid & 15;
  if(node >= N) return;
  uint2 u = *(const uint2*)&xb[(size_t)node*64 + l*4];
  float v0 = bflo(u.x), v1 = bfhi(u.x), v2 = bflo(u.y), v3 = bfhi(u.y);
  float s[8];
  #pragma unroll
  for(int h = 0; h < 8; h++){
    s[h] = v0*ws[(l*4+0)*8+h] + v1*ws[(l*4+1)*8+h] + v2*ws[(l*4+2)*8+h] + v3*ws[(l*4+3)*8+h];
  }
  #pragma unroll
  for(int d = 8; d >= 1; d >>= 1){
    #pragma unroll
    for(int h = 0; h < 8; h++) s[h] += __shfl_xor(s[h], d, 16);
  }
  if(l == 0){
    float4 o1; o1.x = s[0]; o1.y = s[1]; o1.z = s[2]; o1.w = s[3];
    float4 o2; o2.x = s[4]; o2.y = s[5]; o2.z = s[6]; o2.w = s[7];
    *(float4*)&asrc[node*4] = o1;
    *(float4*)&adst[node*4] = o2;
  }
}

// ---------------- MFMA bf16 matmul (generalized multi-target) ----------------
struct MME { const unsigned short* A; const float* W; unsigned short* C; int col0, ldw, ldc; };
struct MMP { MME e[8]; int K, N; };

__global__ __launch_bounds__(256) void k_mm_mfma(MMP p){
  __shared__ unsigned short Wt[64*264];   // transposed W slab, pitch K+8 (max K=256)
  MME m = p.e[blockIdx.y];
  const int K = p.K, N = p.N, pitch = K + 8;
  int tid = threadIdx.x;
  {
    int n = tid & 63;
    for(int k = tid >> 6; k < K; k += 4)
      Wt[n*pitch + k] = f2bf(m.W[(size_t)k*m.ldw + m.col0 + n]);
  }
  __syncthreads();
  int w = tid >> 6, lane = tid & 63, quad = lane >> 4, m16 = lane & 15;
  int rowa = blockIdx.x*64 + w*16 + m16;
  int rowc = rowa < N ? rowa : N - 1;
  f32x4 acc[4];
  #pragma unroll
  for(int t = 0; t < 4; t++){ acc[t][0]=0.f; acc[t][1]=0.f; acc[t][2]=0.f; acc[t][3]=0.f; }
  for(int kc = 0; kc < K; kc += 64){
    bf16x8 a0 = *(const bf16x8*)&m.A[(size_t)rowc*K + kc + quad*8];
    bf16x8 a1 = *(const bf16x8*)&m.A[(size_t)rowc*K + kc + 32 + quad*8];
    #pragma unroll
    for(int t = 0; t < 4; t++){
      bf16x8 b0 = *(const bf16x8*)&Wt[(t*16 + m16)*pitch + kc + quad*8];
      bf16x8 b1 = *(const bf16x8*)&Wt[(t*16 + m16)*pitch + kc + 32 + quad*8];
      acc[t] = __builtin_amdgcn_mfma_f32_16x16x32_bf16(a0, b0, acc[t], 0, 0, 0);
      acc[t] = __builtin_amdgcn_mfma_f32_16x16x32_bf16(a1, b1, acc[t], 0, 0, 0);
    }
  }
  int robase = blockIdx.x*64 + w*16 + quad*4;
  #pragma unroll
  for(int t = 0; t < 4; t++){
    #pragma unroll
    for(int r = 0; r < 4; r++){
      int ro = robase + r;
      if(ro < N) m.C[(size_t)ro*m.ldc + m.col0 + t*16 + m16] = f2bf(acc[t][r]);
    }
  }
}

// ---------------- attdot layer 2 (h2 bf16 [N,64]) ----------------
__global__ void k_attdot1(const unsigned short* __restrict__ h,
                          const float* __restrict__ att_src, const float* __restrict__ att_dst,
                          float* __restrict__ asrc, float* __restrict__ adst, int N){
  int node = blockIdx.x*4 + (threadIdx.x >> 6);
  int lane = threadIdx.x & 63;
  if(node >= N) return;
  float v = bflo((unsigned int)h[(size_t)node*64 + lane]);
  float vs = v*att_src[lane];
  float vd = v*att_dst[lane];
  #pragma unroll
  for(int d = 32; d >= 1; d >>= 1){ vs += __shfl_xor(vs, d, 64); vd += __shfl_xor(vd, d, 64); }
  if(lane == 0){ asrc[node] = vs; adst[node] = vd; }
}

// ---------------- GAT edge weights ----------------
__global__ void k_edgew1(const float* __restrict__ asrc, const float* __restrict__ adst,
                         const int* __restrict__ offs, const int* __restrict__ cnt,
                         const int* __restrict__ csr,
                         float* __restrict__ wvE, float* __restrict__ rdenN,
                         float* __restrict__ wvS, int N){
  int node = blockIdx.x*4 + (threadIdx.x >> 6);
  int lane = threadIdx.x & 63;
  if(node >= N) return;
  float4 ad = *(const float4*)&adst[node*4];
  float a0 = 0.f, a1 = 0.f, a2 = 0.f, a3 = 0.f;
  int e0 = offs[node], e1 = e0 + cnt[node];
  for(int e = e0 + lane; e < e1; e += 64){
    int s = csr[e];
    float4 as = *(const float4*)&asrc[s*4];
    float4 w;
    w.x = expf(lrelu(as.x + ad.x));
    w.y = expf(lrelu(as.y + ad.y));
    w.z = expf(lrelu(as.z + ad.z));
    w.w = expf(lrelu(as.w + ad.w));
    a0 += w.x; a1 += w.y; a2 += w.z; a3 += w.w;
    *(float4*)&wvE[(size_t)e*4] = w;
  }
  #pragma unroll
  for(int d = 32; d >= 1; d >>= 1){
    a0 += __shfl_xor(a0, d, 64); a1 += __shfl_xor(a1, d, 64);
    a2 += __shfl_xor(a2, d, 64); a3 += __shfl_xor(a3, d, 64);
  }
  float4 asl = *(const float4*)&asrc[node*4];
  float4 ws;
  ws.x = expf(lrelu(asl.x + ad.x));
  ws.y = expf(lrelu(asl.y + ad.y));
  ws.z = expf(lrelu(asl.z + ad.z));
  ws.w = expf(lrelu(asl.w + ad.w));
  if(lane == 0){
    float4 rd;
    rd.x = 1.0f/(a0 + ws.x); rd.y = 1.0f/(a1 + ws.y);
    rd.z = 1.0f/(a2 + ws.z); rd.w = 1.0f/(a3 + ws.w);
    *(float4*)&rdenN[node*4] = rd;
    *(float4*)&wvS[node*4] = ws;
  }
}

__global__ void k_edgew2(const float* __restrict__ asrc, const float* __restrict__ adst,
                         const int* __restrict__ offs, const int* __restrict__ cnt,
                         const int* __restrict__ csr,
                         float* __restrict__ wvE, float* __restrict__ rdenN,
                         float* __restrict__ wvS, int N){
  int node = blockIdx.x*4 + (threadIdx.x >> 6);
  int lane = threadIdx.x & 63;
  if(node >= N) return;
  float ad = adst[node];
  float acc = 0.f;
  int e0 = offs[node], e1 = e0 + cnt[node];
  for(int e = e0 + lane; e < e1; e += 64){
    float w = expf(lrelu(asrc[csr[e]] + ad));
    acc += w;
    wvE[e] = w;
  }
  #pragma unroll
  for(int d = 32; d >= 1; d >>= 1) acc += __shfl_xor(acc, d, 64);
  float ws = expf(lrelu(asrc[node] + ad));
  if(lane == 0){
    rdenN[node] = 1.0f/(acc + ws);
    wvS[node] = ws;
  }
}

// ---------------- GAT1 aggregation: wave/node, 2 edges per iteration, uint unpack ----------------
__global__ void k_agg_gat1v(const unsigned short* __restrict__ h1,
                            const float* __restrict__ wvE, const float* __restrict__ rdenN,
                            const float* __restrict__ wvS,
                            const int* __restrict__ offs, const int* __restrict__ cnt,
                            const int* __restrict__ csr,
                            const float* __restrict__ bias, unsigned short* __restrict__ out, int N){
  int node = blockIdx.x*4 + (threadIdx.x >> 6);
  int lane = threadIdx.x & 63;
  if(node >= N) return;
  int half = lane >> 5, subl = lane & 31;
  int head = subl >> 3;
  float num[8];
  #pragma unroll
  for(int j = 0; j < 8; j++) num[j] = 0.f;
  int e0 = offs[node], deg = cnt[node];
  for(int i = half; i <= deg; i += 2){      // i==0 is the self loop
    int s; float a;
    if(i == 0){ s = node; a = wvS[node*4 + head]; }
    else { int e = e0 + i - 1; s = csr[e]; a = wvE[(size_t)e*4 + head]; }
    uint4 u = *(const uint4*)&h1[(size_t)s*256 + subl*8];
    num[0] = fmaf(a, bflo(u.x), num[0]); num[1] = fmaf(a, bfhi(u.x), num[1]);
    num[2] = fmaf(a, bflo(u.y), num[2]); num[3] = fmaf(a, bfhi(u.y), num[3]);
    num[4] = fmaf(a, bflo(u.z), num[4]); num[5] = fmaf(a, bfhi(u.z), num[5]);
    num[6] = fmaf(a, bflo(u.w), num[6]); num[7] = fmaf(a, bfhi(u.w), num[7]);
  }
  #pragma unroll
  for(int j = 0; j < 8; j++) num[j] += __shfl_xor(num[j], 32, 64);
  if(half == 0){
    float rd = rdenN[node*4 + head];
    float4 bA = *(const float4*)&bias[subl*8];
    float4 bB = *(const float4*)&bias[subl*8 + 4];
    float b[8] = {bA.x, bA.y, bA.z, bA.w, bB.x, bB.y, bB.z, bB.w};
    unsigned short o[8];
    #pragma unroll
    for(int j = 0; j < 8; j++) o[j] = f2bf(elu1(num[j]*rd + b[j]));
    *(bf16x8*)&out[(size_t)node*256 + subl*8] = *(bf16x8*)o;
  }
}

// ---------------- fused layer-1 aggregation: GCN (BN+relu) + SAGE (relu+L2norm) ----------------
__global__ void k_agg_l1(const unsigned short* __restrict__ a0, const unsigned short* __restrict__ p1,
                         const unsigned short* __restrict__ q1,
                         const float* __restrict__ dis, const float* __restrict__ invc,
                         const int* __restrict__ offs, const int* __restrict__ cnt,
                         const int* __restrict__ csr,
                         const float* __restrict__ gcn_b1, const float* __restrict__ gamma,
                         const float* __restrict__ beta, const float* __restrict__ sage_bl1,
                         unsigned short* __restrict__ a1, unsigned short* __restrict__ s1, int N){
  int node = blockIdx.x*16 + (threadIdx.x >> 4);
  int l = threadIdx.x & 15;
  if(node >= N) return;
  float dc = dis[node];
  float g0, g1, g2, g3, s0, s1v, s2, s3;
  {
    uint2 u = *(const uint2*)&a0[(size_t)node*64 + l*4];
    g0 = dc*bflo(u.x); g1 = dc*bfhi(u.x); g2 = dc*bflo(u.y); g3 = dc*bfhi(u.y);
  }
  s0 = s1v = s2 = s3 = 0.f;
  int e = offs[node], e1 = e + cnt[node];
  for(; e + 1 < e1; e += 2){
    int sa = csr[e], sb = csr[e+1];
    float da = dis[sa], db = dis[sb];
    uint2 ua = *(const uint2*)&a0[(size_t)sa*64 + l*4];
    uint2 ub = *(const uint2*)&a0[(size_t)sb*64 + l*4];
    uint2 pa = *(const uint2*)&p1[(size_t)sa*64 + l*4];
    uint2 pb = *(const uint2*)&p1[(size_t)sb*64 + l*4];
    g0 = fmaf(da, bflo(ua.x), g0); g1 = fmaf(da, bfhi(ua.x), g1);
    g2 = fmaf(da, bflo(ua.y), g2); g3 = fmaf(da, bfhi(ua.y), g3);
    g0 = fmaf(db, bflo(ub.x), g0); g1 = fmaf(db, bfhi(ub.x), g1);
    g2 = fmaf(db, bflo(ub.y), g2); g3 = fmaf(db, bfhi(ub.y), g3);
    s0 += bflo(pa.x) + bflo(pb.x); s1v += bfhi(pa.x) + bfhi(pb.x);
    s2 += bflo(pa.y) + bflo(pb.y); s3 += bfhi(pa.y) + bfhi(pb.y);
  }
  if(e < e1){
    int sa = csr[e];
    float da = dis[sa];
    uint2 ua = *(const uint2*)&a0[(size_t)sa*64 + l*4];
    uint2 pa = *(const uint2*)&p1[(size_t)sa*64 + l*4];
    g0 = fmaf(da, bflo(ua.x), g0); g1 = fmaf(da, bfhi(ua.x), g1);
    g2 = fmaf(da, bflo(ua.y), g2); g3 = fmaf(da, bfhi(ua.y), g3);
    s0 += bflo(pa.x); s1v += bfhi(pa.x); s2 += bflo(pa.y); s3 += bfhi(pa.y);
  }
  // GCN out
  {
    const float sc = rsqrtf(1.0f + 1e-5f);
    float4 b = *(const float4*)&gcn_b1[l*4];
    float4 gm = *(const float4*)&gamma[l*4];
    float4 be = *(const float4*)&beta[l*4];
    unsigned short o[4];
    o[0] = f2bf(fmaxf((dc*g0 + b.x)*(gm.x*sc) + be.x, 0.f));
    o[1] = f2bf(fmaxf((dc*g1 + b.y)*(gm.y*sc) + be.y, 0.f));
    o[2] = f2bf(fmaxf((dc*g2 + b.z)*(gm.z*sc) + be.z, 0.f));
    o[3] = f2bf(fmaxf((dc*g3 + b.w)*(gm.w*sc) + be.w, 0.f));
    *(ushort4*)&a1[(size_t)node*64 + l*4] = *(ushort4*)o;
  }
  // SAGE out
  {
    float ic = invc[node];
    float4 b = *(const float4*)&sage_bl1[l*4];
    uint2 uq = *(const uint2*)&q1[(size_t)node*64 + l*4];
    float v0 = s0*ic + b.x + bflo(uq.x);
    float v1 = s1v*ic + b.y + bfhi(uq.x);
    float v2 = s2*ic + b.z + bflo(uq.y);
    float v3 = s3*ic + b.w + bfhi(uq.y);
    float n2 = v0*v0 + v1*v1 + v2*v2 + v3*v3;
    #pragma unroll
    for(int d = 8; d >= 1; d >>= 1) n2 += __shfl_xor(n2, d, 64);
    float inv = 1.0f / fmaxf(sqrtf(n2), 1e-12f);
    unsigned short o[4];
    o[0] = f2bf(fmaxf(v0*inv, 0.f)); o[1] = f2bf(fmaxf(v1*inv, 0.f));
    o[2] = f2bf(fmaxf(v2*inv, 0.f)); o[3] = f2bf(fmaxf(v3*inv, 0.f));
    *(ushort4*)&s1[(size_t)node*64 + l*4] = *(ushort4*)o;
  }
}

// ---------------- fused final aggregation: GCN2 + GAT2 + SAGE2 + gate combine ----------------
__global__ void k_agg_final(const unsigned short* __restrict__ a2, const unsigned short* __restrict__ h2,
                            const unsigned short* __restrict__ p2, const unsigned short* __restrict__ q2,
                            const float* __restrict__ dis, const float* __restrict__ invc,
                            const float* __restrict__ wvE, const float* __restrict__ rdenN,
                            const float* __restrict__ wvS,
                            const int* __restrict__ offs, const int* __restrict__ cnt,
                            const int* __restrict__ csr,
                            const float* __restrict__ gcn_b2, const float* __restrict__ gat_b2,
                            const float* __restrict__ sage_bl2, const float* __restrict__ gatew,
                            float* __restrict__ out, int N){
  int node = blockIdx.x*16 + (threadIdx.x >> 4);
  int l = threadIdx.x & 15;
  if(node >= N) return;
  float dc = dis[node];
  float g0, g1, g2, g3, t0, t1, t2, t3;
  {
    uint2 u = *(const uint2*)&a2[(size_t)node*64 + l*4];
    g0 = dc*bflo(u.x); g1 = dc*bfhi(u.x); g2 = dc*bflo(u.y); g3 = dc*bfhi(u.y);
    float a = wvS[node];
    uint2 h = *(const uint2*)&h2[(size_t)node*64 + l*4];
    t0 = a*bflo(h.x); t1 = a*bfhi(h.x); t2 = a*bflo(h.y); t3 = a*bfhi(h.y);
  }
  float s0 = 0.f, s1v = 0.f, s2 = 0.f, s3 = 0.f;
  int e = offs[node], e1 = e + cnt[node];
  for(; e + 1 < e1; e += 2){
    int sa = csr[e], sb = csr[e+1];
    float da = dis[sa], db = dis[sb];
    float aa = wvE[e], ab = wvE[e+1];
    uint2 ua = *(const uint2*)&a2[(size_t)sa*64 + l*4];
    uint2 ub = *(const uint2*)&a2[(size_t)sb*64 + l*4];
    uint2 ha = *(const uint2*)&h2[(size_t)sa*64 + l*4];
    uint2 hb = *(const uint2*)&h2[(size_t)sb*64 + l*4];
    uint2 pa = *(const uint2*)&p2[(size_t)sa*64 + l*4];
    uint2 pb = *(const uint2*)&p2[(size_t)sb*64 + l*4];
    g0 = fmaf(da, bflo(ua.x), g0); g1 = fmaf(da, bfhi(ua.x), g1);
    g2 = fmaf(da, bflo(ua.y), g2); g3 = fmaf(da, bfhi(ua.y), g3);
    g0 = fmaf(db, bflo(ub.x), g0); g1 = fmaf(db, bfhi(ub.x), g1);
    g2 = fmaf(db, bflo(ub.y), g2); g3 = fmaf(db, bfhi(ub.y), g3);
    t0 = fmaf(aa, bflo(ha.x), t0); t1 = fmaf(aa, bfhi(ha.x), t1);
    t2 = fmaf(aa, bflo(ha.y), t2); t3 = fmaf(aa, bfhi(ha.y), t3);
    t0 = fmaf(ab, bflo(hb.x), t0); t1 = fmaf(ab, bfhi(hb.x), t1);
    t2 = fmaf(ab, bflo(hb.y), t2); t3 = fmaf(ab, bfhi(hb.y), t3);
    s0 += bflo(pa.x) + bflo(pb.x); s1v += bfhi(pa.x) + bfhi(pb.x);
    s2 += bflo(pa.y) + bflo(pb.y); s3 += bfhi(pa.y) + bfhi(pb.y);
  }
  if(e < e1){
    int sa = csr[e];
    float da = dis[sa], aa = wvE[e];
    uint2 ua = *(const uint2*)&a2[(size_t)sa*64 + l*4];
    uint2 ha = *(const uint2*)&h2[(size_t)sa*64 + l*4];
    uint2 pa = *(const uint2*)&p2[(size_t)sa*64 + l*4];
    g0 = fmaf(da, bflo(ua.x), g0); g1 = fmaf(da, bfhi(ua.x), g1);
    g2 = fmaf(da, bflo(ua.y), g2); g3 = fmaf(da, bfhi(ua.y), g3);
    t0 = fmaf(aa, bflo(ha.x), t0); t1 = fmaf(aa, bfhi(ha.x), t1);
    t2 = fmaf(aa, bflo(ha.y), t2); t3 = fmaf(aa, bfhi(ha.y), t3);
    s0 += bflo(pa.x); s1v += bfhi(pa.x); s2 += bflo(pa.y); s3 += bfhi(pa.y);
  }
  float w0 = gatew[0], w1 = gatew[1], w2 = gatew[2];
  float4 bg = *(const float4*)&gcn_b2[l*4];
  float4 bt = *(const float4*)&gat_b2[l*4];
  float4 bs = *(const float4*)&sage_bl2[l*4];
  float rd = rdenN[node];
  float ic = invc[node];
  uint2 uq = *(const uint2*)&q2[(size_t)node*64 + l*4];
  float v0 = s0*ic + bs.x + bflo(uq.x);
  float v1 = s1v*ic + bs.y + bfhi(uq.x);
  float v2 = s2*ic + bs.z + bflo(uq.y);
  float v3 = s3*ic + bs.w + bfhi(uq.y);
  float n2 = v0*v0 + v1*v1 + v2*v2 + v3*v3;
  #pragma unroll
  for(int d = 8; d >= 1; d >>= 1) n2 += __shfl_xor(n2, d, 64);
  float inv = 1.0f / fmaxf(sqrtf(n2), 1e-12f);
  float4 o;
  o.x = w0*(dc*g0 + bg.x) + w1*(t0*rd + bt.x) + w2*v0*inv;
  o.y = w0*(dc*g1 + bg.y) + w1*(t1*rd + bt.y) + w2*v1*inv;
  o.z = w0*(dc*g2 + bg.z) + w1*(t2*rd + bt.z) + w2*v2*inv;
  o.w = w0*(dc*g3 + bg.w) + w1*(t3*rd + bt.w) + w2*v3*inv;
  *(float4*)&out[(size_t)node*64 + l*4] = o;
}

// ---------------- host ----------------
extern "C" void kernel_launch(void* const* d_in, const int* in_sizes, int n_in,
                              void* d_out, int out_size, void* d_ws, size_t ws_size,
                              hipStream_t stream){
  const float* x        = (const float*)d_in[0];
  const int*   ei       = (const int*)d_in[1];
  const int*   row      = ei;
  const int*   col      = ei + NE;
  const float* gate_w1  = (const float*)d_in[2];
  const float* gate_b1  = (const float*)d_in[3];
  const float* gate_w2  = (const float*)d_in[4];
  const float* gate_b2  = (const float*)d_in[5];
  const float* gcn_w1   = (const float*)d_in[6];
  const float* gcn_b1   = (const float*)d_in[7];
  const float* bn_gamma = (const float*)d_in[8];
  const float* bn_beta  = (const float*)d_in[9];
  const float* gcn_w2   = (const float*)d_in[10];
  const float* gcn_b2   = (const float*)d_in[11];
  const float* gat_w1   = (const float*)d_in[12];
  const float* gat_as1  = (const float*)d_in[13];
  const float* gat_ad1  = (const float*)d_in[14];
  const float* gat_b1   = (const float*)d_in[15];
  const float* gat_w2   = (const float*)d_in[16];
  const float* gat_as2  = (const float*)d_in[17];
  const float* gat_ad2  = (const float*)d_in[18];
  const float* gat_b2   = (const float*)d_in[19];
  const float* sage_wl1 = (const float*)d_in[20];
  const float* sage_bl1 = (const float*)d_in[21];
  const float* sage_wr1 = (const float*)d_in[22];
  const float* sage_wl2 = (const float*)d_in[23];
  const float* sage_bl2 = (const float*)d_in[24];
  const float* sage_wr2 = (const float*)d_in[25];
  float* out = (float*)d_out;

  char* wp = (char*)d_ws;
  auto alloc = [&](size_t bytes)->char*{ char* p = wp; wp += (bytes + 255) & ~(size_t)255; return p; };
  // zero-init region (contiguous): cnt, cursor, gsum, total
  int*   cnt    = (int*)  alloc((size_t)NN*4);
  int*   cursor = (int*)  alloc((size_t)NN*4);
  float* gsum   = (float*)alloc(64*4);
  int*   total  = (int*)  alloc(256);
  size_t zbytes = (size_t)(wp - (char*)cnt);
  int*   offs   = (int*)  alloc((size_t)NN*4);
  int*   csr    = (int*)  alloc((size_t)NE*4);
  float* dis    = (float*)alloc((size_t)NN*4);
  float* invc   = (float*)alloc((size_t)NN*4);
  float* gatew  = (float*)alloc(16);
  float* wsd    = (float*)alloc(64*8*4);
  float* asrc1  = (float*)alloc((size_t)NN*4*4);
  float* adst1  = (float*)alloc((size_t)NN*4*4);
  float* asrc2  = (float*)alloc((size_t)NN*4);
  float* adst2  = (float*)alloc((size_t)NN*4);
  float* wvE1   = (float*)alloc((size_t)NE*4*4);
  float* rden1  = (float*)alloc((size_t)NN*4*4);
  float* wvS1   = (float*)alloc((size_t)NN*4*4);
  float* wvE2   = (float*)alloc((size_t)NE*4);
  float* rden2  = (float*)alloc((size_t)NN*4);
  float* wvS2   = (float*)alloc((size_t)NN*4);
  unsigned short* xb  = (unsigned short*)alloc((size_t)NN*64*2);
  unsigned short* a0  = (unsigned short*)alloc((size_t)NN*64*2);  // also a2
  unsigned short* a1  = (unsigned short*)alloc((size_t)NN*64*2);
  unsigned short* p1  = (unsigned short*)alloc((size_t)NN*64*2);  // also p2
  unsigned short* q1  = (unsigned short*)alloc((size_t)NN*64*2);  // also q2
  unsigned short* s1  = (unsigned short*)alloc((size_t)NN*64*2);
  unsigned short* h1  = (unsigned short*)alloc((size_t)NN*256*2); // also h2
  unsigned short* gath= (unsigned short*)alloc((size_t)NN*256*2);
  unsigned short* a2 = a0;
  unsigned short* p2 = p1;
  unsigned short* q2 = q1;
  unsigned short* h2 = h1;

  hipMemsetAsync(cnt, 0, zbytes, stream);

  const int gN  = (NN + 63) / 64;   // 782
  const int g4  = NN / 4;           // 12500
  const int g16 = NN / 16;          // 3125
  const int gA  = (NN + 255) / 256; // 196

  k_count<<<(NE+255)/256, 256, 0, stream>>>(col, cnt, NE);
  k_alloc<<<gA, 256, 0, stream>>>(cnt, offs, dis, invc, total, NN);
  k_fill <<<(NE+255)/256, 256, 0, stream>>>(row, col, offs, cursor, csr, NE);
  k_castsum<<<256, 256, 0, stream>>>(x, xb, gsum, NN);
  k_gate  <<<1, 64, 0, stream>>>(gsum, gate_w1, gate_b1, gate_w2, gate_b2, gatew);
  k_fold1 <<<1, 256, 0, stream>>>(gat_w1, gat_as1, gat_ad1, wsd);
  k_attdotx<<<g16, 256, 0, stream>>>(xb, wsd, asrc1, adst1, NN);
  k_edgew1<<<g4, 256, 0, stream>>>(asrc1, adst1, offs, cnt, csr, wvE1, rden1, wvS1, NN);

  // ---- layer-1 matmuls: gcn/sage (3) + gat1 slabs (4) in one dispatch ----
  {
    MMP p = {};
    p.e[0] = {xb, gcn_w1,   a0, 0,   64, 64};
    p.e[1] = {xb, sage_wl1, p1, 0,   64, 64};
    p.e[2] = {xb, sage_wr1, q1, 0,   64, 64};
    p.e[3] = {xb, gat_w1,   h1, 0,   256, 256};
    p.e[4] = {xb, gat_w1,   h1, 64,  256, 256};
    p.e[5] = {xb, gat_w1,   h1, 128, 256, 256};
    p.e[6] = {xb, gat_w1,   h1, 192, 256, 256};
    p.K = 64; p.N = NN;
    k_mm_mfma<<<dim3(gN,7), 256, 0, stream>>>(p);
  }

  k_agg_gat1v<<<g4, 256, 0, stream>>>(h1, wvE1, rden1, wvS1, offs, cnt, csr, gat_b1, gath, NN);
  k_agg_l1<<<g16, 256, 0, stream>>>(a0, p1, q1, dis, invc, offs, cnt, csr,
                                    gcn_b1, bn_gamma, bn_beta, sage_bl1, a1, s1, NN);

  // ---- GAT layer 2 matmul (K=256) ----
  {
    MMP p = {};
    p.e[0] = {gath, gat_w2, h2, 0, 64, 64};
    p.K = 256; p.N = NN;
    k_mm_mfma<<<dim3(gN,1), 256, 0, stream>>>(p);
  }
  k_attdot1<<<g4, 256, 0, stream>>>(h2, gat_as2, gat_ad2, asrc2, adst2, NN);
  k_edgew2<<<g4, 256, 0, stream>>>(asrc2, adst2, offs, cnt, csr, wvE2, rden2, wvS2, NN);

  // ---- layer-2 matmuls ----
  {
    MMP p = {};
    p.e[0] = {a1, gcn_w2,   a2, 0, 64, 64};
    p.e[1] = {s1, sage_wl2, p2, 0, 64, 64};
    p.e[2] = {s1, sage_wr2, q2, 0, 64, 64};
    p.K = 64; p.N = NN;
    k_mm_mfma<<<dim3(gN,3), 256, 0, stream>>>(p);
  }

  // ---- fused final aggregation ----
  k_agg_final<<<g16, 256, 0, stream>>>(a2, h2, p2, q2, dis, invc, wvE2, rden2, wvS2,
                                       offs, cnt, csr, gcn_b2, gat_b2, sage_bl2, gatew, out, NN);
}

// Round 6
// 391.899 us; speedup vs baseline: 1.8688x; 1.0001x over previous
//
#include <hip/hip_runtime.h>
#include <hip/hip_bf16.h>
#include <math.h>

#define NN 50000
#define NE 400000

typedef __attribute__((ext_vector_type(8))) short bf16x8;
typedef __attribute__((ext_vector_type(4))) float f32x4;

// ---------------- helpers ----------------
__device__ __forceinline__ float lrelu(float v){ return v > 0.f ? v : 0.2f*v; }
__device__ __forceinline__ float elu1(float v){ return v > 0.f ? v : expm1f(v); }
__device__ __forceinline__ float bflo(unsigned int u){ return __uint_as_float(u << 16); }
__device__ __forceinline__ float bfhi(unsigned int u){ return __uint_as_float(u & 0xffff0000u); }
__device__ __forceinline__ unsigned short f2bf(float f){
  __hip_bfloat16 h = __float2bfloat16(f);
  return *(unsigned short*)&h;
}
__device__ __forceinline__ void acc8(float* num, float a, uint4 u){
  num[0] = fmaf(a, bflo(u.x), num[0]); num[1] = fmaf(a, bfhi(u.x), num[1]);
  num[2] = fmaf(a, bflo(u.y), num[2]); num[3] = fmaf(a, bfhi(u.y), num[3]);
  num[4] = fmaf(a, bflo(u.z), num[4]); num[5] = fmaf(a, bfhi(u.z), num[5]);
  num[6] = fmaf(a, bflo(u.w), num[6]); num[7] = fmaf(a, bfhi(u.w), num[7]);
}

// ---------------- CSR build ----------------
__global__ void k_count(const int* __restrict__ col, int* __restrict__ cnt, int E){
  int e = blockIdx.x*blockDim.x + threadIdx.x;
  if(e < E) atomicAdd(&cnt[col[e]], 1);
}

__global__ void k_alloc(const int* __restrict__ cnt, int* __restrict__ offs,
                        float* __restrict__ dis, float* __restrict__ invc,
                        int* __restrict__ total, int N){
  int i = blockIdx.x*blockDim.x + threadIdx.x;
  int lane = threadIdx.x & 63;
  int v = (i < N) ? cnt[i] : 0;
  int x = v;
  #pragma unroll
  for(int d = 1; d < 64; d <<= 1){ int t = __shfl_up(x, d, 64); if(lane >= d) x += t; }
  int base = 0;
  if(lane == 63 && x > 0) base = atomicAdd(total, x);
  base = __shfl(base, 63, 64);
  if(i < N){
    offs[i] = base + x - v;
    dis[i]  = 1.0f / sqrtf((float)(v + 1));
    invc[i] = 1.0f / fmaxf((float)v, 1.0f);
  }
}

__global__ void k_fill(const int* __restrict__ row, const int* __restrict__ col,
                       const int* __restrict__ offs, int* __restrict__ cursor,
                       int* __restrict__ csr, int E){
  int e = blockIdx.x*blockDim.x + threadIdx.x;
  if(e < E){
    int c = col[e];
    int pos = offs[c] + atomicAdd(&cursor[c], 1);
    csr[pos] = row[e];
  }
}

// ---------------- cast x -> bf16 + column sums for gate ----------------
__global__ void k_castsum(const float* __restrict__ x, unsigned short* __restrict__ xb,
                          float* __restrict__ gsum, int N){
  __shared__ float part[4][64];
  int lane = threadIdx.x & 63, w = threadIdx.x >> 6;
  float s = 0.f;
  for(int r = blockIdx.x*4 + w; r < N; r += gridDim.x*4){
    float v = x[(size_t)r*64 + lane];
    xb[(size_t)r*64 + lane] = f2bf(v);
    s += v;
  }
  part[w][lane] = s;
  __syncthreads();
  if(w == 0) atomicAdd(&gsum[lane], part[0][lane]+part[1][lane]+part[2][lane]+part[3][lane]);
}

__global__ void k_gate(const float* __restrict__ gsum,
                       const float* __restrict__ w1, const float* __restrict__ b1,
                       const float* __restrict__ w2, const float* __restrict__ b2,
                       float* __restrict__ gatew){
  __shared__ float g[64]; __shared__ float hid[64]; __shared__ float lg[3];
  int t = threadIdx.x;
  g[t] = gsum[t] * (1.0f/(float)NN);
  __syncthreads();
  float acc = b1[t];
  for(int i = 0; i < 64; i++) acc += g[i]*w1[i*64 + t];
  hid[t] = fmaxf(acc, 0.f);
  __syncthreads();
  if(t < 3){
    float a = b2[t];
    for(int j = 0; j < 64; j++) a += hid[j]*w2[j*3 + t];
    lg[t] = a;
  }
  __syncthreads();
  if(t == 0){
    float m = fmaxf(lg[0], fmaxf(lg[1], lg[2]));
    float e0 = expf(lg[0]-m), e1 = expf(lg[1]-m), e2 = expf(lg[2]-m);
    float s = e0 + e1 + e2;
    gatew[0] = e0/s; gatew[1] = e1/s; gatew[2] = e2/s;
  }
}

// ---------------- fold GAT1 attention vectors through W: Wsd[k][0..3]=src, [4..7]=dst ----------------
__global__ void k_fold1(const float* __restrict__ w1, const float* __restrict__ as,
                        const float* __restrict__ ad, float* __restrict__ wsd){
  int t = threadIdx.x;            // 256
  int k = t & 63, h = t >> 6;     // head 0..3
  float ssrc = 0.f, sdst = 0.f;
  for(int c = 0; c < 64; c++){
    float w = w1[k*256 + h*64 + c];
    ssrc += w * as[h*64 + c];
    sdst += w * ad[h*64 + c];
  }
  wsd[k*8 + h] = ssrc;
  wsd[k*8 + 4 + h] = sdst;
}

// ---------------- asrc1/adst1 = xb @ Wsd  (16 lanes per node) ----------------
__global__ void k_attdotx(const unsigned short* __restrict__ xb, const float* __restrict__ wsd,
                          float* __restrict__ asrc, float* __restrict__ adst, int N){
  __shared__ float ws[64*8];
  int tid = threadIdx.x;
  ws[tid] = wsd[tid];
  ws[tid + 256] = wsd[tid + 256];
  __syncthreads();
  int node = blockIdx.x*16 + (tid >> 4);
  int l = tid & 15;
  if(node >= N) return;
  uint2 u = *(const uint2*)&xb[(size_t)node*64 + l*4];
  float v0 = bflo(u.x), v1 = bfhi(u.x), v2 = bflo(u.y), v3 = bfhi(u.y);
  float s[8];
  #pragma unroll
  for(int h = 0; h < 8; h++){
    s[h] = v0*ws[(l*4+0)*8+h] + v1*ws[(l*4+1)*8+h] + v2*ws[(l*4+2)*8+h] + v3*ws[(l*4+3)*8+h];
  }
  #pragma unroll
  for(int d = 8; d >= 1; d >>= 1){
    #pragma unroll
    for(int h = 0; h < 8; h++) s[h] += __shfl_xor(s[h], d, 16);
  }
  if(l == 0){
    float4 o1; o1.x = s[0]; o1.y = s[1]; o1.z = s[2]; o1.w = s[3];
    float4 o2; o2.x = s[4]; o2.y = s[5]; o2.z = s[6]; o2.w = s[7];
    *(float4*)&asrc[node*4] = o1;
    *(float4*)&adst[node*4] = o2;
  }
}

// ---------------- MFMA bf16 matmul (generalized multi-target) ----------------
struct MME { const unsigned short* A; const float* W; unsigned short* C; int col0, ldw, ldc; };
struct MMP { MME e[8]; int K, N; };

__global__ __launch_bounds__(256) void k_mm_mfma(MMP p){
  __shared__ unsigned short Wt[64*264];   // transposed W slab, pitch K+8 (max K=256)
  MME m = p.e[blockIdx.y];
  const int K = p.K, N = p.N, pitch = K + 8;
  int tid = threadIdx.x;
  {
    int n = tid & 63;
    for(int k = tid >> 6; k < K; k += 4)
      Wt[n*pitch + k] = f2bf(m.W[(size_t)k*m.ldw + m.col0 + n]);
  }
  __syncthreads();
  int w = tid >> 6, lane = tid & 63, quad = lane >> 4, m16 = lane & 15;
  int rowa = blockIdx.x*64 + w*16 + m16;
  int rowc = rowa < N ? rowa : N - 1;
  f32x4 acc[4];
  #pragma unroll
  for(int t = 0; t < 4; t++){ acc[t][0]=0.f; acc[t][1]=0.f; acc[t][2]=0.f; acc[t][3]=0.f; }
  for(int kc = 0; kc < K; kc += 64){
    bf16x8 a0 = *(const bf16x8*)&m.A[(size_t)rowc*K + kc + quad*8];
    bf16x8 a1 = *(const bf16x8*)&m.A[(size_t)rowc*K + kc + 32 + quad*8];
    #pragma unroll
    for(int t = 0; t < 4; t++){
      bf16x8 b0 = *(const bf16x8*)&Wt[(t*16 + m16)*pitch + kc + quad*8];
      bf16x8 b1 = *(const bf16x8*)&Wt[(t*16 + m16)*pitch + kc + 32 + quad*8];
      acc[t] = __builtin_amdgcn_mfma_f32_16x16x32_bf16(a0, b0, acc[t], 0, 0, 0);
      acc[t] = __builtin_amdgcn_mfma_f32_16x16x32_bf16(a1, b1, acc[t], 0, 0, 0);
    }
  }
  int robase = blockIdx.x*64 + w*16 + quad*4;
  #pragma unroll
  for(int t = 0; t < 4; t++){
    #pragma unroll
    for(int r = 0; r < 4; r++){
      int ro = robase + r;
      if(ro < N) m.C[(size_t)ro*m.ldc + m.col0 + t*16 + m16] = f2bf(acc[t][r]);
    }
  }
}

// ---------------- attdot layer 2 (h2 bf16 [N,64]) ----------------
__global__ void k_attdot1(const unsigned short* __restrict__ h,
                          const float* __restrict__ att_src, const float* __restrict__ att_dst,
                          float* __restrict__ asrc, float* __restrict__ adst, int N){
  int node = blockIdx.x*4 + (threadIdx.x >> 6);
  int lane = threadIdx.x & 63;
  if(node >= N) return;
  float v = bflo((unsigned int)h[(size_t)node*64 + lane]);
  float vs = v*att_src[lane];
  float vd = v*att_dst[lane];
  #pragma unroll
  for(int d = 32; d >= 1; d >>= 1){ vs += __shfl_xor(vs, d, 64); vd += __shfl_xor(vd, d, 64); }
  if(lane == 0){ asrc[node] = vs; adst[node] = vd; }
}

// ---------------- GAT edge weights ----------------
__global__ void k_edgew1(const float* __restrict__ asrc, const float* __restrict__ adst,
                         const int* __restrict__ offs, const int* __restrict__ cnt,
                         const int* __restrict__ csr,
                         float* __restrict__ wvE, float* __restrict__ rdenN,
                         float* __restrict__ wvS, int N){
  int node = blockIdx.x*4 + (threadIdx.x >> 6);
  int lane = threadIdx.x & 63;
  if(node >= N) return;
  float4 ad = *(const float4*)&adst[node*4];
  float a0 = 0.f, a1 = 0.f, a2 = 0.f, a3 = 0.f;
  int e0 = offs[node], e1 = e0 + cnt[node];
  for(int e = e0 + lane; e < e1; e += 64){
    int s = csr[e];
    float4 as = *(const float4*)&asrc[s*4];
    float4 w;
    w.x = expf(lrelu(as.x + ad.x));
    w.y = expf(lrelu(as.y + ad.y));
    w.z = expf(lrelu(as.z + ad.z));
    w.w = expf(lrelu(as.w + ad.w));
    a0 += w.x; a1 += w.y; a2 += w.z; a3 += w.w;
    *(float4*)&wvE[(size_t)e*4] = w;
  }
  #pragma unroll
  for(int d = 32; d >= 1; d >>= 1){
    a0 += __shfl_xor(a0, d, 64); a1 += __shfl_xor(a1, d, 64);
    a2 += __shfl_xor(a2, d, 64); a3 += __shfl_xor(a3, d, 64);
  }
  float4 asl = *(const float4*)&asrc[node*4];
  float4 ws;
  ws.x = expf(lrelu(asl.x + ad.x));
  ws.y = expf(lrelu(asl.y + ad.y));
  ws.z = expf(lrelu(asl.z + ad.z));
  ws.w = expf(lrelu(asl.w + ad.w));
  if(lane == 0){
    float4 rd;
    rd.x = 1.0f/(a0 + ws.x); rd.y = 1.0f/(a1 + ws.y);
    rd.z = 1.0f/(a2 + ws.z); rd.w = 1.0f/(a3 + ws.w);
    *(float4*)&rdenN[node*4] = rd;
    *(float4*)&wvS[node*4] = ws;
  }
}

__global__ void k_edgew2(const float* __restrict__ asrc, const float* __restrict__ adst,
                         const int* __restrict__ offs, const int* __restrict__ cnt,
                         const int* __restrict__ csr,
                         float* __restrict__ wvE, float* __restrict__ rdenN,
                         float* __restrict__ wvS, int N){
  int node = blockIdx.x*4 + (threadIdx.x >> 6);
  int lane = threadIdx.x & 63;
  if(node >= N) return;
  float ad = adst[node];
  float acc = 0.f;
  int e0 = offs[node], e1 = e0 + cnt[node];
  for(int e = e0 + lane; e < e1; e += 64){
    float w = expf(lrelu(asrc[csr[e]] + ad));
    acc += w;
    wvE[e] = w;
  }
  #pragma unroll
  for(int d = 32; d >= 1; d >>= 1) acc += __shfl_xor(acc, d, 64);
  float ws = expf(lrelu(asrc[node] + ad));
  if(lane == 0){
    rdenN[node] = 1.0f/(acc + ws);
    wvS[node] = ws;
  }
}

// ---------------- GAT1 aggregation: wave/node, halves take even/odd edges, 4-deep unroll ----------------
__global__ void k_agg_gat1v(const unsigned short* __restrict__ h1,
                            const float* __restrict__ wvE, const float* __restrict__ rdenN,
                            const float* __restrict__ wvS,
                            const int* __restrict__ offs, const int* __restrict__ cnt,
                            const int* __restrict__ csr,
                            const float* __restrict__ bias, unsigned short* __restrict__ out, int N){
  int node = blockIdx.x*4 + (threadIdx.x >> 6);
  int lane = threadIdx.x & 63;
  if(node >= N) return;
  int half = lane >> 5, subl = lane & 31;
  int head = subl >> 3;
  float num[8];
  #pragma unroll
  for(int j = 0; j < 8; j++) num[j] = 0.f;
  int e0 = offs[node], e1 = e0 + cnt[node];
  if(half == 0){   // self loop on half 0
    float a = wvS[node*4 + head];
    uint4 u = *(const uint4*)&h1[(size_t)node*256 + subl*8];
    acc8(num, a, u);
  }
  int e = e0 + half;    // half 0: even edges, half 1: odd edges
  for(; e + 6 < e1; e += 8){
    int s0 = csr[e], s1 = csr[e+2], s2 = csr[e+4], s3 = csr[e+6];
    float a0 = wvE[(size_t)e*4 + head];
    float a1 = wvE[(size_t)(e+2)*4 + head];
    float a2 = wvE[(size_t)(e+4)*4 + head];
    float a3 = wvE[(size_t)(e+6)*4 + head];
    uint4 u0 = *(const uint4*)&h1[(size_t)s0*256 + subl*8];
    uint4 u1 = *(const uint4*)&h1[(size_t)s1*256 + subl*8];
    uint4 u2 = *(const uint4*)&h1[(size_t)s2*256 + subl*8];
    uint4 u3 = *(const uint4*)&h1[(size_t)s3*256 + subl*8];
    acc8(num, a0, u0); acc8(num, a1, u1); acc8(num, a2, u2); acc8(num, a3, u3);
  }
  for(; e < e1; e += 2){
    int s = csr[e];
    float a = wvE[(size_t)e*4 + head];
    uint4 u = *(const uint4*)&h1[(size_t)s*256 + subl*8];
    acc8(num, a, u);
  }
  #pragma unroll
  for(int j = 0; j < 8; j++) num[j] += __shfl_xor(num[j], 32, 64);
  if(half == 0){
    float rd = rdenN[node*4 + head];
    float4 bA = *(const float4*)&bias[subl*8];
    float4 bB = *(const float4*)&bias[subl*8 + 4];
    float b[8] = {bA.x, bA.y, bA.z, bA.w, bB.x, bB.y, bB.z, bB.w};
    unsigned short o[8];
    #pragma unroll
    for(int j = 0; j < 8; j++) o[j] = f2bf(elu1(num[j]*rd + b[j]));
    *(bf16x8*)&out[(size_t)node*256 + subl*8] = *(bf16x8*)o;
  }
}

// ---------------- fused layer-1 aggregation: GCN (BN+relu) + SAGE (relu+L2norm), 4-deep ----------------
__global__ void k_agg_l1(const unsigned short* __restrict__ a0, const unsigned short* __restrict__ p1,
                         const unsigned short* __restrict__ q1,
                         const float* __restrict__ dis, const float* __restrict__ invc,
                         const int* __restrict__ offs, const int* __restrict__ cnt,
                         const int* __restrict__ csr,
                         const float* __restrict__ gcn_b1, const float* __restrict__ gamma,
                         const float* __restrict__ beta, const float* __restrict__ sage_bl1,
                         unsigned short* __restrict__ a1, unsigned short* __restrict__ s1, int N){
  int node = blockIdx.x*16 + (threadIdx.x >> 4);
  int l = threadIdx.x & 15;
  if(node >= N) return;
  float dc = dis[node];
  float g0, g1, g2, g3, s0, s1v, s2, s3;
  {
    uint2 u = *(const uint2*)&a0[(size_t)node*64 + l*4];
    g0 = dc*bflo(u.x); g1 = dc*bfhi(u.x); g2 = dc*bflo(u.y); g3 = dc*bfhi(u.y);
  }
  s0 = s1v = s2 = s3 = 0.f;
  int e = offs[node], e1 = e + cnt[node];
  for(; e + 3 < e1; e += 4){
    int sa = csr[e], sb = csr[e+1], sc = csr[e+2], sd = csr[e+3];
    float da = dis[sa], db = dis[sb], dce = dis[sc], dd = dis[sd];
    uint2 ua = *(const uint2*)&a0[(size_t)sa*64 + l*4];
    uint2 ub = *(const uint2*)&a0[(size_t)sb*64 + l*4];
    uint2 uc = *(const uint2*)&a0[(size_t)sc*64 + l*4];
    uint2 ud = *(const uint2*)&a0[(size_t)sd*64 + l*4];
    uint2 pa = *(const uint2*)&p1[(size_t)sa*64 + l*4];
    uint2 pb = *(const uint2*)&p1[(size_t)sb*64 + l*4];
    uint2 pc = *(const uint2*)&p1[(size_t)sc*64 + l*4];
    uint2 pd = *(const uint2*)&p1[(size_t)sd*64 + l*4];
    g0 = fmaf(da, bflo(ua.x), g0); g1 = fmaf(da, bfhi(ua.x), g1);
    g2 = fmaf(da, bflo(ua.y), g2); g3 = fmaf(da, bfhi(ua.y), g3);
    g0 = fmaf(db, bflo(ub.x), g0); g1 = fmaf(db, bfhi(ub.x), g1);
    g2 = fmaf(db, bflo(ub.y), g2); g3 = fmaf(db, bfhi(ub.y), g3);
    g0 = fmaf(dce, bflo(uc.x), g0); g1 = fmaf(dce, bfhi(uc.x), g1);
    g2 = fmaf(dce, bflo(uc.y), g2); g3 = fmaf(dce, bfhi(uc.y), g3);
    g0 = fmaf(dd, bflo(ud.x), g0); g1 = fmaf(dd, bfhi(ud.x), g1);
    g2 = fmaf(dd, bflo(ud.y), g2); g3 = fmaf(dd, bfhi(ud.y), g3);
    s0 += (bflo(pa.x) + bflo(pb.x)) + (bflo(pc.x) + bflo(pd.x));
    s1v += (bfhi(pa.x) + bfhi(pb.x)) + (bfhi(pc.x) + bfhi(pd.x));
    s2 += (bflo(pa.y) + bflo(pb.y)) + (bflo(pc.y) + bflo(pd.y));
    s3 += (bfhi(pa.y) + bfhi(pb.y)) + (bfhi(pc.y) + bfhi(pd.y));
  }
  for(; e < e1; e++){
    int sa = csr[e];
    float da = dis[sa];
    uint2 ua = *(const uint2*)&a0[(size_t)sa*64 + l*4];
    uint2 pa = *(const uint2*)&p1[(size_t)sa*64 + l*4];
    g0 = fmaf(da, bflo(ua.x), g0); g1 = fmaf(da, bfhi(ua.x), g1);
    g2 = fmaf(da, bflo(ua.y), g2); g3 = fmaf(da, bfhi(ua.y), g3);
    s0 += bflo(pa.x); s1v += bfhi(pa.x); s2 += bflo(pa.y); s3 += bfhi(pa.y);
  }
  // GCN out
  {
    const float sc = rsqrtf(1.0f + 1e-5f);
    float4 b = *(const float4*)&gcn_b1[l*4];
    float4 gm = *(const float4*)&gamma[l*4];
    float4 be = *(const float4*)&beta[l*4];
    unsigned short o[4];
    o[0] = f2bf(fmaxf((dc*g0 + b.x)*(gm.x*sc) + be.x, 0.f));
    o[1] = f2bf(fmaxf((dc*g1 + b.y)*(gm.y*sc) + be.y, 0.f));
    o[2] = f2bf(fmaxf((dc*g2 + b.z)*(gm.z*sc) + be.z, 0.f));
    o[3] = f2bf(fmaxf((dc*g3 + b.w)*(gm.w*sc) + be.w, 0.f));
    *(ushort4*)&a1[(size_t)node*64 + l*4] = *(ushort4*)o;
  }
  // SAGE out
  {
    float ic = invc[node];
    float4 b = *(const float4*)&sage_bl1[l*4];
    uint2 uq = *(const uint2*)&q1[(size_t)node*64 + l*4];
    float v0 = s0*ic + b.x + bflo(uq.x);
    float v1 = s1v*ic + b.y + bfhi(uq.x);
    float v2 = s2*ic + b.z + bflo(uq.y);
    float v3 = s3*ic + b.w + bfhi(uq.y);
    float n2 = v0*v0 + v1*v1 + v2*v2 + v3*v3;
    #pragma unroll
    for(int d = 8; d >= 1; d >>= 1) n2 += __shfl_xor(n2, d, 64);
    float inv = 1.0f / fmaxf(sqrtf(n2), 1e-12f);
    unsigned short o[4];
    o[0] = f2bf(fmaxf(v0*inv, 0.f)); o[1] = f2bf(fmaxf(v1*inv, 0.f));
    o[2] = f2bf(fmaxf(v2*inv, 0.f)); o[3] = f2bf(fmaxf(v3*inv, 0.f));
    *(ushort4*)&s1[(size_t)node*64 + l*4] = *(ushort4*)o;
  }
}

// ---------------- fused final aggregation: GCN2 + GAT2 + SAGE2 + gate combine, 4-deep ----------------
__global__ void k_agg_final(const unsigned short* __restrict__ a2, const unsigned short* __restrict__ h2,
                            const unsigned short* __restrict__ p2, const unsigned short* __restrict__ q2,
                            const float* __restrict__ dis, const float* __restrict__ invc,
                            const float* __restrict__ wvE, const float* __restrict__ rdenN,
                            const float* __restrict__ wvS,
                            const int* __restrict__ offs, const int* __restrict__ cnt,
                            const int* __restrict__ csr,
                            const float* __restrict__ gcn_b2, const float* __restrict__ gat_b2,
                            const float* __restrict__ sage_bl2, const float* __restrict__ gatew,
                            float* __restrict__ out, int N){
  int node = blockIdx.x*16 + (threadIdx.x >> 4);
  int l = threadIdx.x & 15;
  if(node >= N) return;
  float dc = dis[node];
  float g0, g1, g2, g3, t0, t1, t2, t3;
  {
    uint2 u = *(const uint2*)&a2[(size_t)node*64 + l*4];
    g0 = dc*bflo(u.x); g1 = dc*bfhi(u.x); g2 = dc*bflo(u.y); g3 = dc*bfhi(u.y);
    float a = wvS[node];
    uint2 h = *(const uint2*)&h2[(size_t)node*64 + l*4];
    t0 = a*bflo(h.x); t1 = a*bfhi(h.x); t2 = a*bflo(h.y); t3 = a*bfhi(h.y);
  }
  float s0 = 0.f, s1v = 0.f, s2 = 0.f, s3 = 0.f;
  int e = offs[node], e1 = e + cnt[node];
  for(; e + 3 < e1; e += 4){
    int sa = csr[e], sb = csr[e+1], sc = csr[e+2], sd = csr[e+3];
    float da = dis[sa], db = dis[sb], dce = dis[sc], dd = dis[sd];
    float aa = wvE[e], ab = wvE[e+1], ac = wvE[e+2], ad_ = wvE[e+3];
    uint2 ua = *(const uint2*)&a2[(size_t)sa*64 + l*4];
    uint2 ub = *(const uint2*)&a2[(size_t)sb*64 + l*4];
    uint2 uc = *(const uint2*)&a2[(size_t)sc*64 + l*4];
    uint2 ud = *(const uint2*)&a2[(size_t)sd*64 + l*4];
    uint2 ha = *(const uint2*)&h2[(size_t)sa*64 + l*4];
    uint2 hb = *(const uint2*)&h2[(size_t)sb*64 + l*4];
    uint2 hc = *(const uint2*)&h2[(size_t)sc*64 + l*4];
    uint2 hd = *(const uint2*)&h2[(size_t)sd*64 + l*4];
    uint2 pa = *(const uint2*)&p2[(size_t)sa*64 + l*4];
    uint2 pb = *(const uint2*)&p2[(size_t)sb*64 + l*4];
    uint2 pc = *(const uint2*)&p2[(size_t)sc*64 + l*4];
    uint2 pd = *(const uint2*)&p2[(size_t)sd*64 + l*4];
    g0 = fmaf(da, bflo(ua.x), g0); g1 = fmaf(da, bfhi(ua.x), g1);
    g2 = fmaf(da, bflo(ua.y), g2); g3 = fmaf(da, bfhi(ua.y), g3);
    g0 = fmaf(db, bflo(ub.x), g0); g1 = fmaf(db, bfhi(ub.x), g1);
    g2 = fmaf(db, bflo(ub.y), g2); g3 = fmaf(db, bfhi(ub.y), g3);
    g0 = fmaf(dce, bflo(uc.x), g0); g1 = fmaf(dce, bfhi(uc.x), g1);
    g2 = fmaf(dce, bflo(uc.y), g2); g3 = fmaf(dce, bfhi(uc.y), g3);
    g0 = fmaf(dd, bflo(ud.x), g0); g1 = fmaf(dd, bfhi(ud.x), g1);
    g2 = fmaf(dd, bflo(ud.y), g2); g3 = fmaf(dd, bfhi(ud.y), g3);
    t0 = fmaf(aa, bflo(ha.x), t0); t1 = fmaf(aa, bfhi(ha.x), t1);
    t2 = fmaf(aa, bflo(ha.y), t2); t3 = fmaf(aa, bfhi(ha.y), t3);
    t0 = fmaf(ab, bflo(hb.x), t0); t1 = fmaf(ab, bfhi(hb.x), t1);
    t2 = fmaf(ab, bflo(hb.y), t2); t3 = fmaf(ab, bfhi(hb.y), t3);
    t0 = fmaf(ac, bflo(hc.x), t0); t1 = fmaf(ac, bfhi(hc.x), t1);
    t2 = fmaf(ac, bflo(hc.y), t2); t3 = fmaf(ac, bfhi(hc.y), t3);
    t0 = fmaf(ad_, bflo(hd.x), t0); t1 = fmaf(ad_, bfhi(hd.x), t1);
    t2 = fmaf(ad_, bflo(hd.y), t2); t3 = fmaf(ad_, bfhi(hd.y), t3);
    s0 += (bflo(pa.x) + bflo(pb.x)) + (bflo(pc.x) + bflo(pd.x));
    s1v += (bfhi(pa.x) + bfhi(pb.x)) + (bfhi(pc.x) + bfhi(pd.x));
    s2 += (bflo(pa.y) + bflo(pb.y)) + (bflo(pc.y) + bflo(pd.y));
    s3 += (bfhi(pa.y) + bfhi(pb.y)) + (bfhi(pc.y) + bfhi(pd.y));
  }
  for(; e < e1; e++){
    int sa = csr[e];
    float da = dis[sa], aa = wvE[e];
    uint2 ua = *(const uint2*)&a2[(size_t)sa*64 + l*4];
    uint2 ha = *(const uint2*)&h2[(size_t)sa*64 + l*4];
    uint2 pa = *(const uint2*)&p2[(size_t)sa*64 + l*4];
    g0 = fmaf(da, bflo(ua.x), g0); g1 = fmaf(da, bfhi(ua.x), g1);
    g2 = fmaf(da, bflo(ua.y), g2); g3 = fmaf(da, bfhi(ua.y), g3);
    t0 = fmaf(aa, bflo(ha.x), t0); t1 = fmaf(aa, bfhi(ha.x), t1);
    t2 = fmaf(aa, bflo(ha.y), t2); t3 = fmaf(aa, bfhi(ha.y), t3);
    s0 += bflo(pa.x); s1v += bfhi(pa.x); s2 += bflo(pa.y); s3 += bfhi(pa.y);
  }
  float w0 = gatew[0], w1 = gatew[1], w2 = gatew[2];
  float4 bg = *(const float4*)&gcn_b2[l*4];
  float4 bt = *(const float4*)&gat_b2[l*4];
  float4 bs = *(const float4*)&sage_bl2[l*4];
  float rd = rdenN[node];
  float ic = invc[node];
  uint2 uq = *(const uint2*)&q2[(size_t)node*64 + l*4];
  float v0 = s0*ic + bs.x + bflo(uq.x);
  float v1 = s1v*ic + bs.y + bfhi(uq.x);
  float v2 = s2*ic + bs.z + bflo(uq.y);
  float v3 = s3*ic + bs.w + bfhi(uq.y);
  float n2 = v0*v0 + v1*v1 + v2*v2 + v3*v3;
  #pragma unroll
  for(int d = 8; d >= 1; d >>= 1) n2 += __shfl_xor(n2, d, 64);
  float inv = 1.0f / fmaxf(sqrtf(n2), 1e-12f);
  float4 o;
  o.x = w0*(dc*g0 + bg.x) + w1*(t0*rd + bt.x) + w2*v0*inv;
  o.y = w0*(dc*g1 + bg.y) + w1*(t1*rd + bt.y) + w2*v1*inv;
  o.z = w0*(dc*g2 + bg.z) + w1*(t2*rd + bt.z) + w2*v2*inv;
  o.w = w0*(dc*g3 + bg.w) + w1*(t3*rd + bt.w) + w2*v3*inv;
  *(float4*)&out[(size_t)node*64 + l*4] = o;
}

// ---------------- host ----------------
extern "C" void kernel_launch(void* const* d_in, const int* in_sizes, int n_in,
                              void* d_out, int out_size, void* d_ws, size_t ws_size,
                              hipStream_t stream){
  const float* x        = (const float*)d_in[0];
  const int*   ei       = (const int*)d_in[1];
  const int*   row      = ei;
  const int*   col      = ei + NE;
  const float* gate_w1  = (const float*)d_in[2];
  const float* gate_b1  = (const float*)d_in[3];
  const float* gate_w2  = (const float*)d_in[4];
  const float* gate_b2  = (const float*)d_in[5];
  const float* gcn_w1   = (const float*)d_in[6];
  const float* gcn_b1   = (const float*)d_in[7];
  const float* bn_gamma = (const float*)d_in[8];
  const float* bn_beta  = (const float*)d_in[9];
  const float* gcn_w2   = (const float*)d_in[10];
  const float* gcn_b2   = (const float*)d_in[11];
  const float* gat_w1   = (const float*)d_in[12];
  const float* gat_as1  = (const float*)d_in[13];
  const float* gat_ad1  = (const float*)d_in[14];
  const float* gat_b1   = (const float*)d_in[15];
  const float* gat_w2   = (const float*)d_in[16];
  const float* gat_as2  = (const float*)d_in[17];
  const float* gat_ad2  = (const float*)d_in[18];
  const float* gat_b2   = (const float*)d_in[19];
  const float* sage_wl1 = (const float*)d_in[20];
  const float* sage_bl1 = (const float*)d_in[21];
  const float* sage_wr1 = (const float*)d_in[22];
  const float* sage_wl2 = (const float*)d_in[23];
  const float* sage_bl2 = (const float*)d_in[24];
  const float* sage_wr2 = (const float*)d_in[25];
  float* out = (float*)d_out;

  char* wp = (char*)d_ws;
  auto alloc = [&](size_t bytes)->char*{ char* p = wp; wp += (bytes + 255) & ~(size_t)255; return p; };
  // zero-init region (contiguous): cnt, cursor, gsum, total
  int*   cnt    = (int*)  alloc((size_t)NN*4);
  int*   cursor = (int*)  alloc((size_t)NN*4);
  float* gsum   = (float*)alloc(64*4);
  int*   total  = (int*)  alloc(256);
  size_t zbytes = (size_t)(wp - (char*)cnt);
  int*   offs   = (int*)  alloc((size_t)NN*4);
  int*   csr    = (int*)  alloc((size_t)NE*4);
  float* dis    = (float*)alloc((size_t)NN*4);
  float* invc   = (float*)alloc((size_t)NN*4);
  float* gatew  = (float*)alloc(16);
  float* wsd    = (float*)alloc(64*8*4);
  float* asrc1  = (float*)alloc((size_t)NN*4*4);
  float* adst1  = (float*)alloc((size_t)NN*4*4);
  float* asrc2  = (float*)alloc((size_t)NN*4);
  float* adst2  = (float*)alloc((size_t)NN*4);
  float* wvE1   = (float*)alloc((size_t)NE*4*4);
  float* rden1  = (float*)alloc((size_t)NN*4*4);
  float* wvS1   = (float*)alloc((size_t)NN*4*4);
  float* wvE2   = (float*)alloc((size_t)NE*4);
  float* rden2  = (float*)alloc((size_t)NN*4);
  float* wvS2   = (float*)alloc((size_t)NN*4);
  unsigned short* xb  = (unsigned short*)alloc((size_t)NN*64*2);
  unsigned short* a0  = (unsigned short*)alloc((size_t)NN*64*2);  // also a2
  unsigned short* a1  = (unsigned short*)alloc((size_t)NN*64*2);
  unsigned short* p1  = (unsigned short*)alloc((size_t)NN*64*2);  // also p2
  unsigned short* q1  = (unsigned short*)alloc((size_t)NN*64*2);  // also q2
  unsigned short* s1  = (unsigned short*)alloc((size_t)NN*64*2);
  unsigned short* h1  = (unsigned short*)alloc((size_t)NN*256*2); // also h2
  unsigned short* gath= (unsigned short*)alloc((size_t)NN*256*2);
  unsigned short* a2 = a0;
  unsigned short* p2 = p1;
  unsigned short* q2 = q1;
  unsigned short* h2 = h1;

  hipMemsetAsync(cnt, 0, zbytes, stream);

  const int gN  = (NN + 63) / 64;   // 782
  const int g4  = NN / 4;           // 12500
  const int g16 = NN / 16;          // 3125
  const int gA  = (NN + 255) / 256; // 196

  k_count<<<(NE+255)/256, 256, 0, stream>>>(col, cnt, NE);
  k_alloc<<<gA, 256, 0, stream>>>(cnt, offs, dis, invc, total, NN);
  k_fill <<<(NE+255)/256, 256, 0, stream>>>(row, col, offs, cursor, csr, NE);
  k_castsum<<<256, 256, 0, stream>>>(x, xb, gsum, NN);
  k_gate  <<<1, 64, 0, stream>>>(gsum, gate_w1, gate_b1, gate_w2, gate_b2, gatew);
  k_fold1 <<<1, 256, 0, stream>>>(gat_w1, gat_as1, gat_ad1, wsd);
  k_attdotx<<<g16, 256, 0, stream>>>(xb, wsd, asrc1, adst1, NN);
  k_edgew1<<<g4, 256, 0, stream>>>(asrc1, adst1, offs, cnt, csr, wvE1, rden1, wvS1, NN);

  // ---- layer-1 matmuls: gcn/sage (3) + gat1 slabs (4) in one dispatch ----
  {
    MMP p = {};
    p.e[0] = {xb, gcn_w1,   a0, 0,   64, 64};
    p.e[1] = {xb, sage_wl1, p1, 0,   64, 64};
    p.e[2] = {xb, sage_wr1, q1, 0,   64, 64};
    p.e[3] = {xb, gat_w1,   h1, 0,   256, 256};
    p.e[4] = {xb, gat_w1,   h1, 64,  256, 256};
    p.e[5] = {xb, gat_w1,   h1, 128, 256, 256};
    p.e[6] = {xb, gat_w1,   h1, 192, 256, 256};
    p.K = 64; p.N = NN;
    k_mm_mfma<<<dim3(gN,7), 256, 0, stream>>>(p);
  }

  k_agg_gat1v<<<g4, 256, 0, stream>>>(h1, wvE1, rden1, wvS1, offs, cnt, csr, gat_b1, gath, NN);
  k_agg_l1<<<g16, 256, 0, stream>>>(a0, p1, q1, dis, invc, offs, cnt, csr,
                                    gcn_b1, bn_gamma, bn_beta, sage_bl1, a1, s1, NN);

  // ---- GAT layer 2 matmul (K=256) ----
  {
    MMP p = {};
    p.e[0] = {gath, gat_w2, h2, 0, 64, 64};
    p.K = 256; p.N = NN;
    k_mm_mfma<<<dim3(gN,1), 256, 0, stream>>>(p);
  }
  k_attdot1<<<g4, 256, 0, stream>>>(h2, gat_as2, gat_ad2, asrc2, adst2, NN);
  k_edgew2<<<g4, 256, 0, stream>>>(asrc2, adst2, offs, cnt, csr, wvE2, rden2, wvS2, NN);

  // ---- layer-2 matmuls ----
  {
    MMP p = {};
    p.e[0] = {a1, gcn_w2,   a2, 0, 64, 64};
    p.e[1] = {s1, sage_wl2, p2, 0, 64, 64};
    p.e[2] = {s1, sage_wr2, q2, 0, 64, 64};
    p.K = 64; p.N = NN;
    k_mm_mfma<<<dim3(gN,3), 256, 0, stream>>>(p);
  }

  // ---- fused final aggregation ----
  k_agg_final<<<g16, 256, 0, stream>>>(a2, h2, p2, q2, dis, invc, wvE2, rden2, wvS2,
                                       offs, cnt, csr, gcn_b2, gat_b2, sage_bl2, gatew, out, NN);
}

// Round 7
// 370.904 us; speedup vs baseline: 1.9746x; 1.0566x over previous
//
#include <hip/hip_runtime.h>
#include <hip/hip_bf16.h>
#include <math.h>

#define NN 50000
#define NE 400000

typedef __attribute__((ext_vector_type(8))) short bf16x8;
typedef __attribute__((ext_vector_type(4))) float f32x4;

// ---------------- helpers ----------------
__device__ __forceinline__ float lrelu(float v){ return v > 0.f ? v : 0.2f*v; }
__device__ __forceinline__ float elu1(float v){ return v > 0.f ? v : expm1f(v); }
__device__ __forceinline__ float bflo(unsigned int u){ return __uint_as_float(u << 16); }
__device__ __forceinline__ float bfhi(unsigned int u){ return __uint_as_float(u & 0xffff0000u); }
__device__ __forceinline__ unsigned short f2bf(float f){
  __hip_bfloat16 h = __float2bfloat16(f);
  return *(unsigned short*)&h;
}
__device__ __forceinline__ unsigned int pack2(float lo, float hi){
  return (unsigned int)f2bf(lo) | ((unsigned int)f2bf(hi) << 16);
}

// ---------------- CSR build ----------------
__global__ void k_count(const int* __restrict__ col, int* __restrict__ cnt, int E){
  int e = blockIdx.x*blockDim.x + threadIdx.x;
  if(e < E) atomicAdd(&cnt[col[e]], 1);
}

__global__ void k_alloc(const int* __restrict__ cnt, int* __restrict__ offs,
                        float* __restrict__ dis, float* __restrict__ invc,
                        int* __restrict__ total, int N){
  int i = blockIdx.x*blockDim.x + threadIdx.x;
  int lane = threadIdx.x & 63;
  int v = (i < N) ? cnt[i] : 0;
  int x = v;
  #pragma unroll
  for(int d = 1; d < 64; d <<= 1){ int t = __shfl_up(x, d, 64); if(lane >= d) x += t; }
  int base = 0;
  if(lane == 63 && x > 0) base = atomicAdd(total, x);
  base = __shfl(base, 63, 64);
  if(i < N){
    offs[i] = base + x - v;
    dis[i]  = 1.0f / sqrtf((float)(v + 1));
    invc[i] = 1.0f / fmaxf((float)v, 1.0f);
  }
}

__global__ void k_fill(const int* __restrict__ row, const int* __restrict__ col,
                       const int* __restrict__ offs, int* __restrict__ cursor,
                       int* __restrict__ csr, int E){
  int e = blockIdx.x*blockDim.x + threadIdx.x;
  if(e < E){
    int c = col[e];
    int pos = offs[c] + atomicAdd(&cursor[c], 1);
    csr[pos] = row[e];
  }
}

// ---------------- cast x -> bf16 + column sums for gate ----------------
__global__ void k_castsum(const float* __restrict__ x, unsigned short* __restrict__ xb,
                          float* __restrict__ gsum, int N){
  __shared__ float part[4][64];
  int lane = threadIdx.x & 63, w = threadIdx.x >> 6;
  float s = 0.f;
  for(int r = blockIdx.x*4 + w; r < N; r += gridDim.x*4){
    float v = x[(size_t)r*64 + lane];
    xb[(size_t)r*64 + lane] = f2bf(v);
    s += v;
  }
  part[w][lane] = s;
  __syncthreads();
  if(w == 0) atomicAdd(&gsum[lane], part[0][lane]+part[1][lane]+part[2][lane]+part[3][lane]);
}

__global__ void k_gate(const float* __restrict__ gsum,
                       const float* __restrict__ w1, const float* __restrict__ b1,
                       const float* __restrict__ w2, const float* __restrict__ b2,
                       float* __restrict__ gatew){
  __shared__ float g[64]; __shared__ float hid[64]; __shared__ float lg[3];
  int t = threadIdx.x;
  g[t] = gsum[t] * (1.0f/(float)NN);
  __syncthreads();
  float acc = b1[t];
  for(int i = 0; i < 64; i++) acc += g[i]*w1[i*64 + t];
  hid[t] = fmaxf(acc, 0.f);
  __syncthreads();
  if(t < 3){
    float a = b2[t];
    for(int j = 0; j < 64; j++) a += hid[j]*w2[j*3 + t];
    lg[t] = a;
  }
  __syncthreads();
  if(t == 0){
    float m = fmaxf(lg[0], fmaxf(lg[1], lg[2]));
    float e0 = expf(lg[0]-m), e1 = expf(lg[1]-m), e2 = expf(lg[2]-m);
    float s = e0 + e1 + e2;
    gatew[0] = e0/s; gatew[1] = e1/s; gatew[2] = e2/s;
  }
}

// ---------------- fold GAT1 attention vectors through W ----------------
__global__ void k_fold1(const float* __restrict__ w1, const float* __restrict__ as,
                        const float* __restrict__ ad, float* __restrict__ wsd){
  int t = threadIdx.x;            // 256
  int k = t & 63, h = t >> 6;
  float ssrc = 0.f, sdst = 0.f;
  for(int c = 0; c < 64; c++){
    float w = w1[k*256 + h*64 + c];
    ssrc += w * as[h*64 + c];
    sdst += w * ad[h*64 + c];
  }
  wsd[k*8 + h] = ssrc;
  wsd[k*8 + 4 + h] = sdst;
}

// ---------------- asrc1/adst1 = xb @ Wsd  (16 lanes per node) ----------------
__global__ void k_attdotx(const unsigned short* __restrict__ xb, const float* __restrict__ wsd,
                          float* __restrict__ asrc, float* __restrict__ adst, int N){
  __shared__ float ws[64*8];
  int tid = threadIdx.x;
  ws[tid] = wsd[tid];
  ws[tid + 256] = wsd[tid + 256];
  __syncthreads();
  int node = blockIdx.x*16 + (tid >> 4);
  int l = tid & 15;
  if(node >= N) return;
  uint2 u = *(const uint2*)&xb[(size_t)node*64 + l*4];
  float v0 = bflo(u.x), v1 = bfhi(u.x), v2 = bflo(u.y), v3 = bfhi(u.y);
  float s[8];
  #pragma unroll
  for(int h = 0; h < 8; h++){
    s[h] = v0*ws[(l*4+0)*8+h] + v1*ws[(l*4+1)*8+h] + v2*ws[(l*4+2)*8+h] + v3*ws[(l*4+3)*8+h];
  }
  #pragma unroll
  for(int d = 8; d >= 1; d >>= 1){
    #pragma unroll
    for(int h = 0; h < 8; h++) s[h] += __shfl_xor(s[h], d, 16);
  }
  if(l == 0){
    float4 o1; o1.x = s[0]; o1.y = s[1]; o1.z = s[2]; o1.w = s[3];
    float4 o2; o2.x = s[4]; o2.y = s[5]; o2.z = s[6]; o2.w = s[7];
    *(float4*)&asrc[node*4] = o1;
    *(float4*)&adst[node*4] = o2;
  }
}

// ---------------- GAT edge weights ----------------
__global__ void k_edgew1(const float* __restrict__ asrc, const float* __restrict__ adst,
                         const int* __restrict__ offs, const int* __restrict__ cnt,
                         const int* __restrict__ csr,
                         float* __restrict__ wvE, float* __restrict__ rdenN,
                         float* __restrict__ wvS, int N){
  int node = blockIdx.x*4 + (threadIdx.x >> 6);
  int lane = threadIdx.x & 63;
  if(node >= N) return;
  float4 ad = *(const float4*)&adst[node*4];
  float a0 = 0.f, a1 = 0.f, a2 = 0.f, a3 = 0.f;
  int e0 = offs[node], e1 = e0 + cnt[node];
  for(int e = e0 + lane; e < e1; e += 64){
    int s = csr[e];
    float4 as = *(const float4*)&asrc[s*4];
    float4 w;
    w.x = expf(lrelu(as.x + ad.x));
    w.y = expf(lrelu(as.y + ad.y));
    w.z = expf(lrelu(as.z + ad.z));
    w.w = expf(lrelu(as.w + ad.w));
    a0 += w.x; a1 += w.y; a2 += w.z; a3 += w.w;
    *(float4*)&wvE[(size_t)e*4] = w;
  }
  #pragma unroll
  for(int d = 32; d >= 1; d >>= 1){
    a0 += __shfl_xor(a0, d, 64); a1 += __shfl_xor(a1, d, 64);
    a2 += __shfl_xor(a2, d, 64); a3 += __shfl_xor(a3, d, 64);
  }
  float4 asl = *(const float4*)&asrc[node*4];
  float4 ws;
  ws.x = expf(lrelu(asl.x + ad.x));
  ws.y = expf(lrelu(asl.y + ad.y));
  ws.z = expf(lrelu(asl.z + ad.z));
  ws.w = expf(lrelu(asl.w + ad.w));
  if(lane == 0){
    float4 rd;
    rd.x = 1.0f/(a0 + ws.x); rd.y = 1.0f/(a1 + ws.y);
    rd.z = 1.0f/(a2 + ws.z); rd.w = 1.0f/(a3 + ws.w);
    *(float4*)&rdenN[node*4] = rd;
    *(float4*)&wvS[node*4] = ws;
  }
}

__global__ void k_edgew2(const float* __restrict__ asrc, const float* __restrict__ adst,
                         const int* __restrict__ offs, const int* __restrict__ cnt,
                         const int* __restrict__ csr,
                         float* __restrict__ wvE, float* __restrict__ rdenN,
                         float* __restrict__ wvS, int N){
  int node = blockIdx.x*4 + (threadIdx.x >> 6);
  int lane = threadIdx.x & 63;
  if(node >= N) return;
  float ad = adst[node];
  float acc = 0.f;
  int e0 = offs[node], e1 = e0 + cnt[node];
  for(int e = e0 + lane; e < e1; e += 64){
    float w = expf(lrelu(asrc[csr[e]] + ad));
    acc += w;
    wvE[e] = w;
  }
  #pragma unroll
  for(int d = 32; d >= 1; d >>= 1) acc += __shfl_xor(acc, d, 64);
  float ws = expf(lrelu(asrc[node] + ad));
  if(lane == 0){
    rdenN[node] = 1.0f/(acc + ws);
    wvS[node] = ws;
  }
}

// ---------------- layer-1 one-pass pre-aggregation over xb ----------------
// per node: z[4][64] = (sum_e wv_h * x_s + wvS_h * x_n) * rd_h   (GAT, x-space)
//           agcnx    = dc*(dc*x_n + sum_e dis_s * x_s)           (GCN)
//           asagex   = (sum_e x_s) * invc                        (SAGE mean)
__global__ void k_aggx(const unsigned short* __restrict__ xb,
                       const float* __restrict__ wvE, const float* __restrict__ rden,
                       const float* __restrict__ wvS,
                       const float* __restrict__ dis, const float* __restrict__ invc,
                       const int* __restrict__ offs, const int* __restrict__ cnt,
                       const int* __restrict__ csr,
                       unsigned short* __restrict__ z, unsigned short* __restrict__ agcnx,
                       unsigned short* __restrict__ asagex, int N){
  int node = blockIdx.x*4 + (threadIdx.x >> 6);
  int lane = threadIdx.x & 63;
  if(node >= N) return;
  int half = lane >> 5, subl = lane & 31;      // subl*2, subl*2+1 channels
  float zg[4][2] = {{0,0},{0,0},{0,0},{0,0}};
  float gg[2] = {0,0}, ssv[2] = {0,0};
  int e0 = offs[node], e1 = e0 + cnt[node];
  #pragma unroll 2
  for(int e = e0 + half; e < e1; e += 2){
    int s = csr[e];
    float4 w4 = *(const float4*)&wvE[(size_t)e*4];
    float ds = dis[s];
    unsigned int u = *(const unsigned int*)&xb[(size_t)s*64 + subl*2];
    float xl = bflo(u), xh = bfhi(u);
    zg[0][0] = fmaf(w4.x, xl, zg[0][0]); zg[0][1] = fmaf(w4.x, xh, zg[0][1]);
    zg[1][0] = fmaf(w4.y, xl, zg[1][0]); zg[1][1] = fmaf(w4.y, xh, zg[1][1]);
    zg[2][0] = fmaf(w4.z, xl, zg[2][0]); zg[2][1] = fmaf(w4.z, xh, zg[2][1]);
    zg[3][0] = fmaf(w4.w, xl, zg[3][0]); zg[3][1] = fmaf(w4.w, xh, zg[3][1]);
    gg[0] = fmaf(ds, xl, gg[0]); gg[1] = fmaf(ds, xh, gg[1]);
    ssv[0] += xl; ssv[1] += xh;
  }
  #pragma unroll
  for(int h = 0; h < 4; h++){
    zg[h][0] += __shfl_xor(zg[h][0], 32, 64);
    zg[h][1] += __shfl_xor(zg[h][1], 32, 64);
  }
  gg[0] += __shfl_xor(gg[0], 32, 64); gg[1] += __shfl_xor(gg[1], 32, 64);
  ssv[0] += __shfl_xor(ssv[0], 32, 64); ssv[1] += __shfl_xor(ssv[1], 32, 64);
  if(half == 0){
    unsigned int un = *(const unsigned int*)&xb[(size_t)node*64 + subl*2];
    float xl = bflo(un), xh = bfhi(un);
    float4 ws4 = *(const float4*)&wvS[node*4];
    float4 rd4 = *(const float4*)&rden[node*4];
    unsigned int* zp = (unsigned int*)&z[(size_t)node*256 + subl*2];
    zp[0]   = pack2((zg[0][0] + ws4.x*xl)*rd4.x, (zg[0][1] + ws4.x*xh)*rd4.x);
    zp[32]  = pack2((zg[1][0] + ws4.y*xl)*rd4.y, (zg[1][1] + ws4.y*xh)*rd4.y);
    zp[64]  = pack2((zg[2][0] + ws4.z*xl)*rd4.z, (zg[2][1] + ws4.z*xh)*rd4.z);
    zp[96]  = pack2((zg[3][0] + ws4.w*xl)*rd4.w, (zg[3][1] + ws4.w*xh)*rd4.w);
    float dc = dis[node], ic = invc[node];
    *(unsigned int*)&agcnx[(size_t)node*64 + subl*2] =
        pack2(dc*fmaf(dc, xl, gg[0]), dc*fmaf(dc, xh, gg[1]));
    *(unsigned int*)&asagex[(size_t)node*64 + subl*2] = pack2(ssv[0]*ic, ssv[1]*ic);
  }
}

// ---------------- layer-2 one-pass pre-aggregation over a1 / s1 / h2 ----------------
__global__ void k_aggf(const unsigned short* __restrict__ a1, const unsigned short* __restrict__ s1,
                       const unsigned short* __restrict__ h2,
                       const float* __restrict__ wvE, const float* __restrict__ rden,
                       const float* __restrict__ wvS,
                       const float* __restrict__ dis, const float* __restrict__ invc,
                       const int* __restrict__ offs, const int* __restrict__ cnt,
                       const int* __restrict__ csr,
                       unsigned short* __restrict__ A2agg, unsigned short* __restrict__ S2agg,
                       unsigned short* __restrict__ T2, int N){
  int node = blockIdx.x*4 + (threadIdx.x >> 6);
  int lane = threadIdx.x & 63;
  if(node >= N) return;
  int half = lane >> 5, subl = lane & 31;
  float aa[2] = {0,0}, ss[2] = {0,0}, tt[2] = {0,0};
  int e0 = offs[node], e1 = e0 + cnt[node];
  #pragma unroll 2
  for(int e = e0 + half; e < e1; e += 2){
    int s = csr[e];
    float ds = dis[s];
    float wv = wvE[e];
    unsigned int ua = *(const unsigned int*)&a1[(size_t)s*64 + subl*2];
    unsigned int us = *(const unsigned int*)&s1[(size_t)s*64 + subl*2];
    unsigned int uh = *(const unsigned int*)&h2[(size_t)s*64 + subl*2];
    aa[0] = fmaf(ds, bflo(ua), aa[0]); aa[1] = fmaf(ds, bfhi(ua), aa[1]);
    ss[0] += bflo(us); ss[1] += bfhi(us);
    tt[0] = fmaf(wv, bflo(uh), tt[0]); tt[1] = fmaf(wv, bfhi(uh), tt[1]);
  }
  aa[0] += __shfl_xor(aa[0], 32, 64); aa[1] += __shfl_xor(aa[1], 32, 64);
  ss[0] += __shfl_xor(ss[0], 32, 64); ss[1] += __shfl_xor(ss[1], 32, 64);
  tt[0] += __shfl_xor(tt[0], 32, 64); tt[1] += __shfl_xor(tt[1], 32, 64);
  if(half == 0){
    unsigned int uan = *(const unsigned int*)&a1[(size_t)node*64 + subl*2];
    unsigned int uhn = *(const unsigned int*)&h2[(size_t)node*64 + subl*2];
    float dc = dis[node], ic = invc[node];
    float rd = rden[node], wss = wvS[node];
    *(unsigned int*)&A2agg[(size_t)node*64 + subl*2] =
        pack2(dc*fmaf(dc, bflo(uan), aa[0]), dc*fmaf(dc, bfhi(uan), aa[1]));
    *(unsigned int*)&S2agg[(size_t)node*64 + subl*2] = pack2(ss[0]*ic, ss[1]*ic);
    *(unsigned int*)&T2[(size_t)node*64 + subl*2] =
        pack2(fmaf(wss, bflo(uhn), tt[0])*rd, fmaf(wss, bfhi(uhn), tt[1])*rd);
  }
}

// ---------------- MFMA bf16 matmul with fused epilogues ----------------
// ep: 0 = plain bf16 store; 1 = BN+relu; 2 = ELU; 3 = sage (+bias, row L2-norm, relu);
//     4 = plain store + row-dot with p1/p2 -> y1/y2 (attention fold)
struct MME {
  const unsigned short* A; const float* W;
  const unsigned short* A2; const float* W2;   // optional second segment (K2=64, lda2=64, ldw2=64)
  unsigned short* C;
  const float* b; const float* p1; const float* p2;
  float* y1; float* y2;
  int lda, ldw, ldc, col0, K, ep;
};
struct MMP { MME e[6]; int N; };

__global__ __launch_bounds__(256) void k_mm_mfma(MMP p){
  __shared__ unsigned short Wt[64*264];
  MME m = p.e[blockIdx.y];
  const int N = p.N;
  int tid = threadIdx.x;
  const int K = m.K, pitch = K + 8;
  {
    int n = tid & 63;
    for(int k = tid >> 6; k < K; k += 4)
      Wt[n*pitch + k] = f2bf(m.W[(size_t)k*m.ldw + m.col0 + n]);
  }
  __syncthreads();
  int w = tid >> 6, lane = tid & 63, quad = lane >> 4, m16 = lane & 15;
  int rowa = blockIdx.x*64 + w*16 + m16;
  int rowc = rowa < N ? rowa : N - 1;
  f32x4 acc[4];
  #pragma unroll
  for(int t = 0; t < 4; t++){ acc[t][0]=0.f; acc[t][1]=0.f; acc[t][2]=0.f; acc[t][3]=0.f; }
  for(int kc = 0; kc < K; kc += 64){
    bf16x8 a0 = *(const bf16x8*)&m.A[(size_t)rowc*m.lda + kc + quad*8];
    bf16x8 a1 = *(const bf16x8*)&m.A[(size_t)rowc*m.lda + kc + 32 + quad*8];
    #pragma unroll
    for(int t = 0; t < 4; t++){
      bf16x8 b0 = *(const bf16x8*)&Wt[(t*16 + m16)*pitch + kc + quad*8];
      bf16x8 b1 = *(const bf16x8*)&Wt[(t*16 + m16)*pitch + kc + 32 + quad*8];
      acc[t] = __builtin_amdgcn_mfma_f32_16x16x32_bf16(a0, b0, acc[t], 0, 0, 0);
      acc[t] = __builtin_amdgcn_mfma_f32_16x16x32_bf16(a1, b1, acc[t], 0, 0, 0);
    }
  }
  if(m.A2){
    __syncthreads();
    {
      int n = tid & 63;
      for(int k = tid >> 6; k < 64; k += 4)
        Wt[n*72 + k] = f2bf(m.W2[(size_t)k*64 + n]);
    }
    __syncthreads();
    bf16x8 a0 = *(const bf16x8*)&m.A2[(size_t)rowc*64 + quad*8];
    bf16x8 a1 = *(const bf16x8*)&m.A2[(size_t)rowc*64 + 32 + quad*8];
    #pragma unroll
    for(int t = 0; t < 4; t++){
      bf16x8 b0 = *(const bf16x8*)&Wt[(t*16 + m16)*72 + quad*8];
      bf16x8 b1 = *(const bf16x8*)&Wt[(t*16 + m16)*72 + 32 + quad*8];
      acc[t] = __builtin_amdgcn_mfma_f32_16x16x32_bf16(a0, b0, acc[t], 0, 0, 0);
      acc[t] = __builtin_amdgcn_mfma_f32_16x16x32_bf16(a1, b1, acc[t], 0, 0, 0);
    }
  }
  int robase = blockIdx.x*64 + w*16 + quad*4;
  if(m.ep == 3){
    // sage: v = acc + b, row L2-norm (cols live on 16 lanes of this quad x 4 regs), relu
    float v[4][4], n2[4] = {0,0,0,0};
    #pragma unroll
    for(int t = 0; t < 4; t++){
      float bv = m.b[m.col0 + t*16 + m16];
      #pragma unroll
      for(int r = 0; r < 4; r++){ v[t][r] = acc[t][r] + bv; n2[r] = fmaf(v[t][r], v[t][r], n2[r]); }
    }
    #pragma unroll
    for(int d = 8; d >= 1; d >>= 1){
      #pragma unroll
      for(int r = 0; r < 4; r++) n2[r] += __shfl_xor(n2[r], d, 64);
    }
    float inv[4];
    #pragma unroll
    for(int r = 0; r < 4; r++) inv[r] = 1.0f / fmaxf(sqrtf(n2[r]), 1e-12f);
    #pragma unroll
    for(int t = 0; t < 4; t++){
      #pragma unroll
      for(int r = 0; r < 4; r++){
        int ro = robase + r;
        if(ro < N) m.C[(size_t)ro*m.ldc + m.col0 + t*16 + m16] = f2bf(fmaxf(v[t][r]*inv[r], 0.f));
      }
    }
    return;
  }
  #pragma unroll
  for(int t = 0; t < 4; t++){
    int col = m.col0 + t*16 + m16;
    float bv = (m.ep == 1 || m.ep == 2) ? m.b[col] : 0.f;
    float gm = (m.ep == 1) ? m.p1[col]*rsqrtf(1.0f + 1e-5f) : 0.f;
    float be = (m.ep == 1) ? m.p2[col] : 0.f;
    #pragma unroll
    for(int r = 0; r < 4; r++){
      int ro = robase + r;
      if(ro < N){
        float val = acc[t][r];
        if(m.ep == 1)      val = fmaxf((val + bv)*gm + be, 0.f);
        else if(m.ep == 2) val = elu1(val + bv);
        m.C[(size_t)ro*m.ldc + col + 0] = f2bf(val);
      }
    }
  }
  if(m.ep == 4){
    float ps[4] = {0,0,0,0}, pd[4] = {0,0,0,0};
    #pragma unroll
    for(int t = 0; t < 4; t++){
      int col = m.col0 + t*16 + m16;
      float a_ = m.p1[col], d_ = m.p2[col];
      #pragma unroll
      for(int r = 0; r < 4; r++){ ps[r] = fmaf(acc[t][r], a_, ps[r]); pd[r] = fmaf(acc[t][r], d_, pd[r]); }
    }
    #pragma unroll
    for(int d = 8; d >= 1; d >>= 1){
      #pragma unroll
      for(int r = 0; r < 4; r++){ ps[r] += __shfl_xor(ps[r], d, 64); pd[r] += __shfl_xor(pd[r], d, 64); }
    }
    if(m16 == 0){
      #pragma unroll
      for(int r = 0; r < 4; r++){
        int ro = robase + r;
        if(ro < N){ m.y1[ro] = ps[r]; m.y2[ro] = pd[r]; }
      }
    }
  }
}

// ---------------- final: GCN2 mm + SAGE2 dual mm + L2norm + GAT2 add + gate combine ----------------
__global__ __launch_bounds__(256) void k_mm_final(
    const unsigned short* __restrict__ A2agg, const float* __restrict__ gcn_w2,
    const float* __restrict__ gcn_b2,
    const unsigned short* __restrict__ S2agg, const float* __restrict__ wl2,
    const float* __restrict__ bl2,
    const unsigned short* __restrict__ s1, const float* __restrict__ wr2,
    const unsigned short* __restrict__ T2, const float* __restrict__ gat_b2,
    const float* __restrict__ gatew, float* __restrict__ out, int N){
  __shared__ unsigned short Wt[64*72];
  int tid = threadIdx.x;
  int w = tid >> 6, lane = tid & 63, quad = lane >> 4, m16 = lane & 15;
  int rowa = blockIdx.x*64 + w*16 + m16;
  int rowc = rowa < N ? rowa : N - 1;
  f32x4 accg[4], accs[4];
  #pragma unroll
  for(int t = 0; t < 4; t++){
    accg[t][0]=0.f; accg[t][1]=0.f; accg[t][2]=0.f; accg[t][3]=0.f;
    accs[t][0]=0.f; accs[t][1]=0.f; accs[t][2]=0.f; accs[t][3]=0.f;
  }
  // segment 1: A2agg @ gcn_w2
  { int n = tid & 63; for(int k = tid >> 6; k < 64; k += 4) Wt[n*72 + k] = f2bf(gcn_w2[(size_t)k*64 + n]); }
  __syncthreads();
  {
    bf16x8 a0 = *(const bf16x8*)&A2agg[(size_t)rowc*64 + quad*8];
    bf16x8 a1 = *(const bf16x8*)&A2agg[(size_t)rowc*64 + 32 + quad*8];
    #pragma unroll
    for(int t = 0; t < 4; t++){
      bf16x8 b0 = *(const bf16x8*)&Wt[(t*16 + m16)*72 + quad*8];
      bf16x8 b1 = *(const bf16x8*)&Wt[(t*16 + m16)*72 + 32 + quad*8];
      accg[t] = __builtin_amdgcn_mfma_f32_16x16x32_bf16(a0, b0, accg[t], 0, 0, 0);
      accg[t] = __builtin_amdgcn_mfma_f32_16x16x32_bf16(a1, b1, accg[t], 0, 0, 0);
    }
  }
  // segment 2: S2agg @ wl2
  __syncthreads();
  { int n = tid & 63; for(int k = tid >> 6; k < 64; k += 4) Wt[n*72 + k] = f2bf(wl2[(size_t)k*64 + n]); }
  __syncthreads();
  {
    bf16x8 a0 = *(const bf16x8*)&S2agg[(size_t)rowc*64 + quad*8];
    bf16x8 a1 = *(const bf16x8*)&S2agg[(size_t)rowc*64 + 32 + quad*8];
    #pragma unroll
    for(int t = 0; t < 4; t++){
      bf16x8 b0 = *(const bf16x8*)&Wt[(t*16 + m16)*72 + quad*8];
      bf16x8 b1 = *(const bf16x8*)&Wt[(t*16 + m16)*72 + 32 + quad*8];
      accs[t] = __builtin_amdgcn_mfma_f32_16x16x32_bf16(a0, b0, accs[t], 0, 0, 0);
      accs[t] = __builtin_amdgcn_mfma_f32_16x16x32_bf16(a1, b1, accs[t], 0, 0, 0);
    }
  }
  // segment 3: s1 @ wr2
  __syncthreads();
  { int n = tid & 63; for(int k = tid >> 6; k < 64; k += 4) Wt[n*72 + k] = f2bf(wr2[(size_t)k*64 + n]); }
  __syncthreads();
  {
    bf16x8 a0 = *(const bf16x8*)&s1[(size_t)rowc*64 + quad*8];
    bf16x8 a1 = *(const bf16x8*)&s1[(size_t)rowc*64 + 32 + quad*8];
    #pragma unroll
    for(int t = 0; t < 4; t++){
      bf16x8 b0 = *(const bf16x8*)&Wt[(t*16 + m16)*72 + quad*8];
      bf16x8 b1 = *(const bf16x8*)&Wt[(t*16 + m16)*72 + 32 + quad*8];
      accs[t] = __builtin_amdgcn_mfma_f32_16x16x32_bf16(a0, b0, accs[t], 0, 0, 0);
      accs[t] = __builtin_amdgcn_mfma_f32_16x16x32_bf16(a1, b1, accs[t], 0, 0, 0);
    }
  }
  // epilogue
  float w0 = gatew[0], w1 = gatew[1], w2 = gatew[2];
  int robase = blockIdx.x*64 + w*16 + quad*4;
  float vs[4][4], n2[4] = {0,0,0,0};
  #pragma unroll
  for(int t = 0; t < 4; t++){
    float bsv = bl2[t*16 + m16];
    #pragma unroll
    for(int r = 0; r < 4; r++){ vs[t][r] = accs[t][r] + bsv; n2[r] = fmaf(vs[t][r], vs[t][r], n2[r]); }
  }
  #pragma unroll
  for(int d = 8; d >= 1; d >>= 1){
    #pragma unroll
    for(int r = 0; r < 4; r++) n2[r] += __shfl_xor(n2[r], d, 64);
  }
  float inv[4];
  #pragma unroll
  for(int r = 0; r < 4; r++) inv[r] = 1.0f / fmaxf(sqrtf(n2[r]), 1e-12f);
  #pragma unroll
  for(int t = 0; t < 4; t++){
    int col = t*16 + m16;
    float bg = gcn_b2[col], bt = gat_b2[col];
    #pragma unroll
    for(int r = 0; r < 4; r++){
      int ro = robase + r;
      if(ro < N){
        float t2 = bflo((unsigned int)T2[(size_t)ro*64 + col]);
        out[(size_t)ro*64 + col] = w0*(accg[t][r] + bg) + w1*(t2 + bt) + w2*vs[t][r]*inv[r];
      }
    }
  }
}

// ---------------- host ----------------
extern "C" void kernel_launch(void* const* d_in, const int* in_sizes, int n_in,
                              void* d_out, int out_size, void* d_ws, size_t ws_size,
                              hipStream_t stream){
  const float* x        = (const float*)d_in[0];
  const int*   ei       = (const int*)d_in[1];
  const int*   row      = ei;
  const int*   col      = ei + NE;
  const float* gate_w1  = (const float*)d_in[2];
  const float* gate_b1  = (const float*)d_in[3];
  const float* gate_w2  = (const float*)d_in[4];
  const float* gate_b2  = (const float*)d_in[5];
  const float* gcn_w1   = (const float*)d_in[6];
  const float* gcn_b1   = (const float*)d_in[7];
  const float* bn_gamma = (const float*)d_in[8];
  const float* bn_beta  = (const float*)d_in[9];
  const float* gcn_w2   = (const float*)d_in[10];
  const float* gcn_b2   = (const float*)d_in[11];
  const float* gat_w1   = (const float*)d_in[12];
  const float* gat_as1  = (const float*)d_in[13];
  const float* gat_ad1  = (const float*)d_in[14];
  const float* gat_b1   = (const float*)d_in[15];
  const float* gat_w2   = (const float*)d_in[16];
  const float* gat_as2  = (const float*)d_in[17];
  const float* gat_ad2  = (const float*)d_in[18];
  const float* gat_b2   = (const float*)d_in[19];
  const float* sage_wl1 = (const float*)d_in[20];
  const float* sage_bl1 = (const float*)d_in[21];
  const float* sage_wr1 = (const float*)d_in[22];
  const float* sage_wl2 = (const float*)d_in[23];
  const float* sage_bl2 = (const float*)d_in[24];
  const float* sage_wr2 = (const float*)d_in[25];
  float* out = (float*)d_out;

  char* wp = (char*)d_ws;
  auto alloc = [&](size_t bytes)->char*{ char* p = wp; wp += (bytes + 255) & ~(size_t)255; return p; };
  // zero-init region (contiguous): cnt, cursor, gsum, total
  int*   cnt    = (int*)  alloc((size_t)NN*4);
  int*   cursor = (int*)  alloc((size_t)NN*4);
  float* gsum   = (float*)alloc(64*4);
  int*   total  = (int*)  alloc(256);
  size_t zbytes = (size_t)(wp - (char*)cnt);
  int*   offs   = (int*)  alloc((size_t)NN*4);
  int*   csr    = (int*)  alloc((size_t)NE*4);
  float* dis    = (float*)alloc((size_t)NN*4);
  float* invc   = (float*)alloc((size_t)NN*4);
  float* gatew  = (float*)alloc(16);
  float* wsd    = (float*)alloc(64*8*4);
  float* asrc1  = (float*)alloc((size_t)NN*4*4);
  float* adst1  = (float*)alloc((size_t)NN*4*4);
  float* asrc2  = (float*)alloc((size_t)NN*4);
  float* adst2  = (float*)alloc((size_t)NN*4);
  float* wvE1   = (float*)alloc((size_t)NE*4*4);
  float* rden1  = (float*)alloc((size_t)NN*4*4);
  float* wvS1   = (float*)alloc((size_t)NN*4*4);
  float* wvE2   = (float*)alloc((size_t)NE*4);
  float* rden2  = (float*)alloc((size_t)NN*4);
  float* wvS2   = (float*)alloc((size_t)NN*4);
  unsigned short* xb     = (unsigned short*)alloc((size_t)NN*64*2);
  unsigned short* z      = (unsigned short*)alloc((size_t)NN*256*2);
  unsigned short* agcnx  = (unsigned short*)alloc((size_t)NN*64*2);
  unsigned short* asagex = (unsigned short*)alloc((size_t)NN*64*2);
  unsigned short* a1     = (unsigned short*)alloc((size_t)NN*64*2);
  unsigned short* s1     = (unsigned short*)alloc((size_t)NN*64*2);
  unsigned short* gath   = (unsigned short*)alloc((size_t)NN*256*2);
  unsigned short* h2     = (unsigned short*)alloc((size_t)NN*64*2);
  unsigned short* A2agg  = (unsigned short*)alloc((size_t)NN*64*2);
  unsigned short* S2agg  = (unsigned short*)alloc((size_t)NN*64*2);
  unsigned short* T2     = (unsigned short*)alloc((size_t)NN*64*2);

  hipMemsetAsync(cnt, 0, zbytes, stream);

  const int gN  = (NN + 63) / 64;   // 782
  const int g4  = NN / 4;           // 12500
  const int g16 = NN / 16;          // 3125
  const int gA  = (NN + 255) / 256; // 196

  k_count<<<(NE+255)/256, 256, 0, stream>>>(col, cnt, NE);
  k_alloc<<<gA, 256, 0, stream>>>(cnt, offs, dis, invc, total, NN);
  k_fill <<<(NE+255)/256, 256, 0, stream>>>(row, col, offs, cursor, csr, NE);
  k_castsum<<<256, 256, 0, stream>>>(x, xb, gsum, NN);
  k_gate  <<<1, 64, 0, stream>>>(gsum, gate_w1, gate_b1, gate_w2, gate_b2, gatew);
  k_fold1 <<<1, 256, 0, stream>>>(gat_w1, gat_as1, gat_ad1, wsd);
  k_attdotx<<<g16, 256, 0, stream>>>(xb, wsd, asrc1, adst1, NN);
  k_edgew1<<<g4, 256, 0, stream>>>(asrc1, adst1, offs, cnt, csr, wvE1, rden1, wvS1, NN);

  // ---- layer-1 one-pass pre-aggregation over xb ----
  k_aggx<<<g4, 256, 0, stream>>>(xb, wvE1, rden1, wvS1, dis, invc, offs, cnt, csr,
                                 z, agcnx, asagex, NN);

  // ---- layer-1 matmuls with fused activations (6 entries, one dispatch) ----
  {
    MMP p = {};
    p.N = NN;
    p.e[0] = {agcnx, gcn_w1, nullptr, nullptr, a1, gcn_b1, bn_gamma, bn_beta,
              nullptr, nullptr, 64, 64, 64, 0, 64, 1};
    p.e[1] = {asagex, sage_wl1, xb, sage_wr1, s1, sage_bl1, nullptr, nullptr,
              nullptr, nullptr, 64, 64, 64, 0, 64, 3};
    for(int hd = 0; hd < 4; hd++)
      p.e[2+hd] = {z + hd*64, gat_w1, nullptr, nullptr, gath, gat_b1, nullptr, nullptr,
                   nullptr, nullptr, 256, 256, 256, hd*64, 64, 2};
    k_mm_mfma<<<dim3(gN,6), 256, 0, stream>>>(p);
  }

  // ---- GAT layer 2 matmul (K=256) + folded attention dots ----
  {
    MMP p = {};
    p.N = NN;
    p.e[0] = {gath, gat_w2, nullptr, nullptr, h2, nullptr, gat_as2, gat_ad2,
              asrc2, adst2, 256, 64, 64, 0, 256, 4};
    k_mm_mfma<<<dim3(gN,1), 256, 0, stream>>>(p);
  }
  k_edgew2<<<g4, 256, 0, stream>>>(asrc2, adst2, offs, cnt, csr, wvE2, rden2, wvS2, NN);

  // ---- layer-2 one-pass pre-aggregation ----
  k_aggf<<<g4, 256, 0, stream>>>(a1, s1, h2, wvE2, rden2, wvS2, dis, invc,
                                 offs, cnt, csr, A2agg, S2agg, T2, NN);

  // ---- final matmuls + gate combine ----
  k_mm_final<<<gN, 256, 0, stream>>>(A2agg, gcn_w2, gcn_b2, S2agg, sage_wl2, sage_bl2,
                                     s1, sage_wr2, T2, gat_b2, gatew, out, NN);
}